// Round 9
// baseline (186.666 us; speedup 1.0000x reference)
//
#include <hip/hip_runtime.h>
#include <math.h>

#define Bn 8
#define Cn 112
#define Hn 64
#define Wn 64
#define On 112
#define Gn 14
#define PGC 378          // 3*G*K2
#define HW 4096          // 64*64
#define CKW 1008         // C*K2
#define KP 1024          // padded K for main GEMM (sampled layout)
#define NP 384           // padded N (oc) for pg GEMM
#define KSH 1152         // shift-GEMM K = 9 taps * 128 padded channels
#define CP 128           // padded channel count
#define MFULL 32768
#define XROW 4356        // 66*66 rows per batch in XT
#define MPAD 34944       // 273*128 tile-padded px'' domain
#define XGUARD 67
#define XALLOC_ROWS (XGUARD + MPAD + XGUARD + 2)   // 35080

typedef __attribute__((ext_vector_type(8))) short bf16x8;
typedef __attribute__((ext_vector_type(4))) float f32x4;

__device__ __forceinline__ unsigned short f2bf(float f) {
    union { float f; unsigned int u; } v; v.f = f;
    unsigned int r = v.u + 0x7fffu + ((v.u >> 16) & 1u);
    return (unsigned short)(r >> 16);
}
__device__ __forceinline__ float bf2f(unsigned short u) {
    union { unsigned int u; float f; } v; v.u = ((unsigned int)u) << 16;
    return v.f;
}
__device__ __forceinline__ float bflo(unsigned int u) {
    union { unsigned int u; float f; } v; v.u = u << 16; return v.f;
}
__device__ __forceinline__ float bfhi(unsigned int u) {
    union { unsigned int u; float f; } v; v.u = u & 0xffff0000u; return v.f;
}
__device__ __forceinline__ void gload_lds16(const void* g, void* l) {
    __builtin_amdgcn_global_load_lds(
        (const __attribute__((address_space(1))) unsigned int*)g,
        (__attribute__((address_space(3))) unsigned int*)l, 16, 0, 0);
}

// ---------------------------------------------------------------------------
// prep (merged): zero XT alloc | B2 shift-layout [384][1152] | WB [128][1024]
// ---------------------------------------------------------------------------
#define ZN (XALLOC_ROWS * CP / 8)
#define B2N (NP * KSH)
#define WBN (128 * KP)
__global__ __launch_bounds__(256) void prep_kernel(
    const float* __restrict__ pgw, const float* __restrict__ w,
    unsigned short* __restrict__ XTa, unsigned short* __restrict__ B2,
    unsigned short* __restrict__ WB)
{
    int t = blockIdx.x * 256 + threadIdx.x;
    if (t < ZN) {
        const uint4 z = {0, 0, 0, 0};
        reinterpret_cast<uint4*>(XTa)[t] = z;
        return;
    }
    t -= ZN;
    if (t < B2N) {
        int oc = t / KSH, ckk = t - oc * KSH;
        int k = ckk >> 7, c = ckk & 127;
        float v = (c < Cn && oc < PGC) ? pgw[(size_t)oc * CKW + c * 9 + k] : 0.f;
        B2[t] = f2bf(v);
        return;
    }
    t -= B2N;
    if (t < WBN) {
        int oc = t >> 10, ck = t & 1023;
        float v = 0.f;
        if (oc < On && ck < CKW) {
            int g = ck / 72, r = ck % 72;
            int k = r >> 3, cc = r & 7;
            v = w[(size_t)oc * CKW + (g * 8 + cc) * 9 + k];
        }
        WB[t] = f2bf(v);
    }
}

// ---------------------------------------------------------------------------
// xpose: x NCHW f32 -> XT bf16 rows [(b*66 + y+1)*66 + x+1][128]
// ---------------------------------------------------------------------------
__global__ __launch_bounds__(256) void xpose_kernel(
    const float* __restrict__ x, unsigned short* __restrict__ XT)
{
    __shared__ unsigned short lds[64][136];

    const int tid = threadIdx.x;
    const int y = blockIdx.x, b = blockIdx.y;
    const int xx = tid & 63, cw = tid >> 6;

    const float* xb = x + (size_t)b * Cn * HW + y * 64;
    #pragma unroll
    for (int p = 0; p < 28; ++p) {
        int c = p * 4 + cw;
        lds[xx][c] = f2bf(xb[(size_t)c * HW + xx]);
        if (p < 4) lds[xx][112 + p * 4 + cw] = 0;
    }
    __syncthreads();

    const int rx = tid >> 2, seg = tid & 3;
    size_t row = (size_t)(b * 66 + y + 1) * 66 + rx + 1;
    unsigned short* dst = XT + row * CP + seg * 32;
    const unsigned short* srcr = &lds[rx][seg * 32];
    #pragma unroll
    for (int j = 0; j < 4; ++j)
        *reinterpret_cast<uint4*>(dst + j * 8) =
            *reinterpret_cast<const uint4*>(srcr + j * 8);
}

// ---------------------------------------------------------------------------
// pg shift-GEMM: 128x128 tile, 36 K-steps (9 taps x 4 c-chunks of 32).
// Double-buffered prefetch: stage(kt+1) issued before waiting on stage(kt);
// counted s_waitcnt vmcnt(4) keeps next tile's loads in flight across the
// barrier (T3-minimum). Exactly 4 global_load_lds per wave per stage.
// ---------------------------------------------------------------------------
__global__ __launch_bounds__(256) void pg_shift_kernel(
    const unsigned short* __restrict__ XT, const unsigned short* __restrict__ B2,
    const float* __restrict__ pgb, unsigned short* __restrict__ pgBF)
{
    __shared__ __align__(16) unsigned short Asm[2][128 * 32];
    __shared__ __align__(16) unsigned short Bsm[2][128 * 32];

    const int tid  = threadIdx.x;
    const int lane = tid & 63;
    const int w    = tid >> 6;
    const int wr   = w >> 1, wc = w & 1;
    const int m0   = blockIdx.x * 128;
    const int n0   = blockIdx.y * 128;
    const int fr   = lane & 15, fq = lane >> 4;

    f32x4 acc[4][4] = {};

    const int ldr = lane >> 2;
    const int ldc = (lane & 3) * 8;

    auto stage = [&](int buf, int kt) {
        const int k = kt >> 2;
        const int shift = (k / 3 - 1) * 66 + (k % 3 - 1);
        const int c0 = (kt & 3) * 32;
        #pragma unroll
        for (int i = 0; i < 2; ++i) {
            int row = w * 32 + i * 16 + ldr;
            gload_lds16(&XT[(size_t)(m0 + row + shift) * CP + c0 + ldc],
                        &Asm[buf][(w * 32 + i * 16) * 32]);
            gload_lds16(&B2[(size_t)(n0 + row) * KSH + kt * 32 + ldc],
                        &Bsm[buf][(w * 32 + i * 16) * 32]);
        }
    };

    stage(0, 0);
    int cur = 0;
    for (int kt = 0; kt < 36; ++kt) {
        if (kt + 1 < 36) {
            stage(cur ^ 1, kt + 1);
            asm volatile("s_waitcnt vmcnt(4)" ::: "memory");
        } else {
            asm volatile("s_waitcnt vmcnt(0)" ::: "memory");
        }
        __builtin_amdgcn_s_barrier();
        asm volatile("" ::: "memory");

        bf16x8 a[4], b[4];
        #pragma unroll
        for (int mi = 0; mi < 4; ++mi)
            a[mi] = *reinterpret_cast<const bf16x8*>(
                &Asm[cur][(wr * 64 + mi * 16 + fr) * 32 + fq * 8]);
        #pragma unroll
        for (int ni = 0; ni < 4; ++ni)
            b[ni] = *reinterpret_cast<const bf16x8*>(
                &Bsm[cur][(wc * 64 + ni * 16 + fr) * 32 + fq * 8]);
        #pragma unroll
        for (int mi = 0; mi < 4; ++mi)
            #pragma unroll
            for (int ni = 0; ni < 4; ++ni)
                acc[mi][ni] = __builtin_amdgcn_mfma_f32_16x16x32_bf16(
                    a[mi], b[ni], acc[mi][ni], 0, 0, 0);

        asm volatile("s_waitcnt lgkmcnt(0)" ::: "memory");
        __builtin_amdgcn_s_barrier();
        asm volatile("" ::: "memory");
        cur ^= 1;
    }

    #pragma unroll
    for (int ni = 0; ni < 4; ++ni) {
        int oc = n0 + wc * 64 + ni * 16 + fr;
        if (oc >= PGC) continue;
        float bias = pgb[oc];
        #pragma unroll
        for (int mi = 0; mi < 4; ++mi) {
            int pxq = m0 + wr * 64 + mi * 16 + fq * 4;
            #pragma unroll
            for (int r = 0; r < 4; ++r) {
                int pxd = pxq + r;
                if (pxd >= Bn * XROW) continue;
                int bb = pxd / XROW;
                int rem = pxd - bb * XROW;
                int yy = rem / 66 - 1;
                int xx = rem - (yy + 1) * 66 - 1;
                if ((unsigned)yy < 64u && (unsigned)xx < 64u)
                    pgBF[((size_t)(bb * PGC + oc)) * HW + yy * 64 + xx] =
                        f2bf(acc[mi][ni][r] + bias);
            }
        }
    }
}

// ---------------------------------------------------------------------------
// sample: thread = (pixel, (g,k) tap); gathers 4 bf16 corner rows (16B each)
// from NHWC XT; writes 16B into tiled S [px/128][ck/8][px%128][8ck].
// ---------------------------------------------------------------------------
__global__ __launch_bounds__(256) void sample_kernel(
    const unsigned short* __restrict__ XT, const unsigned short* __restrict__ pg,
    unsigned short* __restrict__ S, int px_base)
{
    const int pxl = blockIdx.x * 256 + threadIdx.x;
    const int gk  = blockIdx.y;              // 0..125
    const int g = gk / 9, k = gk - 9 * g;
    const int pxg = px_base + pxl;
    const int b = pxg >> 12, hw = pxg & 4095;
    const int y = hw >> 6, xc = hw & 63;
    const int pblk = pxl >> 7, prem = pxl & 127;

    if (gk == 0) {   // zero K-pad blocks cb = 126, 127
        const uint4 z = {0, 0, 0, 0};
        *reinterpret_cast<uint4*>(
            &S[(((size_t)pblk * 128 + 126) * 128 + prem) * 8]) = z;
        *reinterpret_cast<uint4*>(
            &S[(((size_t)pblk * 128 + 127) * 128 + prem) * 8]) = z;
    }

    const unsigned short* pgb = pg + (size_t)b * PGC * HW + hw;
    float dy = bf2f(pgb[(size_t)(18 * g + 2 * k) * HW]);
    float dx = bf2f(pgb[(size_t)(18 * g + 2 * k + 1) * HW]);
    float mv = bf2f(pgb[(size_t)(252 + 9 * g + k) * HW]);
    float m  = 1.f / (1.f + __expf(-mv));

    const int ky = k / 3, kx = k % 3;
    float yf = (float)(y + ky - 1) + dy;
    float xf = (float)(xc + kx - 1) + dx;
    float y0 = floorf(yf), x0 = floorf(xf);
    float wy1 = yf - y0, wx1 = xf - x0;
    float wy0 = 1.f - wy1, wx0 = 1.f - wx1;
    int iy0 = (int)y0, ix0 = (int)x0;
    bool vy0 = (iy0 >= 0) && (iy0 < Hn);
    bool vy1 = (iy0 >= -1) && (iy0 < Hn - 1);
    bool vx0 = (ix0 >= 0) && (ix0 < Wn);
    bool vx1 = (ix0 >= -1) && (ix0 < Wn - 1);
    int cy0 = min(max(iy0, 0), Hn - 1), cy1 = min(max(iy0 + 1, 0), Hn - 1);
    int cx0 = min(max(ix0, 0), Wn - 1), cx1 = min(max(ix0 + 1, 0), Wn - 1);
    float w00 = (vy0 && vx0) ? wy0 * wx0 * m : 0.f;
    float w01 = (vy0 && vx1) ? wy0 * wx1 * m : 0.f;
    float w10 = (vy1 && vx0) ? wy1 * wx0 * m : 0.f;
    float w11 = (vy1 && vx1) ? wy1 * wx1 * m : 0.f;

    const unsigned short* xtb = XT + (size_t)(b * 66) * 66 * CP + g * 8;
    const int r00 = (cy0 + 1) * 66 + cx0 + 1, r01 = (cy0 + 1) * 66 + cx1 + 1;
    const int r10 = (cy1 + 1) * 66 + cx0 + 1, r11 = (cy1 + 1) * 66 + cx1 + 1;
    uint4 q00 = *reinterpret_cast<const uint4*>(xtb + (size_t)r00 * CP);
    uint4 q01 = *reinterpret_cast<const uint4*>(xtb + (size_t)r01 * CP);
    uint4 q10 = *reinterpret_cast<const uint4*>(xtb + (size_t)r10 * CP);
    uint4 q11 = *reinterpret_cast<const uint4*>(xtb + (size_t)r11 * CP);

    unsigned int c00[4] = {q00.x, q00.y, q00.z, q00.w};
    unsigned int c01[4] = {q01.x, q01.y, q01.z, q01.w};
    unsigned int c10[4] = {q10.x, q10.y, q10.z, q10.w};
    unsigned int c11[4] = {q11.x, q11.y, q11.z, q11.w};

    unsigned int pk[4];
    #pragma unroll
    for (int j = 0; j < 4; ++j) {
        float lo = bflo(c00[j]) * w00 + bflo(c01[j]) * w01 +
                   bflo(c10[j]) * w10 + bflo(c11[j]) * w11;
        float hi = bfhi(c00[j]) * w00 + bfhi(c01[j]) * w01 +
                   bfhi(c10[j]) * w10 + bfhi(c11[j]) * w11;
        pk[j] = (unsigned int)f2bf(lo) | ((unsigned int)f2bf(hi) << 16);
    }
    *reinterpret_cast<uint4*>(
        &S[(((size_t)pblk * 128 + gk) * 128 + prem) * 8]) =
        *reinterpret_cast<const uint4*>(pk);
}

// ---------------------------------------------------------------------------
// main GEMM: out[b][oc][hw] = S_tiled[px][ck] * WB[oc][ck] + bias[oc]
// Same double-buffered prefetch structure as pg_shift.
// ---------------------------------------------------------------------------
__global__ __launch_bounds__(256) void main_gemm_kernel(
    const unsigned short* __restrict__ S, const unsigned short* __restrict__ WB,
    const float* __restrict__ bias, float* __restrict__ out, int px_base)
{
    __shared__ __align__(16) unsigned short Asm[2][128 * 32];
    __shared__ __align__(16) unsigned short Bsm[2][128 * 32];

    const int tid  = threadIdx.x;
    const int lane = tid & 63;
    const int w    = tid >> 6;
    const int wr   = w >> 1, wc = w & 1;
    const int m0   = blockIdx.x * 128;
    const int fr   = lane & 15, fq = lane >> 4;

    f32x4 acc[4][4] = {};

    const int ldr = lane >> 2;
    const int lq  = lane & 3;
    const int ldc = lq * 8;

    auto stage = [&](int buf, int kt) {
        #pragma unroll
        for (int i = 0; i < 2; ++i) {
            int row = w * 32 + i * 16 + ldr;
            int cb  = kt * 4 + lq;
            gload_lds16(&S[(((size_t)blockIdx.x * 128 + cb) * 128 + row) * 8],
                        &Asm[buf][(w * 32 + i * 16) * 32]);
            gload_lds16(&WB[(size_t)row * KP + kt * 32 + ldc],
                        &Bsm[buf][(w * 32 + i * 16) * 32]);
        }
    };

    stage(0, 0);
    int cur = 0;
    for (int kt = 0; kt < 32; ++kt) {
        if (kt + 1 < 32) {
            stage(cur ^ 1, kt + 1);
            asm volatile("s_waitcnt vmcnt(4)" ::: "memory");
        } else {
            asm volatile("s_waitcnt vmcnt(0)" ::: "memory");
        }
        __builtin_amdgcn_s_barrier();
        asm volatile("" ::: "memory");

        bf16x8 a[4], b[4];
        #pragma unroll
        for (int mi = 0; mi < 4; ++mi)
            a[mi] = *reinterpret_cast<const bf16x8*>(
                &Asm[cur][(wr * 64 + mi * 16 + fr) * 32 + fq * 8]);
        #pragma unroll
        for (int ni = 0; ni < 4; ++ni)
            b[ni] = *reinterpret_cast<const bf16x8*>(
                &Bsm[cur][(wc * 64 + ni * 16 + fr) * 32 + fq * 8]);
        #pragma unroll
        for (int mi = 0; mi < 4; ++mi)
            #pragma unroll
            for (int ni = 0; ni < 4; ++ni)
                acc[mi][ni] = __builtin_amdgcn_mfma_f32_16x16x32_bf16(
                    a[mi], b[ni], acc[mi][ni], 0, 0, 0);

        asm volatile("s_waitcnt lgkmcnt(0)" ::: "memory");
        __builtin_amdgcn_s_barrier();
        asm volatile("" ::: "memory");
        cur ^= 1;
    }

    #pragma unroll
    for (int ni = 0; ni < 4; ++ni) {
        int oc = wc * 64 + ni * 16 + fr;
        if (oc >= On) continue;
        float bv = bias[oc];
        #pragma unroll
        for (int mi = 0; mi < 4; ++mi) {
            int pxl = m0 + wr * 64 + mi * 16 + fq * 4;
            int pxg = px_base + pxl;
            int b = pxg >> 12, hw = pxg & 4095;
            float4 o;
            o.x = acc[mi][ni][0] + bv;
            o.y = acc[mi][ni][1] + bv;
            o.z = acc[mi][ni][2] + bv;
            o.w = acc[mi][ni][3] + bv;
            *reinterpret_cast<float4*>(
                &out[((size_t)(b * On + oc)) * HW + hw]) = o;
        }
    }
}

// ---------------------------------------------------------------------------
extern "C" void kernel_launch(void* const* d_in, const int* in_sizes, int n_in,
                              void* d_out, int out_size, void* d_ws, size_t ws_size,
                              hipStream_t stream) {
    const float* x    = (const float*)d_in[0];
    const float* pgw  = (const float*)d_in[1];
    const float* pgb  = (const float*)d_in[2];
    const float* w    = (const float*)d_in[3];
    const float* bias = (const float*)d_in[4];
    float* out = (float*)d_out;

    char* wsb = (char*)d_ws;
    unsigned short* pgBF = (unsigned short*)wsb;                 // 24.77 MB
    size_t off = (size_t)PGC * Bn * HW * 2;
    unsigned short* B2   = (unsigned short*)(wsb + off);         // 0.88 MB
    off += (size_t)NP * KSH * 2;
    unsigned short* WB   = (unsigned short*)(wsb + off);         // 0.26 MB
    off += (size_t)128 * KP * 2;
    unsigned short* XTa  = (unsigned short*)(wsb + off);         // 8.98 MB
    unsigned short* XT   = XTa + (size_t)XGUARD * CP;
    off += (size_t)XALLOC_ROWS * CP * 2;
    unsigned short* S    = (unsigned short*)(wsb + off);         // sampled (tiled)

    const size_t sfull = (size_t)MFULL * KP * 2;                 // 67.1 MB
    int nh;
    if (ws_size >= off + sfull)          nh = 1;   // 102.0 MB total
    else if (ws_size >= off + sfull / 2) nh = 2;   //  68.4 MB
    else                                 nh = 4;   //  51.7 MB
    const int cnt = MFULL / nh;

    // prep: zero XT + build B2 + WB
    {
        int tot = ZN + B2N + WBN;
        prep_kernel<<<(tot + 255) / 256, 256, 0, stream>>>(pgw, w, XTa, B2, WB);
    }
    // transpose x -> XT (NHWC bf16, 66x66 halo)
    xpose_kernel<<<dim3(Hn, Bn), 256, 0, stream>>>(x, XT);

    // pg conv as shift-GEMM (double-buffered prefetch)
    pg_shift_kernel<<<dim3(MPAD / 128, NP / 128), 256, 0, stream>>>(
        XT, B2, pgb, pgBF);

    // deformable sampling (NHWC corner loads) -> tiled S, then main GEMM
    for (int h = 0; h < nh; ++h) {
        sample_kernel<<<dim3(cnt / 256, 126), 256, 0, stream>>>(
            XT, pgBF, S, h * cnt);
        main_gemm_kernel<<<dim3(cnt / 128, 1), 256, 0, stream>>>(
            S, WB, bias, out, h * cnt);
    }
}

// Round 10
// 171.017 us; speedup vs baseline: 1.0915x; 1.0915x over previous
//
#include <hip/hip_runtime.h>
#include <math.h>

#define Bn 8
#define Cn 112
#define Hn 64
#define Wn 64
#define On 112
#define Gn 14
#define PGC 378          // 3*G*K2
#define HW 4096          // 64*64
#define CKW 1008         // C*K2
#define KP 1024          // padded K for main GEMM (sampled layout)
#define NP 384           // padded N (oc) for pg GEMM
#define KSH 1152         // shift-GEMM K = 9 taps * 128 padded channels
#define CP 128           // padded channel count
#define MFULL 32768
#define XROW 4356        // 66*66 rows per batch in XT
#define PG_MT 137        // M-tiles of 256
#define MPAD (PG_MT * 256)                 // 35072
#define XGUARD 67
#define XALLOC_ROWS (XGUARD + MPAD + XGUARD + 2)   // 35208

typedef __attribute__((ext_vector_type(8))) short bf16x8;
typedef __attribute__((ext_vector_type(4))) float f32x4;

__device__ __forceinline__ unsigned short f2bf(float f) {
    union { float f; unsigned int u; } v; v.f = f;
    unsigned int r = v.u + 0x7fffu + ((v.u >> 16) & 1u);
    return (unsigned short)(r >> 16);
}
__device__ __forceinline__ float bf2f(unsigned short u) {
    union { unsigned int u; float f; } v; v.u = ((unsigned int)u) << 16;
    return v.f;
}
__device__ __forceinline__ float bflo(unsigned int u) {
    union { unsigned int u; float f; } v; v.u = u << 16; return v.f;
}
__device__ __forceinline__ float bfhi(unsigned int u) {
    union { unsigned int u; float f; } v; v.u = u & 0xffff0000u; return v.f;
}
__device__ __forceinline__ void gload_lds16(const void* g, void* l) {
    __builtin_amdgcn_global_load_lds(
        (const __attribute__((address_space(1))) unsigned int*)g,
        (__attribute__((address_space(3))) unsigned int*)l, 16, 0, 0);
}

// ---------------------------------------------------------------------------
// prep (merged): zero XT alloc | B2 shift-layout [384][1152] | WB [128][1024]
// ---------------------------------------------------------------------------
#define ZN (XALLOC_ROWS * CP / 8)
#define B2N (NP * KSH)
#define WBN (128 * KP)
__global__ __launch_bounds__(256) void prep_kernel(
    const float* __restrict__ pgw, const float* __restrict__ w,
    unsigned short* __restrict__ XTa, unsigned short* __restrict__ B2,
    unsigned short* __restrict__ WB)
{
    int t = blockIdx.x * 256 + threadIdx.x;
    if (t < ZN) {
        const uint4 z = {0, 0, 0, 0};
        reinterpret_cast<uint4*>(XTa)[t] = z;
        return;
    }
    t -= ZN;
    if (t < B2N) {
        int oc = t / KSH, ckk = t - oc * KSH;
        int k = ckk >> 7, c = ckk & 127;
        float v = (c < Cn && oc < PGC) ? pgw[(size_t)oc * CKW + c * 9 + k] : 0.f;
        B2[t] = f2bf(v);
        return;
    }
    t -= B2N;
    if (t < WBN) {
        int oc = t >> 10, ck = t & 1023;
        float v = 0.f;
        if (oc < On && ck < CKW) {
            int g = ck / 72, r = ck % 72;
            int k = r >> 3, cc = r & 7;
            v = w[(size_t)oc * CKW + (g * 8 + cc) * 9 + k];
        }
        WB[t] = f2bf(v);
    }
}

// ---------------------------------------------------------------------------
// xpose: x NCHW f32 -> XT bf16 rows [(b*66 + y+1)*66 + x+1][128]
// ---------------------------------------------------------------------------
__global__ __launch_bounds__(256) void xpose_kernel(
    const float* __restrict__ x, unsigned short* __restrict__ XT)
{
    __shared__ unsigned short lds[64][136];

    const int tid = threadIdx.x;
    const int y = blockIdx.x, b = blockIdx.y;
    const int xx = tid & 63, cw = tid >> 6;

    const float* xb = x + (size_t)b * Cn * HW + y * 64;
    #pragma unroll
    for (int p = 0; p < 28; ++p) {
        int c = p * 4 + cw;
        lds[xx][c] = f2bf(xb[(size_t)c * HW + xx]);
        if (p < 4) lds[xx][112 + p * 4 + cw] = 0;
    }
    __syncthreads();

    const int rx = tid >> 2, seg = tid & 3;
    size_t row = (size_t)(b * 66 + y + 1) * 66 + rx + 1;
    unsigned short* dst = XT + row * CP + seg * 32;
    const unsigned short* srcr = &lds[rx][seg * 32];
    #pragma unroll
    for (int j = 0; j < 4; ++j)
        *reinterpret_cast<uint4*>(dst + j * 8) =
            *reinterpret_cast<const uint4*>(srcr + j * 8);
}

// ---------------------------------------------------------------------------
// pg shift-GEMM v2: 256x128 tile, BK=64 (18 K-steps), 8 waves (4M x 2N),
// per-wave 64x64 output (4x4 frags, 32 MFMA/step).
// T2 XOR-swizzled LDS (chunk ^= row&7); staging = linear-dest global_load_lds
// with inverse-swizzled per-lane GLOBAL source (rule #21).
// Double-buffered, counted vmcnt(6), 2 barriers/step, setprio around MFMA.
// ---------------------------------------------------------------------------
__global__ __launch_bounds__(512, 1) void pg_shift_kernel(
    const unsigned short* __restrict__ XT, const unsigned short* __restrict__ B2,
    const float* __restrict__ pgb, unsigned short* __restrict__ pgBF)
{
    __shared__ __align__(16) unsigned short Asm[2][256 * 64];   // 64 KB
    __shared__ __align__(16) unsigned short Bsm[2][128 * 64];   // 32 KB

    const int tid  = threadIdx.x;
    const int lane = tid & 63;
    const int w    = tid >> 6;          // 0..7
    const int wr   = w >> 1;            // 0..3  (M)
    const int wc   = w & 1;             // 0..1  (N)
    const int m0   = blockIdx.x * 256;
    const int n0   = blockIdx.y * 128;
    const int fr   = lane & 15, fq = lane >> 4;
    const int lr8  = lane >> 3;         // 0..7 row-in-span
    const int lc8  = lane & 7;          // 0..7 chunk

    f32x4 acc[4][4] = {};

    // stage one K-tile (exactly 6 global_load_lds per lane: 4 A + 2 B)
    auto stage = [&](int buf, int kt) {
        const int tap = kt >> 1;
        const int shift = (tap / 3 - 1) * 66 + (tap % 3 - 1);
        const int c0 = (kt & 1) * 64;
        #pragma unroll
        for (int s = 0; s < 4; ++s) {
            int r = w * 32 + s * 8 + lr8;
            int cl = lc8 ^ (r & 7);
            gload_lds16(&XT[(size_t)(m0 + r + shift) * CP + c0 + cl * 8],
                        &Asm[buf][(w * 32 + s * 8) * 64]);
        }
        #pragma unroll
        for (int s = 0; s < 2; ++s) {
            int r = w * 16 + s * 8 + lr8;
            int cl = lc8 ^ (r & 7);
            gload_lds16(&B2[(size_t)(n0 + r) * KSH + kt * 64 + cl * 8],
                        &Bsm[buf][(w * 16 + s * 8) * 64]);
        }
    };

    stage(0, 0);
    int cur = 0;
    for (int kt = 0; kt < 18; ++kt) {
        __builtin_amdgcn_s_barrier();          // prev-iter reads of buf[cur^1] done
        asm volatile("" ::: "memory");
        if (kt + 1 < 18) {
            stage(cur ^ 1, kt + 1);
            asm volatile("s_waitcnt vmcnt(6)" ::: "memory");
        } else {
            asm volatile("s_waitcnt vmcnt(0)" ::: "memory");
        }
        __builtin_amdgcn_s_barrier();          // buf[cur] fully staged (all waves)
        asm volatile("" ::: "memory");

        const char* Ab = (const char*)Asm[cur];
        const char* Bb = (const char*)Bsm[cur];
        bf16x8 a[2][4], b[2][4];
        #pragma unroll
        for (int ks = 0; ks < 2; ++ks) {
            const int csw = ((ks << 2) + fq);
            #pragma unroll
            for (int mi = 0; mi < 4; ++mi) {
                int r = wr * 64 + mi * 16 + fr;
                a[ks][mi] = *reinterpret_cast<const bf16x8*>(
                    Ab + r * 128 + ((csw ^ (fr & 7)) << 4));
            }
            #pragma unroll
            for (int ni = 0; ni < 4; ++ni) {
                int r = wc * 64 + ni * 16 + fr;
                b[ks][ni] = *reinterpret_cast<const bf16x8*>(
                    Bb + r * 128 + ((csw ^ (fr & 7)) << 4));
            }
        }
        __builtin_amdgcn_s_setprio(1);
        #pragma unroll
        for (int ks = 0; ks < 2; ++ks)
            #pragma unroll
            for (int mi = 0; mi < 4; ++mi)
                #pragma unroll
                for (int ni = 0; ni < 4; ++ni)
                    acc[mi][ni] = __builtin_amdgcn_mfma_f32_16x16x32_bf16(
                        a[ks][mi], b[ks][ni], acc[mi][ni], 0, 0, 0);
        __builtin_amdgcn_s_setprio(0);
        cur ^= 1;
    }

    #pragma unroll
    for (int ni = 0; ni < 4; ++ni) {
        int oc = n0 + wc * 64 + ni * 16 + fr;
        if (oc >= PGC) continue;
        float bias = pgb[oc];
        #pragma unroll
        for (int mi = 0; mi < 4; ++mi) {
            int pxq = m0 + wr * 64 + mi * 16 + fq * 4;
            #pragma unroll
            for (int r = 0; r < 4; ++r) {
                int pxd = pxq + r;
                if (pxd >= Bn * XROW) continue;
                int bb = pxd / XROW;
                int rem = pxd - bb * XROW;
                int yy = rem / 66 - 1;
                int xx = rem - (yy + 1) * 66 - 1;
                if ((unsigned)yy < 64u && (unsigned)xx < 64u)
                    pgBF[((size_t)(bb * PGC + oc)) * HW + yy * 64 + xx] =
                        f2bf(acc[mi][ni][r] + bias);
            }
        }
    }
}

// ---------------------------------------------------------------------------
// sample: thread = (pixel, (g,k) tap); gathers 4 bf16 corner rows (16B each)
// from NHWC XT; writes 16B into tiled S [px/128][ck/8][px%128][8ck].
// ---------------------------------------------------------------------------
__global__ __launch_bounds__(256) void sample_kernel(
    const unsigned short* __restrict__ XT, const unsigned short* __restrict__ pg,
    unsigned short* __restrict__ S, int px_base)
{
    const int pxl = blockIdx.x * 256 + threadIdx.x;
    const int gk  = blockIdx.y;              // 0..125
    const int g = gk / 9, k = gk - 9 * g;
    const int pxg = px_base + pxl;
    const int b = pxg >> 12, hw = pxg & 4095;
    const int y = hw >> 6, xc = hw & 63;
    const int pblk = pxl >> 7, prem = pxl & 127;

    if (gk == 0) {   // zero K-pad blocks cb = 126, 127
        const uint4 z = {0, 0, 0, 0};
        *reinterpret_cast<uint4*>(
            &S[(((size_t)pblk * 128 + 126) * 128 + prem) * 8]) = z;
        *reinterpret_cast<uint4*>(
            &S[(((size_t)pblk * 128 + 127) * 128 + prem) * 8]) = z;
    }

    const unsigned short* pgb = pg + (size_t)b * PGC * HW + hw;
    float dy = bf2f(pgb[(size_t)(18 * g + 2 * k) * HW]);
    float dx = bf2f(pgb[(size_t)(18 * g + 2 * k + 1) * HW]);
    float mv = bf2f(pgb[(size_t)(252 + 9 * g + k) * HW]);
    float m  = 1.f / (1.f + __expf(-mv));

    const int ky = k / 3, kx = k % 3;
    float yf = (float)(y + ky - 1) + dy;
    float xf = (float)(xc + kx - 1) + dx;
    float y0 = floorf(yf), x0 = floorf(xf);
    float wy1 = yf - y0, wx1 = xf - x0;
    float wy0 = 1.f - wy1, wx0 = 1.f - wx1;
    int iy0 = (int)y0, ix0 = (int)x0;
    bool vy0 = (iy0 >= 0) && (iy0 < Hn);
    bool vy1 = (iy0 >= -1) && (iy0 < Hn - 1);
    bool vx0 = (ix0 >= 0) && (ix0 < Wn);
    bool vx1 = (ix0 >= -1) && (ix0 < Wn - 1);
    int cy0 = min(max(iy0, 0), Hn - 1), cy1 = min(max(iy0 + 1, 0), Hn - 1);
    int cx0 = min(max(ix0, 0), Wn - 1), cx1 = min(max(ix0 + 1, 0), Wn - 1);
    float w00 = (vy0 && vx0) ? wy0 * wx0 * m : 0.f;
    float w01 = (vy0 && vx1) ? wy0 * wx1 * m : 0.f;
    float w10 = (vy1 && vx0) ? wy1 * wx0 * m : 0.f;
    float w11 = (vy1 && vx1) ? wy1 * wx1 * m : 0.f;

    const unsigned short* xtb = XT + (size_t)(b * 66) * 66 * CP + g * 8;
    const int r00 = (cy0 + 1) * 66 + cx0 + 1, r01 = (cy0 + 1) * 66 + cx1 + 1;
    const int r10 = (cy1 + 1) * 66 + cx0 + 1, r11 = (cy1 + 1) * 66 + cx1 + 1;
    uint4 q00 = *reinterpret_cast<const uint4*>(xtb + (size_t)r00 * CP);
    uint4 q01 = *reinterpret_cast<const uint4*>(xtb + (size_t)r01 * CP);
    uint4 q10 = *reinterpret_cast<const uint4*>(xtb + (size_t)r10 * CP);
    uint4 q11 = *reinterpret_cast<const uint4*>(xtb + (size_t)r11 * CP);

    unsigned int c00[4] = {q00.x, q00.y, q00.z, q00.w};
    unsigned int c01[4] = {q01.x, q01.y, q01.z, q01.w};
    unsigned int c10[4] = {q10.x, q10.y, q10.z, q10.w};
    unsigned int c11[4] = {q11.x, q11.y, q11.z, q11.w};

    unsigned int pk[4];
    #pragma unroll
    for (int j = 0; j < 4; ++j) {
        float lo = bflo(c00[j]) * w00 + bflo(c01[j]) * w01 +
                   bflo(c10[j]) * w10 + bflo(c11[j]) * w11;
        float hi = bfhi(c00[j]) * w00 + bfhi(c01[j]) * w01 +
                   bfhi(c10[j]) * w10 + bfhi(c11[j]) * w11;
        pk[j] = (unsigned int)f2bf(lo) | ((unsigned int)f2bf(hi) << 16);
    }
    *reinterpret_cast<uint4*>(
        &S[(((size_t)pblk * 128 + gk) * 128 + prem) * 8]) =
        *reinterpret_cast<const uint4*>(pk);
}

// ---------------------------------------------------------------------------
// main GEMM: out[b][oc][hw] = S_tiled[px][ck] * WB[oc][ck] + bias[oc]
// Double-buffered prefetch, counted vmcnt (validated round 9).
// ---------------------------------------------------------------------------
__global__ __launch_bounds__(256) void main_gemm_kernel(
    const unsigned short* __restrict__ S, const unsigned short* __restrict__ WB,
    const float* __restrict__ bias, float* __restrict__ out, int px_base)
{
    __shared__ __align__(16) unsigned short Asm[2][128 * 32];
    __shared__ __align__(16) unsigned short Bsm[2][128 * 32];

    const int tid  = threadIdx.x;
    const int lane = tid & 63;
    const int w    = tid >> 6;
    const int wr   = w >> 1, wc = w & 1;
    const int m0   = blockIdx.x * 128;
    const int fr   = lane & 15, fq = lane >> 4;

    f32x4 acc[4][4] = {};

    const int ldr = lane >> 2;
    const int lq  = lane & 3;
    const int ldc = lq * 8;

    auto stage = [&](int buf, int kt) {
        #pragma unroll
        for (int i = 0; i < 2; ++i) {
            int row = w * 32 + i * 16 + ldr;
            int cb  = kt * 4 + lq;
            gload_lds16(&S[(((size_t)blockIdx.x * 128 + cb) * 128 + row) * 8],
                        &Asm[buf][(w * 32 + i * 16) * 32]);
            gload_lds16(&WB[(size_t)row * KP + kt * 32 + ldc],
                        &Bsm[buf][(w * 32 + i * 16) * 32]);
        }
    };

    stage(0, 0);
    int cur = 0;
    for (int kt = 0; kt < 32; ++kt) {
        if (kt + 1 < 32) {
            stage(cur ^ 1, kt + 1);
            asm volatile("s_waitcnt vmcnt(4)" ::: "memory");
        } else {
            asm volatile("s_waitcnt vmcnt(0)" ::: "memory");
        }
        __builtin_amdgcn_s_barrier();
        asm volatile("" ::: "memory");

        bf16x8 a[4], b[4];
        #pragma unroll
        for (int mi = 0; mi < 4; ++mi)
            a[mi] = *reinterpret_cast<const bf16x8*>(
                &Asm[cur][(wr * 64 + mi * 16 + fr) * 32 + fq * 8]);
        #pragma unroll
        for (int ni = 0; ni < 4; ++ni)
            b[ni] = *reinterpret_cast<const bf16x8*>(
                &Bsm[cur][(wc * 64 + ni * 16 + fr) * 32 + fq * 8]);
        #pragma unroll
        for (int mi = 0; mi < 4; ++mi)
            #pragma unroll
            for (int ni = 0; ni < 4; ++ni)
                acc[mi][ni] = __builtin_amdgcn_mfma_f32_16x16x32_bf16(
                    a[mi], b[ni], acc[mi][ni], 0, 0, 0);

        asm volatile("s_waitcnt lgkmcnt(0)" ::: "memory");
        __builtin_amdgcn_s_barrier();
        asm volatile("" ::: "memory");
        cur ^= 1;
    }

    #pragma unroll
    for (int ni = 0; ni < 4; ++ni) {
        int oc = wc * 64 + ni * 16 + fr;
        if (oc >= On) continue;
        float bv = bias[oc];
        #pragma unroll
        for (int mi = 0; mi < 4; ++mi) {
            int pxl = m0 + wr * 64 + mi * 16 + fq * 4;
            int pxg = px_base + pxl;
            int b = pxg >> 12, hw = pxg & 4095;
            float4 o;
            o.x = acc[mi][ni][0] + bv;
            o.y = acc[mi][ni][1] + bv;
            o.z = acc[mi][ni][2] + bv;
            o.w = acc[mi][ni][3] + bv;
            *reinterpret_cast<float4*>(
                &out[((size_t)(b * On + oc)) * HW + hw]) = o;
        }
    }
}

// ---------------------------------------------------------------------------
extern "C" void kernel_launch(void* const* d_in, const int* in_sizes, int n_in,
                              void* d_out, int out_size, void* d_ws, size_t ws_size,
                              hipStream_t stream) {
    const float* x    = (const float*)d_in[0];
    const float* pgw  = (const float*)d_in[1];
    const float* pgb  = (const float*)d_in[2];
    const float* w    = (const float*)d_in[3];
    const float* bias = (const float*)d_in[4];
    float* out = (float*)d_out;

    char* wsb = (char*)d_ws;
    unsigned short* pgBF = (unsigned short*)wsb;                 // 24.77 MB
    size_t off = (size_t)PGC * Bn * HW * 2;
    unsigned short* B2   = (unsigned short*)(wsb + off);         // 0.88 MB
    off += (size_t)NP * KSH * 2;
    unsigned short* WB   = (unsigned short*)(wsb + off);         // 0.26 MB
    off += (size_t)128 * KP * 2;
    unsigned short* XTa  = (unsigned short*)(wsb + off);         // 9.01 MB
    unsigned short* XT   = XTa + (size_t)XGUARD * CP;
    off += (size_t)XALLOC_ROWS * CP * 2;
    unsigned short* S    = (unsigned short*)(wsb + off);         // sampled (tiled)

    const size_t sfull = (size_t)MFULL * KP * 2;                 // 67.1 MB
    int nh;
    if (ws_size >= off + sfull)          nh = 1;   // ~102.1 MB total
    else if (ws_size >= off + sfull / 2) nh = 2;
    else                                 nh = 4;
    const int cnt = MFULL / nh;

    // prep: zero XT + build B2 + WB
    {
        int tot = ZN + B2N + WBN;
        prep_kernel<<<(tot + 255) / 256, 256, 0, stream>>>(pgw, w, XTa, B2, WB);
    }
    // transpose x -> XT (NHWC bf16, 66x66 halo)
    xpose_kernel<<<dim3(Hn, Bn), 256, 0, stream>>>(x, XT);

    // pg conv as 256x128 / BK=64 shift-GEMM (8 waves, T2 swizzle, counted vmcnt)
    pg_shift_kernel<<<dim3(PG_MT, NP / 128), 512, 0, stream>>>(
        XT, B2, pgb, pgBF);

    // deformable sampling (NHWC corner loads) -> tiled S, then main GEMM
    for (int h = 0; h < nh; ++h) {
        sample_kernel<<<dim3(cnt / 256, 126), 256, 0, stream>>>(
            XT, pgBF, S, h * cnt);
        main_gemm_kernel<<<dim3(cnt / 128, 1), 256, 0, stream>>>(
            S, WB, bias, out, h * cnt);
    }
}

// Round 11
// 169.917 us; speedup vs baseline: 1.0986x; 1.0065x over previous
//
#include <hip/hip_runtime.h>
#include <math.h>

#define Bn 8
#define Cn 112
#define Hn 64
#define Wn 64
#define On 112
#define Gn 14
#define PGC 378          // 3*G*K2
#define HW 4096          // 64*64
#define CKW 1008         // C*K2
#define KP 1024          // padded K for main GEMM (sampled layout)
#define NP 384           // padded N (oc) for pg GEMM
#define KSH 1152         // shift-GEMM K = 9 taps * 128 padded channels
#define CP 128           // padded channel count
#define MFULL 32768
#define XROW 4356        // 66*66 rows per batch in XT
#define PG_MT 273        // M-tiles of 128
#define MPAD (PG_MT * 128)                 // 34944
#define XGUARD 67
#define XALLOC_ROWS (XGUARD + MPAD + XGUARD + 2)   // 35080

typedef __attribute__((ext_vector_type(8))) short bf16x8;
typedef __attribute__((ext_vector_type(4))) float f32x4;

__device__ __forceinline__ unsigned short f2bf(float f) {
    union { float f; unsigned int u; } v; v.f = f;
    unsigned int r = v.u + 0x7fffu + ((v.u >> 16) & 1u);
    return (unsigned short)(r >> 16);
}
__device__ __forceinline__ float bf2f(unsigned short u) {
    union { unsigned int u; float f; } v; v.u = ((unsigned int)u) << 16;
    return v.f;
}
__device__ __forceinline__ float bflo(unsigned int u) {
    union { unsigned int u; float f; } v; v.u = u << 16; return v.f;
}
__device__ __forceinline__ float bfhi(unsigned int u) {
    union { unsigned int u; float f; } v; v.u = u & 0xffff0000u; return v.f;
}
__device__ __forceinline__ void gload_lds16(const void* g, void* l) {
    __builtin_amdgcn_global_load_lds(
        (const __attribute__((address_space(1))) unsigned int*)g,
        (__attribute__((address_space(3))) unsigned int*)l, 16, 0, 0);
}

// ---------------------------------------------------------------------------
// prep (merged): zero XT alloc | B2 shift-layout [384][1152] | WB [128][1024]
// ---------------------------------------------------------------------------
#define ZN (XALLOC_ROWS * CP / 8)
#define B2N (NP * KSH)
#define WBN (128 * KP)
__global__ __launch_bounds__(256) void prep_kernel(
    const float* __restrict__ pgw, const float* __restrict__ w,
    unsigned short* __restrict__ XTa, unsigned short* __restrict__ B2,
    unsigned short* __restrict__ WB)
{
    int t = blockIdx.x * 256 + threadIdx.x;
    if (t < ZN) {
        const uint4 z = {0, 0, 0, 0};
        reinterpret_cast<uint4*>(XTa)[t] = z;
        return;
    }
    t -= ZN;
    if (t < B2N) {
        int oc = t / KSH, ckk = t - oc * KSH;
        int k = ckk >> 7, c = ckk & 127;
        float v = (c < Cn && oc < PGC) ? pgw[(size_t)oc * CKW + c * 9 + k] : 0.f;
        B2[t] = f2bf(v);
        return;
    }
    t -= B2N;
    if (t < WBN) {
        int oc = t >> 10, ck = t & 1023;
        float v = 0.f;
        if (oc < On && ck < CKW) {
            int g = ck / 72, r = ck % 72;
            int k = r >> 3, cc = r & 7;
            v = w[(size_t)oc * CKW + (g * 8 + cc) * 9 + k];
        }
        WB[t] = f2bf(v);
    }
}

// ---------------------------------------------------------------------------
// xpose: x NCHW f32 -> XT bf16 rows [(b*66 + y+1)*66 + x+1][128]
// ---------------------------------------------------------------------------
__global__ __launch_bounds__(256) void xpose_kernel(
    const float* __restrict__ x, unsigned short* __restrict__ XT)
{
    __shared__ unsigned short lds[64][136];

    const int tid = threadIdx.x;
    const int y = blockIdx.x, b = blockIdx.y;
    const int xx = tid & 63, cw = tid >> 6;

    const float* xb = x + (size_t)b * Cn * HW + y * 64;
    #pragma unroll
    for (int p = 0; p < 28; ++p) {
        int c = p * 4 + cw;
        lds[xx][c] = f2bf(xb[(size_t)c * HW + xx]);
        if (p < 4) lds[xx][112 + p * 4 + cw] = 0;
    }
    __syncthreads();

    const int rx = tid >> 2, seg = tid & 3;
    size_t row = (size_t)(b * 66 + y + 1) * 66 + rx + 1;
    unsigned short* dst = XT + row * CP + seg * 32;
    const unsigned short* srcr = &lds[rx][seg * 32];
    #pragma unroll
    for (int j = 0; j < 4; ++j)
        *reinterpret_cast<uint4*>(dst + j * 8) =
            *reinterpret_cast<const uint4*>(srcr + j * 8);
}

// ---------------------------------------------------------------------------
// pg shift-GEMM v3: 128x128 tile, BK=64 (18 K-steps), 4 waves (2M x 2N),
// per-wave 64x64 output (4x4 frags, 32 MFMA/step).
// T2 XOR-swizzled LDS; staging = linear-dest global_load_lds with
// inverse-swizzled per-lane GLOBAL source (rule #21).
// Double-buffered, counted vmcnt(8), 2 barriers/step, setprio around MFMA.
// LDS = 64 KB -> 2 blocks/CU (inter-block stall hiding, m114).
// ---------------------------------------------------------------------------
__global__ __launch_bounds__(256) void pg_shift_kernel(
    const unsigned short* __restrict__ XT, const unsigned short* __restrict__ B2,
    const float* __restrict__ pgb, unsigned short* __restrict__ pgBF)
{
    __shared__ __align__(16) unsigned short Asm[2][128 * 64];   // 32 KB
    __shared__ __align__(16) unsigned short Bsm[2][128 * 64];   // 32 KB

    const int tid  = threadIdx.x;
    const int lane = tid & 63;
    const int w    = tid >> 6;          // 0..3
    const int wr   = w >> 1;            // 0..1  (M)
    const int wc   = w & 1;             // 0..1  (N)
    const int m0   = blockIdx.x * 128;
    const int n0   = blockIdx.y * 128;
    const int fr   = lane & 15, fq = lane >> 4;
    const int lr8  = lane >> 3;         // 0..7 row-in-group
    const int lc8  = lane & 7;          // 0..7 chunk

    f32x4 acc[4][4] = {};

    // stage one K-tile (exactly 8 global_load_lds per lane: 4 A + 4 B)
    auto stage = [&](int buf, int kt) {
        const int tap = kt >> 1;
        const int shift = (tap / 3 - 1) * 66 + (tap % 3 - 1);
        const int c0 = (kt & 1) * 64;
        #pragma unroll
        for (int s = 0; s < 4; ++s) {
            int r = w * 32 + s * 8 + lr8;
            int cl = lc8 ^ (r & 7);
            gload_lds16(&XT[(size_t)(m0 + r + shift) * CP + c0 + cl * 8],
                        &Asm[buf][(w * 32 + s * 8) * 64]);
            gload_lds16(&B2[(size_t)(n0 + r) * KSH + kt * 64 + cl * 8],
                        &Bsm[buf][(w * 32 + s * 8) * 64]);
        }
    };

    stage(0, 0);
    int cur = 0;
    for (int kt = 0; kt < 18; ++kt) {
        __builtin_amdgcn_s_barrier();          // prev-iter reads of buf[cur^1] done
        asm volatile("" ::: "memory");
        if (kt + 1 < 18) {
            stage(cur ^ 1, kt + 1);
            asm volatile("s_waitcnt vmcnt(8)" ::: "memory");
        } else {
            asm volatile("s_waitcnt vmcnt(0)" ::: "memory");
        }
        __builtin_amdgcn_s_barrier();          // buf[cur] fully staged (all waves)
        asm volatile("" ::: "memory");

        const char* Ab = (const char*)Asm[cur];
        const char* Bb = (const char*)Bsm[cur];
        bf16x8 a[2][4], b[2][4];
        #pragma unroll
        for (int ks = 0; ks < 2; ++ks) {
            const int csw = ((ks << 2) + fq);
            #pragma unroll
            for (int mi = 0; mi < 4; ++mi) {
                int r = wr * 64 + mi * 16 + fr;
                a[ks][mi] = *reinterpret_cast<const bf16x8*>(
                    Ab + r * 128 + ((csw ^ (fr & 7)) << 4));
            }
            #pragma unroll
            for (int ni = 0; ni < 4; ++ni) {
                int r = wc * 64 + ni * 16 + fr;
                b[ks][ni] = *reinterpret_cast<const bf16x8*>(
                    Bb + r * 128 + ((csw ^ (fr & 7)) << 4));
            }
        }
        __builtin_amdgcn_s_setprio(1);
        #pragma unroll
        for (int ks = 0; ks < 2; ++ks)
            #pragma unroll
            for (int mi = 0; mi < 4; ++mi)
                #pragma unroll
                for (int ni = 0; ni < 4; ++ni)
                    acc[mi][ni] = __builtin_amdgcn_mfma_f32_16x16x32_bf16(
                        a[ks][mi], b[ks][ni], acc[mi][ni], 0, 0, 0);
        __builtin_amdgcn_s_setprio(0);
        cur ^= 1;
    }

    #pragma unroll
    for (int ni = 0; ni < 4; ++ni) {
        int oc = n0 + wc * 64 + ni * 16 + fr;
        if (oc >= PGC) continue;
        float bias = pgb[oc];
        #pragma unroll
        for (int mi = 0; mi < 4; ++mi) {
            int pxq = m0 + wr * 64 + mi * 16 + fq * 4;
            #pragma unroll
            for (int r = 0; r < 4; ++r) {
                int pxd = pxq + r;
                if (pxd >= Bn * XROW) continue;
                int bb = pxd / XROW;
                int rem = pxd - bb * XROW;
                int yy = rem / 66 - 1;
                int xx = rem - (yy + 1) * 66 - 1;
                if ((unsigned)yy < 64u && (unsigned)xx < 64u)
                    pgBF[((size_t)(bb * PGC + oc)) * HW + yy * 64 + xx] =
                        f2bf(acc[mi][ni][r] + bias);
            }
        }
    }
}

// ---------------------------------------------------------------------------
// sample: thread = (pixel, (g,k) tap); gathers 4 bf16 corner rows (16B each)
// from NHWC XT; writes 16B into tiled S [px/128][ck/8][px%128][8ck].
// ---------------------------------------------------------------------------
__global__ __launch_bounds__(256) void sample_kernel(
    const unsigned short* __restrict__ XT, const unsigned short* __restrict__ pg,
    unsigned short* __restrict__ S, int px_base)
{
    const int pxl = blockIdx.x * 256 + threadIdx.x;
    const int gk  = blockIdx.y;              // 0..125
    const int g = gk / 9, k = gk - 9 * g;
    const int pxg = px_base + pxl;
    const int b = pxg >> 12, hw = pxg & 4095;
    const int y = hw >> 6, xc = hw & 63;
    const int pblk = pxl >> 7, prem = pxl & 127;

    if (gk == 0) {   // zero K-pad blocks cb = 126, 127
        const uint4 z = {0, 0, 0, 0};
        *reinterpret_cast<uint4*>(
            &S[(((size_t)pblk * 128 + 126) * 128 + prem) * 8]) = z;
        *reinterpret_cast<uint4*>(
            &S[(((size_t)pblk * 128 + 127) * 128 + prem) * 8]) = z;
    }

    const unsigned short* pgb = pg + (size_t)b * PGC * HW + hw;
    float dy = bf2f(pgb[(size_t)(18 * g + 2 * k) * HW]);
    float dx = bf2f(pgb[(size_t)(18 * g + 2 * k + 1) * HW]);
    float mv = bf2f(pgb[(size_t)(252 + 9 * g + k) * HW]);
    float m  = 1.f / (1.f + __expf(-mv));

    const int ky = k / 3, kx = k % 3;
    float yf = (float)(y + ky - 1) + dy;
    float xf = (float)(xc + kx - 1) + dx;
    float y0 = floorf(yf), x0 = floorf(xf);
    float wy1 = yf - y0, wx1 = xf - x0;
    float wy0 = 1.f - wy1, wx0 = 1.f - wx1;
    int iy0 = (int)y0, ix0 = (int)x0;
    bool vy0 = (iy0 >= 0) && (iy0 < Hn);
    bool vy1 = (iy0 >= -1) && (iy0 < Hn - 1);
    bool vx0 = (ix0 >= 0) && (ix0 < Wn);
    bool vx1 = (ix0 >= -1) && (ix0 < Wn - 1);
    int cy0 = min(max(iy0, 0), Hn - 1), cy1 = min(max(iy0 + 1, 0), Hn - 1);
    int cx0 = min(max(ix0, 0), Wn - 1), cx1 = min(max(ix0 + 1, 0), Wn - 1);
    float w00 = (vy0 && vx0) ? wy0 * wx0 * m : 0.f;
    float w01 = (vy0 && vx1) ? wy0 * wx1 * m : 0.f;
    float w10 = (vy1 && vx0) ? wy1 * wx0 * m : 0.f;
    float w11 = (vy1 && vx1) ? wy1 * wx1 * m : 0.f;

    const unsigned short* xtb = XT + (size_t)(b * 66) * 66 * CP + g * 8;
    const int r00 = (cy0 + 1) * 66 + cx0 + 1, r01 = (cy0 + 1) * 66 + cx1 + 1;
    const int r10 = (cy1 + 1) * 66 + cx0 + 1, r11 = (cy1 + 1) * 66 + cx1 + 1;
    uint4 q00 = *reinterpret_cast<const uint4*>(xtb + (size_t)r00 * CP);
    uint4 q01 = *reinterpret_cast<const uint4*>(xtb + (size_t)r01 * CP);
    uint4 q10 = *reinterpret_cast<const uint4*>(xtb + (size_t)r10 * CP);
    uint4 q11 = *reinterpret_cast<const uint4*>(xtb + (size_t)r11 * CP);

    unsigned int c00[4] = {q00.x, q00.y, q00.z, q00.w};
    unsigned int c01[4] = {q01.x, q01.y, q01.z, q01.w};
    unsigned int c10[4] = {q10.x, q10.y, q10.z, q10.w};
    unsigned int c11[4] = {q11.x, q11.y, q11.z, q11.w};

    unsigned int pk[4];
    #pragma unroll
    for (int j = 0; j < 4; ++j) {
        float lo = bflo(c00[j]) * w00 + bflo(c01[j]) * w01 +
                   bflo(c10[j]) * w10 + bflo(c11[j]) * w11;
        float hi = bfhi(c00[j]) * w00 + bfhi(c01[j]) * w01 +
                   bfhi(c10[j]) * w10 + bfhi(c11[j]) * w11;
        pk[j] = (unsigned int)f2bf(lo) | ((unsigned int)f2bf(hi) << 16);
    }
    *reinterpret_cast<uint4*>(
        &S[(((size_t)pblk * 128 + gk) * 128 + prem) * 8]) =
        *reinterpret_cast<const uint4*>(pk);
}

// ---------------------------------------------------------------------------
// main GEMM: out[b][oc][hw] = S_tiled[px][ck] * WB[oc][ck] + bias[oc]
// Double-buffered prefetch, counted vmcnt (validated round 9).
// ---------------------------------------------------------------------------
__global__ __launch_bounds__(256) void main_gemm_kernel(
    const unsigned short* __restrict__ S, const unsigned short* __restrict__ WB,
    const float* __restrict__ bias, float* __restrict__ out, int px_base)
{
    __shared__ __align__(16) unsigned short Asm[2][128 * 32];
    __shared__ __align__(16) unsigned short Bsm[2][128 * 32];

    const int tid  = threadIdx.x;
    const int lane = tid & 63;
    const int w    = tid >> 6;
    const int wr   = w >> 1, wc = w & 1;
    const int m0   = blockIdx.x * 128;
    const int fr   = lane & 15, fq = lane >> 4;

    f32x4 acc[4][4] = {};

    const int ldr = lane >> 2;
    const int lq  = lane & 3;
    const int ldc = lq * 8;

    auto stage = [&](int buf, int kt) {
        #pragma unroll
        for (int i = 0; i < 2; ++i) {
            int row = w * 32 + i * 16 + ldr;
            int cb  = kt * 4 + lq;
            gload_lds16(&S[(((size_t)blockIdx.x * 128 + cb) * 128 + row) * 8],
                        &Asm[buf][(w * 32 + i * 16) * 32]);
            gload_lds16(&WB[(size_t)row * KP + kt * 32 + ldc],
                        &Bsm[buf][(w * 32 + i * 16) * 32]);
        }
    };

    stage(0, 0);
    int cur = 0;
    for (int kt = 0; kt < 32; ++kt) {
        if (kt + 1 < 32) {
            stage(cur ^ 1, kt + 1);
            asm volatile("s_waitcnt vmcnt(4)" ::: "memory");
        } else {
            asm volatile("s_waitcnt vmcnt(0)" ::: "memory");
        }
        __builtin_amdgcn_s_barrier();
        asm volatile("" ::: "memory");

        bf16x8 a[4], b[4];
        #pragma unroll
        for (int mi = 0; mi < 4; ++mi)
            a[mi] = *reinterpret_cast<const bf16x8*>(
                &Asm[cur][(wr * 64 + mi * 16 + fr) * 32 + fq * 8]);
        #pragma unroll
        for (int ni = 0; ni < 4; ++ni)
            b[ni] = *reinterpret_cast<const bf16x8*>(
                &Bsm[cur][(wc * 64 + ni * 16 + fr) * 32 + fq * 8]);
        #pragma unroll
        for (int mi = 0; mi < 4; ++mi)
            #pragma unroll
            for (int ni = 0; ni < 4; ++ni)
                acc[mi][ni] = __builtin_amdgcn_mfma_f32_16x16x32_bf16(
                    a[mi], b[ni], acc[mi][ni], 0, 0, 0);

        asm volatile("s_waitcnt lgkmcnt(0)" ::: "memory");
        __builtin_amdgcn_s_barrier();
        asm volatile("" ::: "memory");
        cur ^= 1;
    }

    #pragma unroll
    for (int ni = 0; ni < 4; ++ni) {
        int oc = wc * 64 + ni * 16 + fr;
        if (oc >= On) continue;
        float bv = bias[oc];
        #pragma unroll
        for (int mi = 0; mi < 4; ++mi) {
            int pxl = m0 + wr * 64 + mi * 16 + fq * 4;
            int pxg = px_base + pxl;
            int b = pxg >> 12, hw = pxg & 4095;
            float4 o;
            o.x = acc[mi][ni][0] + bv;
            o.y = acc[mi][ni][1] + bv;
            o.z = acc[mi][ni][2] + bv;
            o.w = acc[mi][ni][3] + bv;
            *reinterpret_cast<float4*>(
                &out[((size_t)(b * On + oc)) * HW + hw]) = o;
        }
    }
}

// ---------------------------------------------------------------------------
extern "C" void kernel_launch(void* const* d_in, const int* in_sizes, int n_in,
                              void* d_out, int out_size, void* d_ws, size_t ws_size,
                              hipStream_t stream) {
    const float* x    = (const float*)d_in[0];
    const float* pgw  = (const float*)d_in[1];
    const float* pgb  = (const float*)d_in[2];
    const float* w    = (const float*)d_in[3];
    const float* bias = (const float*)d_in[4];
    float* out = (float*)d_out;

    char* wsb = (char*)d_ws;
    unsigned short* pgBF = (unsigned short*)wsb;                 // 24.77 MB
    size_t off = (size_t)PGC * Bn * HW * 2;
    unsigned short* B2   = (unsigned short*)(wsb + off);         // 0.88 MB
    off += (size_t)NP * KSH * 2;
    unsigned short* WB   = (unsigned short*)(wsb + off);         // 0.26 MB
    off += (size_t)128 * KP * 2;
    unsigned short* XTa  = (unsigned short*)(wsb + off);         // 8.98 MB
    unsigned short* XT   = XTa + (size_t)XGUARD * CP;
    off += (size_t)XALLOC_ROWS * CP * 2;
    unsigned short* S    = (unsigned short*)(wsb + off);         // sampled (tiled)

    const size_t sfull = (size_t)MFULL * KP * 2;                 // 67.1 MB
    int nh;
    if (ws_size >= off + sfull)          nh = 1;   // ~102 MB total
    else if (ws_size >= off + sfull / 2) nh = 2;
    else                                 nh = 4;
    const int cnt = MFULL / nh;

    // prep: zero XT + build B2 + WB
    {
        int tot = ZN + B2N + WBN;
        prep_kernel<<<(tot + 255) / 256, 256, 0, stream>>>(pgw, w, XTa, B2, WB);
    }
    // transpose x -> XT (NHWC bf16, 66x66 halo)
    xpose_kernel<<<dim3(Hn, Bn), 256, 0, stream>>>(x, XT);

    // pg conv as 128x128 / BK=64 shift-GEMM (4 waves, T2 swizzle, 2 blocks/CU)
    pg_shift_kernel<<<dim3(PG_MT, NP / 128), 256, 0, stream>>>(
        XT, B2, pgb, pgBF);

    // deformable sampling (NHWC corner loads) -> tiled S, then main GEMM
    for (int h = 0; h < nh; ++h) {
        sample_kernel<<<dim3(cnt / 256, 126), 256, 0, stream>>>(
            XT, pgBF, S, h * cnt);
        main_gemm_kernel<<<dim3(cnt / 128, 1), 256, 0, stream>>>(
            S, WB, bias, out, h * cnt);
    }
}

// Round 12
// 161.953 us; speedup vs baseline: 1.1526x; 1.0492x over previous
//
#include <hip/hip_runtime.h>
#include <math.h>

#define Bn 8
#define Cn 112
#define Hn 64
#define Wn 64
#define On 112
#define Gn 14
#define PGC 378          // 3*G*K2
#define HW 4096          // 64*64
#define CKW 1008         // C*K2
#define KP 1024          // padded K for main GEMM (sampled layout)
#define NP 384           // padded N (oc) for pg GEMM
#define KSH 1152         // shift-GEMM K = 9 taps * 128 padded channels
#define CP 128           // padded channel count
#define MFULL 32768
#define XROW 4356        // 66*66 rows per batch in XT
#define PG_MT 137        // M-tiles of 256
#define MPAD (PG_MT * 256)                 // 35072
#define XGUARD 67
#define XALLOC_ROWS (XGUARD + MPAD + XGUARD + 2)   // 35208

typedef __attribute__((ext_vector_type(8))) short bf16x8;
typedef __attribute__((ext_vector_type(4))) float f32x4;

__device__ __forceinline__ unsigned short f2bf(float f) {
    union { float f; unsigned int u; } v; v.f = f;
    unsigned int r = v.u + 0x7fffu + ((v.u >> 16) & 1u);
    return (unsigned short)(r >> 16);
}
__device__ __forceinline__ float bf2f(unsigned short u) {
    union { unsigned int u; float f; } v; v.u = ((unsigned int)u) << 16;
    return v.f;
}
__device__ __forceinline__ float bflo(unsigned int u) {
    union { unsigned int u; float f; } v; v.u = u << 16; return v.f;
}
__device__ __forceinline__ float bfhi(unsigned int u) {
    union { unsigned int u; float f; } v; v.u = u & 0xffff0000u; return v.f;
}
__device__ __forceinline__ void gload_lds16(const void* g, void* l) {
    __builtin_amdgcn_global_load_lds(
        (const __attribute__((address_space(1))) unsigned int*)g,
        (__attribute__((address_space(3))) unsigned int*)l, 16, 0, 0);
}

// ---------------------------------------------------------------------------
// prep (merged): zero XT alloc | B2 shift-layout [384][1152] | WB [128][1024]
// ---------------------------------------------------------------------------
#define ZN (XALLOC_ROWS * CP / 8)
#define B2N (NP * KSH)
#define WBN (128 * KP)
__global__ __launch_bounds__(256) void prep_kernel(
    const float* __restrict__ pgw, const float* __restrict__ w,
    unsigned short* __restrict__ XTa, unsigned short* __restrict__ B2,
    unsigned short* __restrict__ WB)
{
    int t = blockIdx.x * 256 + threadIdx.x;
    if (t < ZN) {
        const uint4 z = {0, 0, 0, 0};
        reinterpret_cast<uint4*>(XTa)[t] = z;
        return;
    }
    t -= ZN;
    if (t < B2N) {
        int oc = t / KSH, ckk = t - oc * KSH;
        int k = ckk >> 7, c = ckk & 127;
        float v = (c < Cn && oc < PGC) ? pgw[(size_t)oc * CKW + c * 9 + k] : 0.f;
        B2[t] = f2bf(v);
        return;
    }
    t -= B2N;
    if (t < WBN) {
        int oc = t >> 10, ck = t & 1023;
        float v = 0.f;
        if (oc < On && ck < CKW) {
            int g = ck / 72, r = ck % 72;
            int k = r >> 3, cc = r & 7;
            v = w[(size_t)oc * CKW + (g * 8 + cc) * 9 + k];
        }
        WB[t] = f2bf(v);
    }
}

// ---------------------------------------------------------------------------
// xpose: x NCHW f32 -> XT bf16 rows [(b*66 + y+1)*66 + x+1][128]
// ---------------------------------------------------------------------------
__global__ __launch_bounds__(256) void xpose_kernel(
    const float* __restrict__ x, unsigned short* __restrict__ XT)
{
    __shared__ unsigned short lds[64][136];

    const int tid = threadIdx.x;
    const int y = blockIdx.x, b = blockIdx.y;
    const int xx = tid & 63, cw = tid >> 6;

    const float* xb = x + (size_t)b * Cn * HW + y * 64;
    #pragma unroll
    for (int p = 0; p < 28; ++p) {
        int c = p * 4 + cw;
        lds[xx][c] = f2bf(xb[(size_t)c * HW + xx]);
        if (p < 4) lds[xx][112 + p * 4 + cw] = 0;
    }
    __syncthreads();

    const int rx = tid >> 2, seg = tid & 3;
    size_t row = (size_t)(b * 66 + y + 1) * 66 + rx + 1;
    unsigned short* dst = XT + row * CP + seg * 32;
    const unsigned short* srcr = &lds[rx][seg * 32];
    #pragma unroll
    for (int j = 0; j < 4; ++j)
        *reinterpret_cast<uint4*>(dst + j * 8) =
            *reinterpret_cast<const uint4*>(srcr + j * 8);
}

// ---------------------------------------------------------------------------
// pg shift-GEMM v4: 256x128 tile, BK=64 (18 K-steps), 8 waves (4M x 2N),
// per-wave 64x64 (4x4 frags, 32 MFMA/step).  T2 XOR-swizzled LDS.
// 3-stage pipeline: tile t+2 issued during step t; top-of-step
// s_waitcnt vmcnt(6) (one tile always in flight across the barrier);
// ONE barrier per step; ds_read || stage || MFMA inside the step.
// ---------------------------------------------------------------------------
__global__ __launch_bounds__(512, 1) void pg_shift_kernel(
    const unsigned short* __restrict__ XT, const unsigned short* __restrict__ B2,
    const float* __restrict__ pgb, unsigned short* __restrict__ pgBF)
{
    __shared__ __align__(16) unsigned short Asm[3][256 * 64];   // 96 KB
    __shared__ __align__(16) unsigned short Bsm[3][128 * 64];   // 48 KB

    const int tid  = threadIdx.x;
    const int lane = tid & 63;
    const int w    = tid >> 6;          // 0..7
    const int wr   = w >> 1;            // 0..3  (M)
    const int wc   = w & 1;             // 0..1  (N)
    const int m0   = blockIdx.x * 256;
    const int n0   = blockIdx.y * 128;
    const int fr   = lane & 15, fq = lane >> 4;
    const int lr8  = lane >> 3;         // 0..7 row-in-span
    const int lc8  = lane & 7;          // 0..7 chunk

    f32x4 acc[4][4] = {};

    // stage one K-tile (exactly 6 global_load_lds per lane: 4 A + 2 B)
    auto stage = [&](int buf, int kt) {
        const int tap = kt >> 1;
        const int shift = (tap / 3 - 1) * 66 + (tap % 3 - 1);
        const int c0 = (kt & 1) * 64;
        #pragma unroll
        for (int s = 0; s < 4; ++s) {
            int r = w * 32 + s * 8 + lr8;
            int cl = lc8 ^ (r & 7);
            gload_lds16(&XT[(size_t)(m0 + r + shift) * CP + c0 + cl * 8],
                        &Asm[buf][(w * 32 + s * 8) * 64]);
        }
        #pragma unroll
        for (int s = 0; s < 2; ++s) {
            int r = w * 16 + s * 8 + lr8;
            int cl = lc8 ^ (r & 7);
            gload_lds16(&B2[(size_t)(n0 + r) * KSH + kt * 64 + cl * 8],
                        &Bsm[buf][(w * 16 + s * 8) * 64]);
        }
    };

    stage(0, 0);
    stage(1, 1);
    for (int kt = 0; kt < 18; ++kt) {
        // my tile-kt loads landed (one newer tile stays in flight) ...
        if (kt < 16) asm volatile("s_waitcnt vmcnt(6)" ::: "memory");
        else         asm volatile("s_waitcnt vmcnt(0)" ::: "memory");
        // ... and everyone's landed; also all step-(kt-1) reads of the
        // buffer we are about to overwrite are complete.
        __builtin_amdgcn_s_barrier();
        asm volatile("" ::: "memory");

        const int cur = kt % 3;
        const char* Ab = (const char*)Asm[cur];
        const char* Bb = (const char*)Bsm[cur];
        bf16x8 a[2][4], b[2][4];
        #pragma unroll
        for (int ks = 0; ks < 2; ++ks) {
            const int csw = ((ks << 2) + fq);
            #pragma unroll
            for (int mi = 0; mi < 4; ++mi) {
                int r = wr * 64 + mi * 16 + fr;
                a[ks][mi] = *reinterpret_cast<const bf16x8*>(
                    Ab + r * 128 + ((csw ^ (fr & 7)) << 4));
            }
            #pragma unroll
            for (int ni = 0; ni < 4; ++ni) {
                int r = wc * 64 + ni * 16 + fr;
                b[ks][ni] = *reinterpret_cast<const bf16x8*>(
                    Bb + r * 128 + ((csw ^ (fr & 7)) << 4));
            }
        }
        if (kt + 2 < 18) stage((kt + 2) % 3, kt + 2);

        __builtin_amdgcn_s_setprio(1);
        #pragma unroll
        for (int ks = 0; ks < 2; ++ks)
            #pragma unroll
            for (int mi = 0; mi < 4; ++mi)
                #pragma unroll
                for (int ni = 0; ni < 4; ++ni)
                    acc[mi][ni] = __builtin_amdgcn_mfma_f32_16x16x32_bf16(
                        a[ks][mi], b[ks][ni], acc[mi][ni], 0, 0, 0);
        __builtin_amdgcn_s_setprio(0);
    }

    #pragma unroll
    for (int ni = 0; ni < 4; ++ni) {
        int oc = n0 + wc * 64 + ni * 16 + fr;
        if (oc >= PGC) continue;
        float bias = pgb[oc];
        #pragma unroll
        for (int mi = 0; mi < 4; ++mi) {
            int pxq = m0 + wr * 64 + mi * 16 + fq * 4;
            #pragma unroll
            for (int r = 0; r < 4; ++r) {
                int pxd = pxq + r;
                if (pxd >= Bn * XROW) continue;
                int bb = pxd / XROW;
                int rem = pxd - bb * XROW;
                int yy = rem / 66 - 1;
                int xx = rem - (yy + 1) * 66 - 1;
                if ((unsigned)yy < 64u && (unsigned)xx < 64u)
                    pgBF[((size_t)(bb * PGC + oc)) * HW + yy * 64 + xx] =
                        f2bf(acc[mi][ni][r] + bias);
            }
        }
    }
}

// ---------------------------------------------------------------------------
// sample: thread = (pixel, (g,k) tap); gathers 4 bf16 corner rows (16B each)
// from NHWC XT; writes 16B into tiled S [px/128][ck/8][px%128][8ck].
// ---------------------------------------------------------------------------
__global__ __launch_bounds__(256) void sample_kernel(
    const unsigned short* __restrict__ XT, const unsigned short* __restrict__ pg,
    unsigned short* __restrict__ S, int px_base)
{
    const int pxl = blockIdx.x * 256 + threadIdx.x;
    const int gk  = blockIdx.y;              // 0..125
    const int g = gk / 9, k = gk - 9 * g;
    const int pxg = px_base + pxl;
    const int b = pxg >> 12, hw = pxg & 4095;
    const int y = hw >> 6, xc = hw & 63;
    const int pblk = pxl >> 7, prem = pxl & 127;

    if (gk == 0) {   // zero K-pad blocks cb = 126, 127
        const uint4 z = {0, 0, 0, 0};
        *reinterpret_cast<uint4*>(
            &S[(((size_t)pblk * 128 + 126) * 128 + prem) * 8]) = z;
        *reinterpret_cast<uint4*>(
            &S[(((size_t)pblk * 128 + 127) * 128 + prem) * 8]) = z;
    }

    const unsigned short* pgb = pg + (size_t)b * PGC * HW + hw;
    float dy = bf2f(pgb[(size_t)(18 * g + 2 * k) * HW]);
    float dx = bf2f(pgb[(size_t)(18 * g + 2 * k + 1) * HW]);
    float mv = bf2f(pgb[(size_t)(252 + 9 * g + k) * HW]);
    float m  = 1.f / (1.f + __expf(-mv));

    const int ky = k / 3, kx = k % 3;
    float yf = (float)(y + ky - 1) + dy;
    float xf = (float)(xc + kx - 1) + dx;
    float y0 = floorf(yf), x0 = floorf(xf);
    float wy1 = yf - y0, wx1 = xf - x0;
    float wy0 = 1.f - wy1, wx0 = 1.f - wx1;
    int iy0 = (int)y0, ix0 = (int)x0;
    bool vy0 = (iy0 >= 0) && (iy0 < Hn);
    bool vy1 = (iy0 >= -1) && (iy0 < Hn - 1);
    bool vx0 = (ix0 >= 0) && (ix0 < Wn);
    bool vx1 = (ix0 >= -1) && (ix0 < Wn - 1);
    int cy0 = min(max(iy0, 0), Hn - 1), cy1 = min(max(iy0 + 1, 0), Hn - 1);
    int cx0 = min(max(ix0, 0), Wn - 1), cx1 = min(max(ix0 + 1, 0), Wn - 1);
    float w00 = (vy0 && vx0) ? wy0 * wx0 * m : 0.f;
    float w01 = (vy0 && vx1) ? wy0 * wx1 * m : 0.f;
    float w10 = (vy1 && vx0) ? wy1 * wx0 * m : 0.f;
    float w11 = (vy1 && vx1) ? wy1 * wx1 * m : 0.f;

    const unsigned short* xtb = XT + (size_t)(b * 66) * 66 * CP + g * 8;
    const int r00 = (cy0 + 1) * 66 + cx0 + 1, r01 = (cy0 + 1) * 66 + cx1 + 1;
    const int r10 = (cy1 + 1) * 66 + cx0 + 1, r11 = (cy1 + 1) * 66 + cx1 + 1;
    uint4 q00 = *reinterpret_cast<const uint4*>(xtb + (size_t)r00 * CP);
    uint4 q01 = *reinterpret_cast<const uint4*>(xtb + (size_t)r01 * CP);
    uint4 q10 = *reinterpret_cast<const uint4*>(xtb + (size_t)r10 * CP);
    uint4 q11 = *reinterpret_cast<const uint4*>(xtb + (size_t)r11 * CP);

    unsigned int c00[4] = {q00.x, q00.y, q00.z, q00.w};
    unsigned int c01[4] = {q01.x, q01.y, q01.z, q01.w};
    unsigned int c10[4] = {q10.x, q10.y, q10.z, q10.w};
    unsigned int c11[4] = {q11.x, q11.y, q11.z, q11.w};

    unsigned int pk[4];
    #pragma unroll
    for (int j = 0; j < 4; ++j) {
        float lo = bflo(c00[j]) * w00 + bflo(c01[j]) * w01 +
                   bflo(c10[j]) * w10 + bflo(c11[j]) * w11;
        float hi = bfhi(c00[j]) * w00 + bfhi(c01[j]) * w01 +
                   bfhi(c10[j]) * w10 + bfhi(c11[j]) * w11;
        pk[j] = (unsigned int)f2bf(lo) | ((unsigned int)f2bf(hi) << 16);
    }
    *reinterpret_cast<uint4*>(
        &S[(((size_t)pblk * 128 + gk) * 128 + prem) * 8]) =
        *reinterpret_cast<const uint4*>(pk);
}

// ---------------------------------------------------------------------------
// main GEMM: out[b][oc][hw] = S_tiled[px][ck] * WB[oc][ck] + bias[oc]
// Double-buffered prefetch, counted vmcnt (validated round 9).
// ---------------------------------------------------------------------------
__global__ __launch_bounds__(256) void main_gemm_kernel(
    const unsigned short* __restrict__ S, const unsigned short* __restrict__ WB,
    const float* __restrict__ bias, float* __restrict__ out, int px_base)
{
    __shared__ __align__(16) unsigned short Asm[2][128 * 32];
    __shared__ __align__(16) unsigned short Bsm[2][128 * 32];

    const int tid  = threadIdx.x;
    const int lane = tid & 63;
    const int w    = tid >> 6;
    const int wr   = w >> 1, wc = w & 1;
    const int m0   = blockIdx.x * 128;
    const int fr   = lane & 15, fq = lane >> 4;

    f32x4 acc[4][4] = {};

    const int ldr = lane >> 2;
    const int lq  = lane & 3;
    const int ldc = lq * 8;

    auto stage = [&](int buf, int kt) {
        #pragma unroll
        for (int i = 0; i < 2; ++i) {
            int row = w * 32 + i * 16 + ldr;
            int cb  = kt * 4 + lq;
            gload_lds16(&S[(((size_t)blockIdx.x * 128 + cb) * 128 + row) * 8],
                        &Asm[buf][(w * 32 + i * 16) * 32]);
            gload_lds16(&WB[(size_t)row * KP + kt * 32 + ldc],
                        &Bsm[buf][(w * 32 + i * 16) * 32]);
        }
    };

    stage(0, 0);
    int cur = 0;
    for (int kt = 0; kt < 32; ++kt) {
        if (kt + 1 < 32) {
            stage(cur ^ 1, kt + 1);
            asm volatile("s_waitcnt vmcnt(4)" ::: "memory");
        } else {
            asm volatile("s_waitcnt vmcnt(0)" ::: "memory");
        }
        __builtin_amdgcn_s_barrier();
        asm volatile("" ::: "memory");

        bf16x8 a[4], b[4];
        #pragma unroll
        for (int mi = 0; mi < 4; ++mi)
            a[mi] = *reinterpret_cast<const bf16x8*>(
                &Asm[cur][(wr * 64 + mi * 16 + fr) * 32 + fq * 8]);
        #pragma unroll
        for (int ni = 0; ni < 4; ++ni)
            b[ni] = *reinterpret_cast<const bf16x8*>(
                &Bsm[cur][(wc * 64 + ni * 16 + fr) * 32 + fq * 8]);
        #pragma unroll
        for (int mi = 0; mi < 4; ++mi)
            #pragma unroll
            for (int ni = 0; ni < 4; ++ni)
                acc[mi][ni] = __builtin_amdgcn_mfma_f32_16x16x32_bf16(
                    a[mi], b[ni], acc[mi][ni], 0, 0, 0);

        asm volatile("s_waitcnt lgkmcnt(0)" ::: "memory");
        __builtin_amdgcn_s_barrier();
        asm volatile("" ::: "memory");
        cur ^= 1;
    }

    #pragma unroll
    for (int ni = 0; ni < 4; ++ni) {
        int oc = wc * 64 + ni * 16 + fr;
        if (oc >= On) continue;
        float bv = bias[oc];
        #pragma unroll
        for (int mi = 0; mi < 4; ++mi) {
            int pxl = m0 + wr * 64 + mi * 16 + fq * 4;
            int pxg = px_base + pxl;
            int b = pxg >> 12, hw = pxg & 4095;
            float4 o;
            o.x = acc[mi][ni][0] + bv;
            o.y = acc[mi][ni][1] + bv;
            o.z = acc[mi][ni][2] + bv;
            o.w = acc[mi][ni][3] + bv;
            *reinterpret_cast<float4*>(
                &out[((size_t)(b * On + oc)) * HW + hw]) = o;
        }
    }
}

// ---------------------------------------------------------------------------
extern "C" void kernel_launch(void* const* d_in, const int* in_sizes, int n_in,
                              void* d_out, int out_size, void* d_ws, size_t ws_size,
                              hipStream_t stream) {
    const float* x    = (const float*)d_in[0];
    const float* pgw  = (const float*)d_in[1];
    const float* pgb  = (const float*)d_in[2];
    const float* w    = (const float*)d_in[3];
    const float* bias = (const float*)d_in[4];
    float* out = (float*)d_out;

    char* wsb = (char*)d_ws;
    unsigned short* pgBF = (unsigned short*)wsb;                 // 24.77 MB
    size_t off = (size_t)PGC * Bn * HW * 2;
    unsigned short* B2   = (unsigned short*)(wsb + off);         // 0.88 MB
    off += (size_t)NP * KSH * 2;
    unsigned short* WB   = (unsigned short*)(wsb + off);         // 0.26 MB
    off += (size_t)128 * KP * 2;
    unsigned short* XTa  = (unsigned short*)(wsb + off);         // 9.01 MB
    unsigned short* XT   = XTa + (size_t)XGUARD * CP;
    off += (size_t)XALLOC_ROWS * CP * 2;
    unsigned short* S    = (unsigned short*)(wsb + off);         // sampled (tiled)

    const size_t sfull = (size_t)MFULL * KP * 2;                 // 67.1 MB
    int nh;
    if (ws_size >= off + sfull)          nh = 1;   // ~102 MB total
    else if (ws_size >= off + sfull / 2) nh = 2;
    else                                 nh = 4;
    const int cnt = MFULL / nh;

    // prep: zero XT + build B2 + WB
    {
        int tot = ZN + B2N + WBN;
        prep_kernel<<<(tot + 255) / 256, 256, 0, stream>>>(pgw, w, XTa, B2, WB);
    }
    // transpose x -> XT (NHWC bf16, 66x66 halo)
    xpose_kernel<<<dim3(Hn, Bn), 256, 0, stream>>>(x, XT);

    // pg conv: 256x128/BK=64, 8 waves, T2 swizzle, 3-stage pipeline
    pg_shift_kernel<<<dim3(PG_MT, NP / 128), 512, 0, stream>>>(
        XT, B2, pgb, pgBF);

    // deformable sampling (NHWC corner loads) -> tiled S, then main GEMM
    for (int h = 0; h < nh; ++h) {
        sample_kernel<<<dim3(cnt / 256, 126), 256, 0, stream>>>(
            XT, pgBF, S, h * cnt);
        main_gemm_kernel<<<dim3(cnt / 128, 1), 256, 0, stream>>>(
            S, WB, bias, out, h * cnt);
    }
}

// Round 13
// 160.586 us; speedup vs baseline: 1.1624x; 1.0085x over previous
//
#include <hip/hip_runtime.h>
#include <math.h>

#define Bn 8
#define Cn 112
#define Hn 64
#define Wn 64
#define On 112
#define Gn 14
#define PGC 378          // 3*G*K2
#define HW 4096          // 64*64
#define CKW 1008         // C*K2
#define KP 1024          // padded K for main GEMM (sampled layout)
#define NP 384           // padded N (oc) for pg GEMM
#define KSH 1152         // shift-GEMM K = 9 taps * 128 padded channels
#define CP 128           // padded channel count
#define MFULL 32768
#define XROW 4356        // 66*66 rows per batch in XT
#define PG_MT 137        // M-tiles of 256
#define MPAD (PG_MT * 256)                 // 35072
#define XGUARD 67
#define XALLOC_ROWS (XGUARD + MPAD + XGUARD + 2)   // 35208

typedef __attribute__((ext_vector_type(8))) short bf16x8;
typedef __attribute__((ext_vector_type(4))) float f32x4;

__device__ __forceinline__ unsigned short f2bf(float f) {
    union { float f; unsigned int u; } v; v.f = f;
    unsigned int r = v.u + 0x7fffu + ((v.u >> 16) & 1u);
    return (unsigned short)(r >> 16);
}
__device__ __forceinline__ float bf2f(unsigned short u) {
    union { unsigned int u; float f; } v; v.u = ((unsigned int)u) << 16;
    return v.f;
}
__device__ __forceinline__ float bflo(unsigned int u) {
    union { unsigned int u; float f; } v; v.u = u << 16; return v.f;
}
__device__ __forceinline__ float bfhi(unsigned int u) {
    union { unsigned int u; float f; } v; v.u = u & 0xffff0000u; return v.f;
}
__device__ __forceinline__ void gload_lds16(const void* g, void* l) {
    __builtin_amdgcn_global_load_lds(
        (const __attribute__((address_space(1))) unsigned int*)g,
        (__attribute__((address_space(3))) unsigned int*)l, 16, 0, 0);
}

// ---------------------------------------------------------------------------
// prep (merged): zero XT alloc | B2 shift-layout [384][1152] | WB [128][1024]
// ---------------------------------------------------------------------------
#define ZN (XALLOC_ROWS * CP / 8)
#define B2N (NP * KSH)
#define WBN (128 * KP)
__global__ __launch_bounds__(256) void prep_kernel(
    const float* __restrict__ pgw, const float* __restrict__ w,
    unsigned short* __restrict__ XTa, unsigned short* __restrict__ B2,
    unsigned short* __restrict__ WB)
{
    int t = blockIdx.x * 256 + threadIdx.x;
    if (t < ZN) {
        const uint4 z = {0, 0, 0, 0};
        reinterpret_cast<uint4*>(XTa)[t] = z;
        return;
    }
    t -= ZN;
    if (t < B2N) {
        int oc = t / KSH, ckk = t - oc * KSH;
        int k = ckk >> 7, c = ckk & 127;
        float v = (c < Cn && oc < PGC) ? pgw[(size_t)oc * CKW + c * 9 + k] : 0.f;
        B2[t] = f2bf(v);
        return;
    }
    t -= B2N;
    if (t < WBN) {
        int oc = t >> 10, ck = t & 1023;
        float v = 0.f;
        if (oc < On && ck < CKW) {
            int g = ck / 72, r = ck % 72;
            int k = r >> 3, cc = r & 7;
            v = w[(size_t)oc * CKW + (g * 8 + cc) * 9 + k];
        }
        WB[t] = f2bf(v);
    }
}

// ---------------------------------------------------------------------------
// xpose: x NCHW f32 -> XT bf16 rows [(b*66 + y+1)*66 + x+1][128]
// ---------------------------------------------------------------------------
__global__ __launch_bounds__(256) void xpose_kernel(
    const float* __restrict__ x, unsigned short* __restrict__ XT)
{
    __shared__ unsigned short lds[64][136];

    const int tid = threadIdx.x;
    const int y = blockIdx.x, b = blockIdx.y;
    const int xx = tid & 63, cw = tid >> 6;

    const float* xb = x + (size_t)b * Cn * HW + y * 64;
    #pragma unroll
    for (int p = 0; p < 28; ++p) {
        int c = p * 4 + cw;
        lds[xx][c] = f2bf(xb[(size_t)c * HW + xx]);
        if (p < 4) lds[xx][112 + p * 4 + cw] = 0;
    }
    __syncthreads();

    const int rx = tid >> 2, seg = tid & 3;
    size_t row = (size_t)(b * 66 + y + 1) * 66 + rx + 1;
    unsigned short* dst = XT + row * CP + seg * 32;
    const unsigned short* srcr = &lds[rx][seg * 32];
    #pragma unroll
    for (int j = 0; j < 4; ++j)
        *reinterpret_cast<uint4*>(dst + j * 8) =
            *reinterpret_cast<const uint4*>(srcr + j * 8);
}

// ---------------------------------------------------------------------------
// pg shift-GEMM v5: 256x128 tile, BK=64 (18 K-tiles), 8 waves (4M x 2N),
// per-wave 64x64 (4x4 frags).  T2 XOR-swizzled LDS, 3 LDS buffers.
// PHASE-SPLIT schedule (T3): each K-tile = 2 phases; phase = {8 ds_read
// (one ks half, no operand re-reads) || 3 stage loads of tile t+2 ->
// setprio(1) -> 16 MFMA -> setprio(0) -> barrier}.  Counted vmcnt(6) at
// tile top keeps tile t+1's loads in flight across barriers.
// ---------------------------------------------------------------------------
__global__ __launch_bounds__(512, 1) void pg_shift_kernel(
    const unsigned short* __restrict__ XT, const unsigned short* __restrict__ B2,
    const float* __restrict__ pgb, unsigned short* __restrict__ pgBF)
{
    __shared__ __align__(16) unsigned short Asm[3][256 * 64];   // 96 KB
    __shared__ __align__(16) unsigned short Bsm[3][128 * 64];   // 48 KB

    const int tid  = threadIdx.x;
    const int lane = tid & 63;
    const int w    = tid >> 6;          // 0..7
    const int wr   = w >> 1;            // 0..3  (M)
    const int wc   = w & 1;             // 0..1  (N)
    const int m0   = blockIdx.x * 256;
    const int n0   = blockIdx.y * 128;
    const int fr   = lane & 15, fq = lane >> 4;
    const int lr8  = lane >> 3;         // 0..7 row-in-span
    const int lc8  = lane & 7;          // 0..7 chunk

    f32x4 acc[4][4] = {};

    // stage half 1: A spans 0,1 + B span 0 (3 loads per lane)
    auto stageA = [&](int buf, int kt) {
        const int tap = kt >> 1;
        const int shift = (tap / 3 - 1) * 66 + (tap % 3 - 1);
        const int c0 = (kt & 1) * 64;
        #pragma unroll
        for (int s = 0; s < 2; ++s) {
            int r = w * 32 + s * 8 + lr8;
            int cl = lc8 ^ (r & 7);
            gload_lds16(&XT[(size_t)(m0 + r + shift) * CP + c0 + cl * 8],
                        &Asm[buf][(w * 32 + s * 8) * 64]);
        }
        {
            int r = w * 16 + lr8;
            int cl = lc8 ^ (r & 7);
            gload_lds16(&B2[(size_t)(n0 + r) * KSH + kt * 64 + cl * 8],
                        &Bsm[buf][(w * 16) * 64]);
        }
    };
    // stage half 2: A spans 2,3 + B span 1 (3 loads per lane)
    auto stageB = [&](int buf, int kt) {
        const int tap = kt >> 1;
        const int shift = (tap / 3 - 1) * 66 + (tap % 3 - 1);
        const int c0 = (kt & 1) * 64;
        #pragma unroll
        for (int s = 2; s < 4; ++s) {
            int r = w * 32 + s * 8 + lr8;
            int cl = lc8 ^ (r & 7);
            gload_lds16(&XT[(size_t)(m0 + r + shift) * CP + c0 + cl * 8],
                        &Asm[buf][(w * 32 + s * 8) * 64]);
        }
        {
            int r = w * 16 + 8 + lr8;
            int cl = lc8 ^ (r & 7);
            gload_lds16(&B2[(size_t)(n0 + r) * KSH + kt * 64 + cl * 8],
                        &Bsm[buf][(w * 16 + 8) * 64]);
        }
    };

    // prologue: tiles 0, 1
    stageA(0, 0); stageB(0, 0);
    stageA(1, 1); stageB(1, 1);

    for (int kt = 0; kt < 18; ++kt) {
        // my tile-kt loads have landed (tile kt+1 stays in flight)
        if (kt < 17) asm volatile("s_waitcnt vmcnt(6)" ::: "memory");
        else         asm volatile("s_waitcnt vmcnt(0)" ::: "memory");
        // all waves' tile-kt data visible; buf[(kt+2)%3] readers done
        __builtin_amdgcn_s_barrier();
        asm volatile("" ::: "memory");

        const int cur = kt % 3;
        const int nxt = (kt + 2) % 3;
        const char* Ab = (const char*)Asm[cur];
        const char* Bb = (const char*)Bsm[cur];

        // ---------------- phase A (ks = 0) ----------------
        {
            bf16x8 a[4], b[4];
            const int csw = fq;
            #pragma unroll
            for (int mi = 0; mi < 4; ++mi) {
                int r = wr * 64 + mi * 16 + fr;
                a[mi] = *reinterpret_cast<const bf16x8*>(
                    Ab + r * 128 + ((csw ^ (fr & 7)) << 4));
            }
            #pragma unroll
            for (int ni = 0; ni < 4; ++ni) {
                int r = wc * 64 + ni * 16 + fr;
                b[ni] = *reinterpret_cast<const bf16x8*>(
                    Bb + r * 128 + ((csw ^ (fr & 7)) << 4));
            }
            if (kt + 2 < 18) stageA(nxt, kt + 2);
            __builtin_amdgcn_s_setprio(1);
            #pragma unroll
            for (int mi = 0; mi < 4; ++mi)
                #pragma unroll
                for (int ni = 0; ni < 4; ++ni)
                    acc[mi][ni] = __builtin_amdgcn_mfma_f32_16x16x32_bf16(
                        a[mi], b[ni], acc[mi][ni], 0, 0, 0);
            __builtin_amdgcn_s_setprio(0);
        }
        __builtin_amdgcn_s_barrier();
        asm volatile("" ::: "memory");

        // ---------------- phase B (ks = 1) ----------------
        {
            bf16x8 a[4], b[4];
            const int csw = 4 + fq;
            #pragma unroll
            for (int mi = 0; mi < 4; ++mi) {
                int r = wr * 64 + mi * 16 + fr;
                a[mi] = *reinterpret_cast<const bf16x8*>(
                    Ab + r * 128 + ((csw ^ (fr & 7)) << 4));
            }
            #pragma unroll
            for (int ni = 0; ni < 4; ++ni) {
                int r = wc * 64 + ni * 16 + fr;
                b[ni] = *reinterpret_cast<const bf16x8*>(
                    Bb + r * 128 + ((csw ^ (fr & 7)) << 4));
            }
            if (kt + 2 < 18) stageB(nxt, kt + 2);
            __builtin_amdgcn_s_setprio(1);
            #pragma unroll
            for (int mi = 0; mi < 4; ++mi)
                #pragma unroll
                for (int ni = 0; ni < 4; ++ni)
                    acc[mi][ni] = __builtin_amdgcn_mfma_f32_16x16x32_bf16(
                        a[mi], b[ni], acc[mi][ni], 0, 0, 0);
            __builtin_amdgcn_s_setprio(0);
        }
        // loop-top barrier of tile kt+1 closes this tile
    }

    #pragma unroll
    for (int ni = 0; ni < 4; ++ni) {
        int oc = n0 + wc * 64 + ni * 16 + fr;
        if (oc >= PGC) continue;
        float bias = pgb[oc];
        #pragma unroll
        for (int mi = 0; mi < 4; ++mi) {
            int pxq = m0 + wr * 64 + mi * 16 + fq * 4;
            #pragma unroll
            for (int r = 0; r < 4; ++r) {
                int pxd = pxq + r;
                if (pxd >= Bn * XROW) continue;
                int bb = pxd / XROW;
                int rem = pxd - bb * XROW;
                int yy = rem / 66 - 1;
                int xx = rem - (yy + 1) * 66 - 1;
                if ((unsigned)yy < 64u && (unsigned)xx < 64u)
                    pgBF[((size_t)(bb * PGC + oc)) * HW + yy * 64 + xx] =
                        f2bf(acc[mi][ni][r] + bias);
            }
        }
    }
}

// ---------------------------------------------------------------------------
// sample: thread = (pixel, (g,k) tap); gathers 4 bf16 corner rows (16B each)
// from NHWC XT; writes 16B into tiled S [px/128][ck/8][px%128][8ck].
// ---------------------------------------------------------------------------
__global__ __launch_bounds__(256) void sample_kernel(
    const unsigned short* __restrict__ XT, const unsigned short* __restrict__ pg,
    unsigned short* __restrict__ S, int px_base)
{
    const int pxl = blockIdx.x * 256 + threadIdx.x;
    const int gk  = blockIdx.y;              // 0..125
    const int g = gk / 9, k = gk - 9 * g;
    const int pxg = px_base + pxl;
    const int b = pxg >> 12, hw = pxg & 4095;
    const int y = hw >> 6, xc = hw & 63;
    const int pblk = pxl >> 7, prem = pxl & 127;

    if (gk == 0) {   // zero K-pad blocks cb = 126, 127
        const uint4 z = {0, 0, 0, 0};
        *reinterpret_cast<uint4*>(
            &S[(((size_t)pblk * 128 + 126) * 128 + prem) * 8]) = z;
        *reinterpret_cast<uint4*>(
            &S[(((size_t)pblk * 128 + 127) * 128 + prem) * 8]) = z;
    }

    const unsigned short* pgb = pg + (size_t)b * PGC * HW + hw;
    float dy = bf2f(pgb[(size_t)(18 * g + 2 * k) * HW]);
    float dx = bf2f(pgb[(size_t)(18 * g + 2 * k + 1) * HW]);
    float mv = bf2f(pgb[(size_t)(252 + 9 * g + k) * HW]);
    float m  = 1.f / (1.f + __expf(-mv));

    const int ky = k / 3, kx = k % 3;
    float yf = (float)(y + ky - 1) + dy;
    float xf = (float)(xc + kx - 1) + dx;
    float y0 = floorf(yf), x0 = floorf(xf);
    float wy1 = yf - y0, wx1 = xf - x0;
    float wy0 = 1.f - wy1, wx0 = 1.f - wx1;
    int iy0 = (int)y0, ix0 = (int)x0;
    bool vy0 = (iy0 >= 0) && (iy0 < Hn);
    bool vy1 = (iy0 >= -1) && (iy0 < Hn - 1);
    bool vx0 = (ix0 >= 0) && (ix0 < Wn);
    bool vx1 = (ix0 >= -1) && (ix0 < Wn - 1);
    int cy0 = min(max(iy0, 0), Hn - 1), cy1 = min(max(iy0 + 1, 0), Hn - 1);
    int cx0 = min(max(ix0, 0), Wn - 1), cx1 = min(max(ix0 + 1, 0), Wn - 1);
    float w00 = (vy0 && vx0) ? wy0 * wx0 * m : 0.f;
    float w01 = (vy0 && vx1) ? wy0 * wx1 * m : 0.f;
    float w10 = (vy1 && vx0) ? wy1 * wx0 * m : 0.f;
    float w11 = (vy1 && vx1) ? wy1 * wx1 * m : 0.f;

    const unsigned short* xtb = XT + (size_t)(b * 66) * 66 * CP + g * 8;
    const int r00 = (cy0 + 1) * 66 + cx0 + 1, r01 = (cy0 + 1) * 66 + cx1 + 1;
    const int r10 = (cy1 + 1) * 66 + cx0 + 1, r11 = (cy1 + 1) * 66 + cx1 + 1;
    uint4 q00 = *reinterpret_cast<const uint4*>(xtb + (size_t)r00 * CP);
    uint4 q01 = *reinterpret_cast<const uint4*>(xtb + (size_t)r01 * CP);
    uint4 q10 = *reinterpret_cast<const uint4*>(xtb + (size_t)r10 * CP);
    uint4 q11 = *reinterpret_cast<const uint4*>(xtb + (size_t)r11 * CP);

    unsigned int c00[4] = {q00.x, q00.y, q00.z, q00.w};
    unsigned int c01[4] = {q01.x, q01.y, q01.z, q01.w};
    unsigned int c10[4] = {q10.x, q10.y, q10.z, q10.w};
    unsigned int c11[4] = {q11.x, q11.y, q11.z, q11.w};

    unsigned int pk[4];
    #pragma unroll
    for (int j = 0; j < 4; ++j) {
        float lo = bflo(c00[j]) * w00 + bflo(c01[j]) * w01 +
                   bflo(c10[j]) * w10 + bflo(c11[j]) * w11;
        float hi = bfhi(c00[j]) * w00 + bfhi(c01[j]) * w01 +
                   bfhi(c10[j]) * w10 + bfhi(c11[j]) * w11;
        pk[j] = (unsigned int)f2bf(lo) | ((unsigned int)f2bf(hi) << 16);
    }
    *reinterpret_cast<uint4*>(
        &S[(((size_t)pblk * 128 + gk) * 128 + prem) * 8]) =
        *reinterpret_cast<const uint4*>(pk);
}

// ---------------------------------------------------------------------------
// main GEMM: out[b][oc][hw] = S_tiled[px][ck] * WB[oc][ck] + bias[oc]
// Double-buffered prefetch, counted vmcnt (validated round 9).
// ---------------------------------------------------------------------------
__global__ __launch_bounds__(256) void main_gemm_kernel(
    const unsigned short* __restrict__ S, const unsigned short* __restrict__ WB,
    const float* __restrict__ bias, float* __restrict__ out, int px_base)
{
    __shared__ __align__(16) unsigned short Asm[2][128 * 32];
    __shared__ __align__(16) unsigned short Bsm[2][128 * 32];

    const int tid  = threadIdx.x;
    const int lane = tid & 63;
    const int w    = tid >> 6;
    const int wr   = w >> 1, wc = w & 1;
    const int m0   = blockIdx.x * 128;
    const int fr   = lane & 15, fq = lane >> 4;

    f32x4 acc[4][4] = {};

    const int ldr = lane >> 2;
    const int lq  = lane & 3;
    const int ldc = lq * 8;

    auto stage = [&](int buf, int kt) {
        #pragma unroll
        for (int i = 0; i < 2; ++i) {
            int row = w * 32 + i * 16 + ldr;
            int cb  = kt * 4 + lq;
            gload_lds16(&S[(((size_t)blockIdx.x * 128 + cb) * 128 + row) * 8],
                        &Asm[buf][(w * 32 + i * 16) * 32]);
            gload_lds16(&WB[(size_t)row * KP + kt * 32 + ldc],
                        &Bsm[buf][(w * 32 + i * 16) * 32]);
        }
    };

    stage(0, 0);
    int cur = 0;
    for (int kt = 0; kt < 32; ++kt) {
        if (kt + 1 < 32) {
            stage(cur ^ 1, kt + 1);
            asm volatile("s_waitcnt vmcnt(4)" ::: "memory");
        } else {
            asm volatile("s_waitcnt vmcnt(0)" ::: "memory");
        }
        __builtin_amdgcn_s_barrier();
        asm volatile("" ::: "memory");

        bf16x8 a[4], b[4];
        #pragma unroll
        for (int mi = 0; mi < 4; ++mi)
            a[mi] = *reinterpret_cast<const bf16x8*>(
                &Asm[cur][(wr * 64 + mi * 16 + fr) * 32 + fq * 8]);
        #pragma unroll
        for (int ni = 0; ni < 4; ++ni)
            b[ni] = *reinterpret_cast<const bf16x8*>(
                &Bsm[cur][(wc * 64 + ni * 16 + fr) * 32 + fq * 8]);
        #pragma unroll
        for (int mi = 0; mi < 4; ++mi)
            #pragma unroll
            for (int ni = 0; ni < 4; ++ni)
                acc[mi][ni] = __builtin_amdgcn_mfma_f32_16x16x32_bf16(
                    a[mi], b[ni], acc[mi][ni], 0, 0, 0);

        asm volatile("s_waitcnt lgkmcnt(0)" ::: "memory");
        __builtin_amdgcn_s_barrier();
        asm volatile("" ::: "memory");
        cur ^= 1;
    }

    #pragma unroll
    for (int ni = 0; ni < 4; ++ni) {
        int oc = wc * 64 + ni * 16 + fr;
        if (oc >= On) continue;
        float bv = bias[oc];
        #pragma unroll
        for (int mi = 0; mi < 4; ++mi) {
            int pxl = m0 + wr * 64 + mi * 16 + fq * 4;
            int pxg = px_base + pxl;
            int b = pxg >> 12, hw = pxg & 4095;
            float4 o;
            o.x = acc[mi][ni][0] + bv;
            o.y = acc[mi][ni][1] + bv;
            o.z = acc[mi][ni][2] + bv;
            o.w = acc[mi][ni][3] + bv;
            *reinterpret_cast<float4*>(
                &out[((size_t)(b * On + oc)) * HW + hw]) = o;
        }
    }
}

// ---------------------------------------------------------------------------
extern "C" void kernel_launch(void* const* d_in, const int* in_sizes, int n_in,
                              void* d_out, int out_size, void* d_ws, size_t ws_size,
                              hipStream_t stream) {
    const float* x    = (const float*)d_in[0];
    const float* pgw  = (const float*)d_in[1];
    const float* pgb  = (const float*)d_in[2];
    const float* w    = (const float*)d_in[3];
    const float* bias = (const float*)d_in[4];
    float* out = (float*)d_out;

    char* wsb = (char*)d_ws;
    unsigned short* pgBF = (unsigned short*)wsb;                 // 24.77 MB
    size_t off = (size_t)PGC * Bn * HW * 2;
    unsigned short* B2   = (unsigned short*)(wsb + off);         // 0.88 MB
    off += (size_t)NP * KSH * 2;
    unsigned short* WB   = (unsigned short*)(wsb + off);         // 0.26 MB
    off += (size_t)128 * KP * 2;
    unsigned short* XTa  = (unsigned short*)(wsb + off);         // 9.01 MB
    unsigned short* XT   = XTa + (size_t)XGUARD * CP;
    off += (size_t)XALLOC_ROWS * CP * 2;
    unsigned short* S    = (unsigned short*)(wsb + off);         // sampled (tiled)

    const size_t sfull = (size_t)MFULL * KP * 2;                 // 67.1 MB
    int nh;
    if (ws_size >= off + sfull)          nh = 1;   // ~102 MB total
    else if (ws_size >= off + sfull / 2) nh = 2;
    else                                 nh = 4;
    const int cnt = MFULL / nh;

    // prep: zero XT + build B2 + WB
    {
        int tot = ZN + B2N + WBN;
        prep_kernel<<<(tot + 255) / 256, 256, 0, stream>>>(pgw, w, XTa, B2, WB);
    }
    // transpose x -> XT (NHWC bf16, 66x66 halo)
    xpose_kernel<<<dim3(Hn, Bn), 256, 0, stream>>>(x, XT);

    // pg conv: 256x128/BK=64, 8 waves, T2 swizzle, phase-split pipeline
    pg_shift_kernel<<<dim3(PG_MT, NP / 128), 512, 0, stream>>>(
        XT, B2, pgb, pgBF);

    // deformable sampling (NHWC corner loads) -> tiled S, then main GEMM
    for (int h = 0; h < nh; ++h) {
        sample_kernel<<<dim3(cnt / 256, 126), 256, 0, stream>>>(
            XT, pgBF, S, h * cnt);
        main_gemm_kernel<<<dim3(cnt / 128, 1), 256, 0, stream>>>(
            S, WB, bias, out, h * cnt);
    }
}

// Round 14
// 142.767 us; speedup vs baseline: 1.3075x; 1.1248x over previous
//
#include <hip/hip_runtime.h>
#include <math.h>

#define Bn 8
#define Cn 112
#define Hn 64
#define Wn 64
#define On 112
#define Gn 14
#define PGC 378          // 3*G*K2
#define HW 4096          // 64*64
#define CKW 1008         // C*K2
#define KP 1024          // padded K for main GEMM (sampled layout)
#define NP 384           // padded N (oc) for pg GEMM
#define KSH 1152         // shift-GEMM K = 9 taps * 128 padded channels
#define MFULL 32768
#define XROW 4356        // 66*66 rows per batch
#define PG_MT 137        // M-tiles of 256
#define MPAD (PG_MT * 256)                 // 35072
#define PLANE_ROWS 34848                   // 8 batches * 4356 rows per plane
#define XGUARD 67
#define XTG_ALLOC_ROWS (XGUARD + 16 * PLANE_ROWS + 384)   // 558019 -> round up
#define XTG_ROWS_TOTAL 558080                              // padded alloc rows

typedef __attribute__((ext_vector_type(8))) short bf16x8;
typedef __attribute__((ext_vector_type(4))) float f32x4;

__device__ __forceinline__ unsigned short f2bf(float f) {
    union { float f; unsigned int u; } v; v.f = f;
    unsigned int r = v.u + 0x7fffu + ((v.u >> 16) & 1u);
    return (unsigned short)(r >> 16);
}
__device__ __forceinline__ float bf2f(unsigned short u) {
    union { unsigned int u; float f; } v; v.u = ((unsigned int)u) << 16;
    return v.f;
}
__device__ __forceinline__ float bflo(unsigned int u) {
    union { unsigned int u; float f; } v; v.u = u << 16; return v.f;
}
__device__ __forceinline__ float bfhi(unsigned int u) {
    union { unsigned int u; float f; } v; v.u = u & 0xffff0000u; return v.f;
}
__device__ __forceinline__ void gload_lds16(const void* g, void* l) {
    __builtin_amdgcn_global_load_lds(
        (const __attribute__((address_space(1))) unsigned int*)g,
        (__attribute__((address_space(3))) unsigned int*)l, 16, 0, 0);
}

// ---------------------------------------------------------------------------
// prep (merged): zero XTG alloc (1 uint4 per row) | B2 [384][1152] | WB [128][1024]
// ---------------------------------------------------------------------------
#define ZN XTG_ROWS_TOTAL
#define B2N (NP * KSH)
#define WBN (128 * KP)
__global__ __launch_bounds__(256) void prep_kernel(
    const float* __restrict__ pgw, const float* __restrict__ w,
    unsigned short* __restrict__ XTGa, unsigned short* __restrict__ B2,
    unsigned short* __restrict__ WB)
{
    int t = blockIdx.x * 256 + threadIdx.x;
    if (t < ZN) {
        const uint4 z = {0, 0, 0, 0};
        reinterpret_cast<uint4*>(XTGa)[t] = z;
        return;
    }
    t -= ZN;
    if (t < B2N) {
        int oc = t / KSH, ckk = t - oc * KSH;
        int k = ckk >> 7, c = ckk & 127;
        float v = (c < Cn && oc < PGC) ? pgw[(size_t)oc * CKW + c * 9 + k] : 0.f;
        B2[t] = f2bf(v);
        return;
    }
    t -= B2N;
    if (t < WBN) {
        int oc = t >> 10, ck = t & 1023;
        float v = 0.f;
        if (oc < On && ck < CKW) {
            int g = ck / 72, r = ck % 72;
            int k = r >> 3, cc = r & 7;
            v = w[(size_t)oc * CKW + (g * 8 + cc) * 9 + k];
        }
        WB[t] = f2bf(v);
    }
}

// ---------------------------------------------------------------------------
// xpose: x NCHW f32 -> XTG bf16 planes [g][b][row66x66][8ch]
// block = (y, b); LDS transpose; interior rows only (halo pre-zeroed)
// ---------------------------------------------------------------------------
__global__ __launch_bounds__(256) void xpose_kernel(
    const float* __restrict__ x, unsigned short* __restrict__ XTG)
{
    __shared__ unsigned short lds[64][136];   // row stride 272 B (16B-aligned)

    const int tid = threadIdx.x;
    const int y = blockIdx.x, b = blockIdx.y;
    const int xx = tid & 63, cw = tid >> 6;

    const float* xb = x + (size_t)b * Cn * HW + y * 64;
    #pragma unroll
    for (int p = 0; p < 28; ++p) {
        int c = p * 4 + cw;
        lds[xx][c] = f2bf(xb[(size_t)c * HW + xx]);
    }
    __syncthreads();

    #pragma unroll
    for (int q = 0; q < 4; ++q) {
        int task = q * 256 + tid;            // 0..895 used (64 xx * 14 g)
        if (task < 896) {
            int g = task >> 6;
            int x2 = task & 63;
            unsigned short* dst = XTG + ((size_t)g * PLANE_ROWS
                + (size_t)b * XROW + (y + 1) * 66 + x2 + 1) * 8;
            *reinterpret_cast<uint4*>(dst) =
                *reinterpret_cast<const uint4*>(&lds[x2][g * 8]);
        }
    }
}

// ---------------------------------------------------------------------------
// pg shift-GEMM v5 (round-13 schedule, XTG-planar A source):
// 256x128 tile, BK=64 (18 K-tiles), 8 waves (4M x 2N), per-wave 64x64.
// T2 XOR-swizzled LDS, 3 buffers, counted vmcnt(6), phase-split, setprio.
// A chunk j of half h = plane h*8+j of XTG (planes 14,15 are the zero pad).
// ---------------------------------------------------------------------------
__global__ __launch_bounds__(512, 1) void pg_shift_kernel(
    const unsigned short* __restrict__ XTG, const unsigned short* __restrict__ B2,
    const float* __restrict__ pgb, unsigned short* __restrict__ pgBF)
{
    __shared__ __align__(16) unsigned short Asm[3][256 * 64];   // 96 KB
    __shared__ __align__(16) unsigned short Bsm[3][128 * 64];   // 48 KB

    const int tid  = threadIdx.x;
    const int lane = tid & 63;
    const int w    = tid >> 6;          // 0..7
    const int wr   = w >> 1;            // 0..3  (M)
    const int wc   = w & 1;             // 0..1  (N)
    const int m0   = blockIdx.x * 256;
    const int n0   = blockIdx.y * 128;
    const int fr   = lane & 15, fq = lane >> 4;
    const int lr8  = lane >> 3;
    const int lc8  = lane & 7;

    f32x4 acc[4][4] = {};

    auto stageA = [&](int buf, int kt) {
        const int tap = kt >> 1;
        const int shift = (tap / 3 - 1) * 66 + (tap % 3 - 1);
        const int pbase = (kt & 1) * 8;
        #pragma unroll
        for (int s = 0; s < 2; ++s) {
            int r = w * 32 + s * 8 + lr8;
            long pl = pbase + (lc8 ^ (r & 7));
            gload_lds16(XTG + (pl * PLANE_ROWS + (long)(m0 + r + shift)) * 8,
                        &Asm[buf][(w * 32 + s * 8) * 64]);
        }
        {
            int r = w * 16 + lr8;
            int cl = lc8 ^ (r & 7);
            gload_lds16(&B2[(size_t)(n0 + r) * KSH + kt * 64 + cl * 8],
                        &Bsm[buf][(w * 16) * 64]);
        }
    };
    auto stageB = [&](int buf, int kt) {
        const int tap = kt >> 1;
        const int shift = (tap / 3 - 1) * 66 + (tap % 3 - 1);
        const int pbase = (kt & 1) * 8;
        #pragma unroll
        for (int s = 2; s < 4; ++s) {
            int r = w * 32 + s * 8 + lr8;
            long pl = pbase + (lc8 ^ (r & 7));
            gload_lds16(XTG + (pl * PLANE_ROWS + (long)(m0 + r + shift)) * 8,
                        &Asm[buf][(w * 32 + s * 8) * 64]);
        }
        {
            int r = w * 16 + 8 + lr8;
            int cl = lc8 ^ (r & 7);
            gload_lds16(&B2[(size_t)(n0 + r) * KSH + kt * 64 + cl * 8],
                        &Bsm[buf][(w * 16 + 8) * 64]);
        }
    };

    stageA(0, 0); stageB(0, 0);
    stageA(1, 1); stageB(1, 1);

    for (int kt = 0; kt < 18; ++kt) {
        if (kt < 17) asm volatile("s_waitcnt vmcnt(6)" ::: "memory");
        else         asm volatile("s_waitcnt vmcnt(0)" ::: "memory");
        __builtin_amdgcn_s_barrier();
        asm volatile("" ::: "memory");

        const int cur = kt % 3;
        const int nxt = (kt + 2) % 3;
        const char* Ab = (const char*)Asm[cur];
        const char* Bb = (const char*)Bsm[cur];

        // phase A (ks = 0)
        {
            bf16x8 a[4], b[4];
            const int csw = fq;
            #pragma unroll
            for (int mi = 0; mi < 4; ++mi) {
                int r = wr * 64 + mi * 16 + fr;
                a[mi] = *reinterpret_cast<const bf16x8*>(
                    Ab + r * 128 + ((csw ^ (fr & 7)) << 4));
            }
            #pragma unroll
            for (int ni = 0; ni < 4; ++ni) {
                int r = wc * 64 + ni * 16 + fr;
                b[ni] = *reinterpret_cast<const bf16x8*>(
                    Bb + r * 128 + ((csw ^ (fr & 7)) << 4));
            }
            if (kt + 2 < 18) stageA(nxt, kt + 2);
            __builtin_amdgcn_s_setprio(1);
            #pragma unroll
            for (int mi = 0; mi < 4; ++mi)
                #pragma unroll
                for (int ni = 0; ni < 4; ++ni)
                    acc[mi][ni] = __builtin_amdgcn_mfma_f32_16x16x32_bf16(
                        a[mi], b[ni], acc[mi][ni], 0, 0, 0);
            __builtin_amdgcn_s_setprio(0);
        }
        __builtin_amdgcn_s_barrier();
        asm volatile("" ::: "memory");

        // phase B (ks = 1)
        {
            bf16x8 a[4], b[4];
            const int csw = 4 + fq;
            #pragma unroll
            for (int mi = 0; mi < 4; ++mi) {
                int r = wr * 64 + mi * 16 + fr;
                a[mi] = *reinterpret_cast<const bf16x8*>(
                    Ab + r * 128 + ((csw ^ (fr & 7)) << 4));
            }
            #pragma unroll
            for (int ni = 0; ni < 4; ++ni) {
                int r = wc * 64 + ni * 16 + fr;
                b[ni] = *reinterpret_cast<const bf16x8*>(
                    Bb + r * 128 + ((csw ^ (fr & 7)) << 4));
            }
            if (kt + 2 < 18) stageB(nxt, kt + 2);
            __builtin_amdgcn_s_setprio(1);
            #pragma unroll
            for (int mi = 0; mi < 4; ++mi)
                #pragma unroll
                for (int ni = 0; ni < 4; ++ni)
                    acc[mi][ni] = __builtin_amdgcn_mfma_f32_16x16x32_bf16(
                        a[mi], b[ni], acc[mi][ni], 0, 0, 0);
            __builtin_amdgcn_s_setprio(0);
        }
    }

    #pragma unroll
    for (int ni = 0; ni < 4; ++ni) {
        int oc = n0 + wc * 64 + ni * 16 + fr;
        if (oc >= PGC) continue;
        float bias = pgb[oc];
        #pragma unroll
        for (int mi = 0; mi < 4; ++mi) {
            int pxq = m0 + wr * 64 + mi * 16 + fq * 4;
            #pragma unroll
            for (int r = 0; r < 4; ++r) {
                int pxd = pxq + r;
                if (pxd >= Bn * XROW) continue;
                int bb = pxd / XROW;
                int rem = pxd - bb * XROW;
                int yy = rem / 66 - 1;
                int xx = rem - (yy + 1) * 66 - 1;
                if ((unsigned)yy < 64u && (unsigned)xx < 64u)
                    pgBF[((size_t)(bb * PGC + oc)) * HW + yy * 64 + xx] =
                        f2bf(acc[mi][ni][r] + bias);
            }
        }
    }
}

// ---------------------------------------------------------------------------
// sample: grid (gk, px-block); thread = (pixel, (g,k) tap).
// Corner loads from XTG plane g: consecutive lanes -> consecutive 16B chunks
// (100% cache-line utilization).  Writes tiled S [px/128][ck/8][px%128][8ch].
// ---------------------------------------------------------------------------
__global__ __launch_bounds__(256) void sample_kernel(
    const unsigned short* __restrict__ XTG, const unsigned short* __restrict__ pg,
    unsigned short* __restrict__ S, int px_base)
{
    const int gk  = blockIdx.x;              // 0..125
    const int pxl = blockIdx.y * 256 + threadIdx.x;
    const int g = gk / 9, k = gk - 9 * g;
    const int pxg = px_base + pxl;
    const int b = pxg >> 12, hw = pxg & 4095;
    const int y = hw >> 6, xc = hw & 63;
    const int pblk = pxl >> 7, prem = pxl & 127;

    if (gk == 0) {   // zero K-pad blocks cb = 126, 127
        const uint4 z = {0, 0, 0, 0};
        *reinterpret_cast<uint4*>(
            &S[(((size_t)pblk * 128 + 126) * 128 + prem) * 8]) = z;
        *reinterpret_cast<uint4*>(
            &S[(((size_t)pblk * 128 + 127) * 128 + prem) * 8]) = z;
    }

    const unsigned short* pgb = pg + (size_t)b * PGC * HW + hw;
    float dy = bf2f(pgb[(size_t)(18 * g + 2 * k) * HW]);
    float dx = bf2f(pgb[(size_t)(18 * g + 2 * k + 1) * HW]);
    float mv = bf2f(pgb[(size_t)(252 + 9 * g + k) * HW]);
    float m  = 1.f / (1.f + __expf(-mv));

    const int ky = k / 3, kx = k % 3;
    float yf = (float)(y + ky - 1) + dy;
    float xf = (float)(xc + kx - 1) + dx;
    float y0 = floorf(yf), x0 = floorf(xf);
    float wy1 = yf - y0, wx1 = xf - x0;
    float wy0 = 1.f - wy1, wx0 = 1.f - wx1;
    int iy0 = (int)y0, ix0 = (int)x0;
    bool vy0 = (iy0 >= 0) && (iy0 < Hn);
    bool vy1 = (iy0 >= -1) && (iy0 < Hn - 1);
    bool vx0 = (ix0 >= 0) && (ix0 < Wn);
    bool vx1 = (ix0 >= -1) && (ix0 < Wn - 1);
    int cy0 = min(max(iy0, 0), Hn - 1), cy1 = min(max(iy0 + 1, 0), Hn - 1);
    int cx0 = min(max(ix0, 0), Wn - 1), cx1 = min(max(ix0 + 1, 0), Wn - 1);
    float w00 = (vy0 && vx0) ? wy0 * wx0 * m : 0.f;
    float w01 = (vy0 && vx1) ? wy0 * wx1 * m : 0.f;
    float w10 = (vy1 && vx0) ? wy1 * wx0 * m : 0.f;
    float w11 = (vy1 && vx1) ? wy1 * wx1 * m : 0.f;

    const unsigned short* xg = XTG +
        ((size_t)g * PLANE_ROWS + (size_t)b * XROW) * 8;
    const int r00 = (cy0 + 1) * 66 + cx0 + 1, r01 = (cy0 + 1) * 66 + cx1 + 1;
    const int r10 = (cy1 + 1) * 66 + cx0 + 1, r11 = (cy1 + 1) * 66 + cx1 + 1;
    uint4 q00 = *reinterpret_cast<const uint4*>(xg + (size_t)r00 * 8);
    uint4 q01 = *reinterpret_cast<const uint4*>(xg + (size_t)r01 * 8);
    uint4 q10 = *reinterpret_cast<const uint4*>(xg + (size_t)r10 * 8);
    uint4 q11 = *reinterpret_cast<const uint4*>(xg + (size_t)r11 * 8);

    unsigned int c00[4] = {q00.x, q00.y, q00.z, q00.w};
    unsigned int c01[4] = {q01.x, q01.y, q01.z, q01.w};
    unsigned int c10[4] = {q10.x, q10.y, q10.z, q10.w};
    unsigned int c11[4] = {q11.x, q11.y, q11.z, q11.w};

    unsigned int pk[4];
    #pragma unroll
    for (int j = 0; j < 4; ++j) {
        float lo = bflo(c00[j]) * w00 + bflo(c01[j]) * w01 +
                   bflo(c10[j]) * w10 + bflo(c11[j]) * w11;
        float hi = bfhi(c00[j]) * w00 + bfhi(c01[j]) * w01 +
                   bfhi(c10[j]) * w10 + bfhi(c11[j]) * w11;
        pk[j] = (unsigned int)f2bf(lo) | ((unsigned int)f2bf(hi) << 16);
    }
    *reinterpret_cast<uint4*>(
        &S[(((size_t)pblk * 128 + gk) * 128 + prem) * 8]) =
        *reinterpret_cast<const uint4*>(pk);
}

// ---------------------------------------------------------------------------
// main GEMM: out[b][oc][hw] = S_tiled[px][ck] * WB[oc][ck] + bias[oc]
// Double-buffered prefetch, counted vmcnt (validated rounds 9-13).
// ---------------------------------------------------------------------------
__global__ __launch_bounds__(256) void main_gemm_kernel(
    const unsigned short* __restrict__ S, const unsigned short* __restrict__ WB,
    const float* __restrict__ bias, float* __restrict__ out, int px_base)
{
    __shared__ __align__(16) unsigned short Asm[2][128 * 32];
    __shared__ __align__(16) unsigned short Bsm[2][128 * 32];

    const int tid  = threadIdx.x;
    const int lane = tid & 63;
    const int w    = tid >> 6;
    const int wr   = w >> 1, wc = w & 1;
    const int m0   = blockIdx.x * 128;
    const int fr   = lane & 15, fq = lane >> 4;

    f32x4 acc[4][4] = {};

    const int ldr = lane >> 2;
    const int lq  = lane & 3;
    const int ldc = lq * 8;

    auto stage = [&](int buf, int kt) {
        #pragma unroll
        for (int i = 0; i < 2; ++i) {
            int row = w * 32 + i * 16 + ldr;
            int cb  = kt * 4 + lq;
            gload_lds16(&S[(((size_t)blockIdx.x * 128 + cb) * 128 + row) * 8],
                        &Asm[buf][(w * 32 + i * 16) * 32]);
            gload_lds16(&WB[(size_t)row * KP + kt * 32 + ldc],
                        &Bsm[buf][(w * 32 + i * 16) * 32]);
        }
    };

    stage(0, 0);
    int cur = 0;
    for (int kt = 0; kt < 32; ++kt) {
        if (kt + 1 < 32) {
            stage(cur ^ 1, kt + 1);
            asm volatile("s_waitcnt vmcnt(4)" ::: "memory");
        } else {
            asm volatile("s_waitcnt vmcnt(0)" ::: "memory");
        }
        __builtin_amdgcn_s_barrier();
        asm volatile("" ::: "memory");

        bf16x8 a[4], b[4];
        #pragma unroll
        for (int mi = 0; mi < 4; ++mi)
            a[mi] = *reinterpret_cast<const bf16x8*>(
                &Asm[cur][(wr * 64 + mi * 16 + fr) * 32 + fq * 8]);
        #pragma unroll
        for (int ni = 0; ni < 4; ++ni)
            b[ni] = *reinterpret_cast<const bf16x8*>(
                &Bsm[cur][(wc * 64 + ni * 16 + fr) * 32 + fq * 8]);
        #pragma unroll
        for (int mi = 0; mi < 4; ++mi)
            #pragma unroll
            for (int ni = 0; ni < 4; ++ni)
                acc[mi][ni] = __builtin_amdgcn_mfma_f32_16x16x32_bf16(
                    a[mi], b[ni], acc[mi][ni], 0, 0, 0);

        asm volatile("s_waitcnt lgkmcnt(0)" ::: "memory");
        __builtin_amdgcn_s_barrier();
        asm volatile("" ::: "memory");
        cur ^= 1;
    }

    #pragma unroll
    for (int ni = 0; ni < 4; ++ni) {
        int oc = wc * 64 + ni * 16 + fr;
        if (oc >= On) continue;
        float bv = bias[oc];
        #pragma unroll
        for (int mi = 0; mi < 4; ++mi) {
            int pxl = m0 + wr * 64 + mi * 16 + fq * 4;
            int pxg = px_base + pxl;
            int b = pxg >> 12, hw = pxg & 4095;
            float4 o;
            o.x = acc[mi][ni][0] + bv;
            o.y = acc[mi][ni][1] + bv;
            o.z = acc[mi][ni][2] + bv;
            o.w = acc[mi][ni][3] + bv;
            *reinterpret_cast<float4*>(
                &out[((size_t)(b * On + oc)) * HW + hw]) = o;
        }
    }
}

// ---------------------------------------------------------------------------
extern "C" void kernel_launch(void* const* d_in, const int* in_sizes, int n_in,
                              void* d_out, int out_size, void* d_ws, size_t ws_size,
                              hipStream_t stream) {
    const float* x    = (const float*)d_in[0];
    const float* pgw  = (const float*)d_in[1];
    const float* pgb  = (const float*)d_in[2];
    const float* w    = (const float*)d_in[3];
    const float* bias = (const float*)d_in[4];
    float* out = (float*)d_out;

    char* wsb = (char*)d_ws;
    unsigned short* pgBF = (unsigned short*)wsb;                 // 24.77 MB
    size_t off = (size_t)PGC * Bn * HW * 2;
    unsigned short* B2   = (unsigned short*)(wsb + off);         // 0.88 MB
    off += (size_t)NP * KSH * 2;
    unsigned short* WB   = (unsigned short*)(wsb + off);         // 0.26 MB
    off += (size_t)128 * KP * 2;
    unsigned short* XTGa = (unsigned short*)(wsb + off);         // 8.93 MB
    unsigned short* XTG  = XTGa + (size_t)XGUARD * 8;            // guarded base
    off += (size_t)XTG_ROWS_TOTAL * 16;
    unsigned short* S    = (unsigned short*)(wsb + off);         // sampled (tiled)

    const size_t sfull = (size_t)MFULL * KP * 2;                 // 67.1 MB
    int nh;
    if (ws_size >= off + sfull)          nh = 1;   // ~102 MB total
    else if (ws_size >= off + sfull / 2) nh = 2;
    else                                 nh = 4;
    const int cnt = MFULL / nh;

    // prep: zero XTG + build B2 + WB
    {
        int tot = ZN + B2N + WBN;
        prep_kernel<<<(tot + 255) / 256, 256, 0, stream>>>(pgw, w, XTGa, B2, WB);
    }
    // transpose x -> XTG (group-planar NHWC bf16, 66x66 halo)
    xpose_kernel<<<dim3(Hn, Bn), 256, 0, stream>>>(x, XTG);

    // pg conv: 256x128/BK=64, 8 waves, T2 swizzle, phase-split pipeline
    pg_shift_kernel<<<dim3(PG_MT, NP / 128), 512, 0, stream>>>(
        XTG, B2, pgb, pgBF);

    // deformable sampling (planar 16B corner loads) -> tiled S, then main GEMM
    for (int h = 0; h < nh; ++h) {
        sample_kernel<<<dim3(126, cnt / 256), 256, 0, stream>>>(
            XTG, pgBF, S, h * cnt);
        main_gemm_kernel<<<dim3(cnt / 128, 1), 256, 0, stream>>>(
            S, WB, bias, out, h * cnt);
    }
}

// Round 15
// 139.277 us; speedup vs baseline: 1.3402x; 1.0251x over previous
//
#include <hip/hip_runtime.h>
#include <math.h>

#define Bn 8
#define Cn 112
#define Hn 64
#define Wn 64
#define On 112
#define Gn 14
#define PGC 378          // 3*G*K2
#define HW 4096          // 64*64
#define CKW 1008         // C*K2
#define KP 1024          // padded K for main GEMM (sampled layout)
#define NP 384           // padded N (oc) for pg GEMM
#define KSH 1152         // shift-GEMM K = 9 taps * 128 padded channels
#define MFULL 32768
#define XROW 4356        // 66*66 rows per batch
#define PG_MT 137        // M-tiles of 256
#define MPAD (PG_MT * 256)                 // 35072
#define PLANE_ROWS 34848                   // 8 batches * 4356 rows per plane
#define XGUARD 67
#define XTG_ROWS_TOTAL 558080              // padded alloc rows

typedef __attribute__((ext_vector_type(8))) short bf16x8;
typedef __attribute__((ext_vector_type(4))) float f32x4;

__device__ __forceinline__ unsigned short f2bf(float f) {
    union { float f; unsigned int u; } v; v.f = f;
    unsigned int r = v.u + 0x7fffu + ((v.u >> 16) & 1u);
    return (unsigned short)(r >> 16);
}
__device__ __forceinline__ float bf2f(unsigned short u) {
    union { unsigned int u; float f; } v; v.u = ((unsigned int)u) << 16;
    return v.f;
}
__device__ __forceinline__ float bflo(unsigned int u) {
    union { unsigned int u; float f; } v; v.u = u << 16; return v.f;
}
__device__ __forceinline__ float bfhi(unsigned int u) {
    union { unsigned int u; float f; } v; v.u = u & 0xffff0000u; return v.f;
}
__device__ __forceinline__ void gload_lds16(const void* g, void* l) {
    __builtin_amdgcn_global_load_lds(
        (const __attribute__((address_space(1))) unsigned int*)g,
        (__attribute__((address_space(3))) unsigned int*)l, 16, 0, 0);
}

// ---------------------------------------------------------------------------
// prep (merged): zero XTG alloc | B2 [384][1152] | WB [128][1024]
// ---------------------------------------------------------------------------
#define ZN XTG_ROWS_TOTAL
#define B2N (NP * KSH)
#define WBN (128 * KP)
__global__ __launch_bounds__(256) void prep_kernel(
    const float* __restrict__ pgw, const float* __restrict__ w,
    unsigned short* __restrict__ XTGa, unsigned short* __restrict__ B2,
    unsigned short* __restrict__ WB)
{
    int t = blockIdx.x * 256 + threadIdx.x;
    if (t < ZN) {
        const uint4 z = {0, 0, 0, 0};
        reinterpret_cast<uint4*>(XTGa)[t] = z;
        return;
    }
    t -= ZN;
    if (t < B2N) {
        int oc = t / KSH, ckk = t - oc * KSH;
        int k = ckk >> 7, c = ckk & 127;
        float v = (c < Cn && oc < PGC) ? pgw[(size_t)oc * CKW + c * 9 + k] : 0.f;
        B2[t] = f2bf(v);
        return;
    }
    t -= B2N;
    if (t < WBN) {
        int oc = t >> 10, ck = t & 1023;
        float v = 0.f;
        if (oc < On && ck < CKW) {
            int g = ck / 72, r = ck % 72;
            int k = r >> 3, cc = r & 7;
            v = w[(size_t)oc * CKW + (g * 8 + cc) * 9 + k];
        }
        WB[t] = f2bf(v);
    }
}

// ---------------------------------------------------------------------------
// xpose: x NCHW f32 -> XTG bf16 planes [g][b][row66x66][8ch]
// ---------------------------------------------------------------------------
__global__ __launch_bounds__(256) void xpose_kernel(
    const float* __restrict__ x, unsigned short* __restrict__ XTG)
{
    __shared__ unsigned short lds[64][136];

    const int tid = threadIdx.x;
    const int y = blockIdx.x, b = blockIdx.y;
    const int xx = tid & 63, cw = tid >> 6;

    const float* xb = x + (size_t)b * Cn * HW + y * 64;
    #pragma unroll
    for (int p = 0; p < 28; ++p) {
        int c = p * 4 + cw;
        lds[xx][c] = f2bf(xb[(size_t)c * HW + xx]);
    }
    __syncthreads();

    #pragma unroll
    for (int q = 0; q < 4; ++q) {
        int task = q * 256 + tid;            // 0..895 used (64 xx * 14 g)
        if (task < 896) {
            int g = task >> 6;
            int x2 = task & 63;
            unsigned short* dst = XTG + ((size_t)g * PLANE_ROWS
                + (size_t)b * XROW + (y + 1) * 66 + x2 + 1) * 8;
            *reinterpret_cast<uint4*>(dst) =
                *reinterpret_cast<const uint4*>(&lds[x2][g * 8]);
        }
    }
}

// ---------------------------------------------------------------------------
// pg shift-GEMM v5 (round-13 schedule, XTG-planar A source):
// 256x128 tile, BK=64 (18 K-tiles), 8 waves (4M x 2N), per-wave 64x64.
// T2 XOR-swizzled LDS, 3 buffers, counted vmcnt(6), phase-split, setprio.
// ---------------------------------------------------------------------------
__global__ __launch_bounds__(512, 1) void pg_shift_kernel(
    const unsigned short* __restrict__ XTG, const unsigned short* __restrict__ B2,
    const float* __restrict__ pgb, unsigned short* __restrict__ pgBF)
{
    __shared__ __align__(16) unsigned short Asm[3][256 * 64];   // 96 KB
    __shared__ __align__(16) unsigned short Bsm[3][128 * 64];   // 48 KB

    const int tid  = threadIdx.x;
    const int lane = tid & 63;
    const int w    = tid >> 6;          // 0..7
    const int wr   = w >> 1;            // 0..3  (M)
    const int wc   = w & 1;             // 0..1  (N)
    const int m0   = blockIdx.x * 256;
    const int n0   = blockIdx.y * 128;
    const int fr   = lane & 15, fq = lane >> 4;
    const int lr8  = lane >> 3;
    const int lc8  = lane & 7;

    f32x4 acc[4][4] = {};

    auto stageA = [&](int buf, int kt) {
        const int tap = kt >> 1;
        const int shift = (tap / 3 - 1) * 66 + (tap % 3 - 1);
        const int pbase = (kt & 1) * 8;
        #pragma unroll
        for (int s = 0; s < 2; ++s) {
            int r = w * 32 + s * 8 + lr8;
            long pl = pbase + (lc8 ^ (r & 7));
            gload_lds16(XTG + (pl * PLANE_ROWS + (long)(m0 + r + shift)) * 8,
                        &Asm[buf][(w * 32 + s * 8) * 64]);
        }
        {
            int r = w * 16 + lr8;
            int cl = lc8 ^ (r & 7);
            gload_lds16(&B2[(size_t)(n0 + r) * KSH + kt * 64 + cl * 8],
                        &Bsm[buf][(w * 16) * 64]);
        }
    };
    auto stageB = [&](int buf, int kt) {
        const int tap = kt >> 1;
        const int shift = (tap / 3 - 1) * 66 + (tap % 3 - 1);
        const int pbase = (kt & 1) * 8;
        #pragma unroll
        for (int s = 2; s < 4; ++s) {
            int r = w * 32 + s * 8 + lr8;
            long pl = pbase + (lc8 ^ (r & 7));
            gload_lds16(XTG + (pl * PLANE_ROWS + (long)(m0 + r + shift)) * 8,
                        &Asm[buf][(w * 32 + s * 8) * 64]);
        }
        {
            int r = w * 16 + 8 + lr8;
            int cl = lc8 ^ (r & 7);
            gload_lds16(&B2[(size_t)(n0 + r) * KSH + kt * 64 + cl * 8],
                        &Bsm[buf][(w * 16 + 8) * 64]);
        }
    };

    stageA(0, 0); stageB(0, 0);
    stageA(1, 1); stageB(1, 1);

    for (int kt = 0; kt < 18; ++kt) {
        if (kt < 17) asm volatile("s_waitcnt vmcnt(6)" ::: "memory");
        else         asm volatile("s_waitcnt vmcnt(0)" ::: "memory");
        __builtin_amdgcn_s_barrier();
        asm volatile("" ::: "memory");

        const int cur = kt % 3;
        const int nxt = (kt + 2) % 3;
        const char* Ab = (const char*)Asm[cur];
        const char* Bb = (const char*)Bsm[cur];

        // phase A (ks = 0)
        {
            bf16x8 a[4], b[4];
            const int csw = fq;
            #pragma unroll
            for (int mi = 0; mi < 4; ++mi) {
                int r = wr * 64 + mi * 16 + fr;
                a[mi] = *reinterpret_cast<const bf16x8*>(
                    Ab + r * 128 + ((csw ^ (fr & 7)) << 4));
            }
            #pragma unroll
            for (int ni = 0; ni < 4; ++ni) {
                int r = wc * 64 + ni * 16 + fr;
                b[ni] = *reinterpret_cast<const bf16x8*>(
                    Bb + r * 128 + ((csw ^ (fr & 7)) << 4));
            }
            if (kt + 2 < 18) stageA(nxt, kt + 2);
            __builtin_amdgcn_s_setprio(1);
            #pragma unroll
            for (int mi = 0; mi < 4; ++mi)
                #pragma unroll
                for (int ni = 0; ni < 4; ++ni)
                    acc[mi][ni] = __builtin_amdgcn_mfma_f32_16x16x32_bf16(
                        a[mi], b[ni], acc[mi][ni], 0, 0, 0);
            __builtin_amdgcn_s_setprio(0);
        }
        __builtin_amdgcn_s_barrier();
        asm volatile("" ::: "memory");

        // phase B (ks = 1)
        {
            bf16x8 a[4], b[4];
            const int csw = 4 + fq;
            #pragma unroll
            for (int mi = 0; mi < 4; ++mi) {
                int r = wr * 64 + mi * 16 + fr;
                a[mi] = *reinterpret_cast<const bf16x8*>(
                    Ab + r * 128 + ((csw ^ (fr & 7)) << 4));
            }
            #pragma unroll
            for (int ni = 0; ni < 4; ++ni) {
                int r = wc * 64 + ni * 16 + fr;
                b[ni] = *reinterpret_cast<const bf16x8*>(
                    Bb + r * 128 + ((csw ^ (fr & 7)) << 4));
            }
            if (kt + 2 < 18) stageB(nxt, kt + 2);
            __builtin_amdgcn_s_setprio(1);
            #pragma unroll
            for (int mi = 0; mi < 4; ++mi)
                #pragma unroll
                for (int ni = 0; ni < 4; ++ni)
                    acc[mi][ni] = __builtin_amdgcn_mfma_f32_16x16x32_bf16(
                        a[mi], b[ni], acc[mi][ni], 0, 0, 0);
            __builtin_amdgcn_s_setprio(0);
        }
    }

    #pragma unroll
    for (int ni = 0; ni < 4; ++ni) {
        int oc = n0 + wc * 64 + ni * 16 + fr;
        if (oc >= PGC) continue;
        float bias = pgb[oc];
        #pragma unroll
        for (int mi = 0; mi < 4; ++mi) {
            int pxq = m0 + wr * 64 + mi * 16 + fq * 4;
            #pragma unroll
            for (int r = 0; r < 4; ++r) {
                int pxd = pxq + r;
                if (pxd >= Bn * XROW) continue;
                int bb = pxd / XROW;
                int rem = pxd - bb * XROW;
                int yy = rem / 66 - 1;
                int xx = rem - (yy + 1) * 66 - 1;
                if ((unsigned)yy < 64u && (unsigned)xx < 64u)
                    pgBF[((size_t)(bb * PGC + oc)) * HW + yy * 64 + xx] =
                        f2bf(acc[mi][ni][r] + bias);
            }
        }
    }
}

// ---------------------------------------------------------------------------
// sample: 1D grid with bijective XCD swizzle; inner order (batch, gk, pxb)
// so each XCD works one batch -> XTG slab (1.1MB) + pg slab (3.1MB) are
// L2-resident and gathers hit L2.  Thread = (pixel, (g,k) tap), planar
// 16B corner loads; writes tiled S [px/128][ck/8][px%128][8ch].
// ---------------------------------------------------------------------------
__global__ __launch_bounds__(256) void sample_kernel(
    const unsigned short* __restrict__ XTG, const unsigned short* __restrict__ pg,
    unsigned short* __restrict__ S, int px_base)
{
    // bijective XCD swizzle (gridDim.x % 8 == 0 for all nh paths)
    const int cpx = gridDim.x >> 3;
    const int swz = (blockIdx.x & 7) * cpx + (blockIdx.x >> 3);
    const int bloc = swz / 2016;             // local batch (2016 = 126 gk * 16 pxb)
    const int rem  = swz - bloc * 2016;
    const int gk   = rem >> 4;               // 0..125
    const int pxb  = rem & 15;
    const int pxl  = (bloc << 12) + (pxb << 8) + threadIdx.x;

    const int g = gk / 9, k = gk - 9 * g;
    const int pxg = px_base + pxl;
    const int b = pxg >> 12, hw = pxg & 4095;
    const int y = hw >> 6, xc = hw & 63;
    const int pblk = pxl >> 7, prem = pxl & 127;

    if (gk == 0) {   // zero K-pad blocks cb = 126, 127
        const uint4 z = {0, 0, 0, 0};
        *reinterpret_cast<uint4*>(
            &S[(((size_t)pblk * 128 + 126) * 128 + prem) * 8]) = z;
        *reinterpret_cast<uint4*>(
            &S[(((size_t)pblk * 128 + 127) * 128 + prem) * 8]) = z;
    }

    const unsigned short* pgb = pg + (size_t)b * PGC * HW + hw;
    float dy = bf2f(pgb[(size_t)(18 * g + 2 * k) * HW]);
    float dx = bf2f(pgb[(size_t)(18 * g + 2 * k + 1) * HW]);
    float mv = bf2f(pgb[(size_t)(252 + 9 * g + k) * HW]);
    float m  = 1.f / (1.f + __expf(-mv));

    const int ky = k / 3, kx = k % 3;
    float yf = (float)(y + ky - 1) + dy;
    float xf = (float)(xc + kx - 1) + dx;
    float y0 = floorf(yf), x0 = floorf(xf);
    float wy1 = yf - y0, wx1 = xf - x0;
    float wy0 = 1.f - wy1, wx0 = 1.f - wx1;
    int iy0 = (int)y0, ix0 = (int)x0;
    bool vy0 = (iy0 >= 0) && (iy0 < Hn);
    bool vy1 = (iy0 >= -1) && (iy0 < Hn - 1);
    bool vx0 = (ix0 >= 0) && (ix0 < Wn);
    bool vx1 = (ix0 >= -1) && (ix0 < Wn - 1);
    int cy0 = min(max(iy0, 0), Hn - 1), cy1 = min(max(iy0 + 1, 0), Hn - 1);
    int cx0 = min(max(ix0, 0), Wn - 1), cx1 = min(max(ix0 + 1, 0), Wn - 1);
    float w00 = (vy0 && vx0) ? wy0 * wx0 * m : 0.f;
    float w01 = (vy0 && vx1) ? wy0 * wx1 * m : 0.f;
    float w10 = (vy1 && vx0) ? wy1 * wx0 * m : 0.f;
    float w11 = (vy1 && vx1) ? wy1 * wx1 * m : 0.f;

    const unsigned short* xg = XTG +
        ((size_t)g * PLANE_ROWS + (size_t)b * XROW) * 8;
    const int r00 = (cy0 + 1) * 66 + cx0 + 1, r01 = (cy0 + 1) * 66 + cx1 + 1;
    const int r10 = (cy1 + 1) * 66 + cx0 + 1, r11 = (cy1 + 1) * 66 + cx1 + 1;
    uint4 q00 = *reinterpret_cast<const uint4*>(xg + (size_t)r00 * 8);
    uint4 q01 = *reinterpret_cast<const uint4*>(xg + (size_t)r01 * 8);
    uint4 q10 = *reinterpret_cast<const uint4*>(xg + (size_t)r10 * 8);
    uint4 q11 = *reinterpret_cast<const uint4*>(xg + (size_t)r11 * 8);

    unsigned int c00[4] = {q00.x, q00.y, q00.z, q00.w};
    unsigned int c01[4] = {q01.x, q01.y, q01.z, q01.w};
    unsigned int c10[4] = {q10.x, q10.y, q10.z, q10.w};
    unsigned int c11[4] = {q11.x, q11.y, q11.z, q11.w};

    unsigned int pk[4];
    #pragma unroll
    for (int j = 0; j < 4; ++j) {
        float lo = bflo(c00[j]) * w00 + bflo(c01[j]) * w01 +
                   bflo(c10[j]) * w10 + bflo(c11[j]) * w11;
        float hi = bfhi(c00[j]) * w00 + bfhi(c01[j]) * w01 +
                   bfhi(c10[j]) * w10 + bfhi(c11[j]) * w11;
        pk[j] = (unsigned int)f2bf(lo) | ((unsigned int)f2bf(hi) << 16);
    }
    *reinterpret_cast<uint4*>(
        &S[(((size_t)pblk * 128 + gk) * 128 + prem) * 8]) =
        *reinterpret_cast<const uint4*>(pk);
}

// ---------------------------------------------------------------------------
// main GEMM: out[b][oc][hw] = S_tiled[px][ck] * WB[oc][ck] + bias[oc]
// Double-buffered prefetch, counted vmcnt (validated rounds 9-14).
// ---------------------------------------------------------------------------
__global__ __launch_bounds__(256) void main_gemm_kernel(
    const unsigned short* __restrict__ S, const unsigned short* __restrict__ WB,
    const float* __restrict__ bias, float* __restrict__ out, int px_base)
{
    __shared__ __align__(16) unsigned short Asm[2][128 * 32];
    __shared__ __align__(16) unsigned short Bsm[2][128 * 32];

    const int tid  = threadIdx.x;
    const int lane = tid & 63;
    const int w    = tid >> 6;
    const int wr   = w >> 1, wc = w & 1;
    const int m0   = blockIdx.x * 128;
    const int fr   = lane & 15, fq = lane >> 4;

    f32x4 acc[4][4] = {};

    const int ldr = lane >> 2;
    const int lq  = lane & 3;
    const int ldc = lq * 8;

    auto stage = [&](int buf, int kt) {
        #pragma unroll
        for (int i = 0; i < 2; ++i) {
            int row = w * 32 + i * 16 + ldr;
            int cb  = kt * 4 + lq;
            gload_lds16(&S[(((size_t)blockIdx.x * 128 + cb) * 128 + row) * 8],
                        &Asm[buf][(w * 32 + i * 16) * 32]);
            gload_lds16(&WB[(size_t)row * KP + kt * 32 + ldc],
                        &Bsm[buf][(w * 32 + i * 16) * 32]);
        }
    };

    stage(0, 0);
    int cur = 0;
    for (int kt = 0; kt < 32; ++kt) {
        if (kt + 1 < 32) {
            stage(cur ^ 1, kt + 1);
            asm volatile("s_waitcnt vmcnt(4)" ::: "memory");
        } else {
            asm volatile("s_waitcnt vmcnt(0)" ::: "memory");
        }
        __builtin_amdgcn_s_barrier();
        asm volatile("" ::: "memory");

        bf16x8 a[4], b[4];
        #pragma unroll
        for (int mi = 0; mi < 4; ++mi)
            a[mi] = *reinterpret_cast<const bf16x8*>(
                &Asm[cur][(wr * 64 + mi * 16 + fr) * 32 + fq * 8]);
        #pragma unroll
        for (int ni = 0; ni < 4; ++ni)
            b[ni] = *reinterpret_cast<const bf16x8*>(
                &Bsm[cur][(wc * 64 + ni * 16 + fr) * 32 + fq * 8]);
        #pragma unroll
        for (int mi = 0; mi < 4; ++mi)
            #pragma unroll
            for (int ni = 0; ni < 4; ++ni)
                acc[mi][ni] = __builtin_amdgcn_mfma_f32_16x16x32_bf16(
                    a[mi], b[ni], acc[mi][ni], 0, 0, 0);

        asm volatile("s_waitcnt lgkmcnt(0)" ::: "memory");
        __builtin_amdgcn_s_barrier();
        asm volatile("" ::: "memory");
        cur ^= 1;
    }

    #pragma unroll
    for (int ni = 0; ni < 4; ++ni) {
        int oc = wc * 64 + ni * 16 + fr;
        if (oc >= On) continue;
        float bv = bias[oc];
        #pragma unroll
        for (int mi = 0; mi < 4; ++mi) {
            int pxl = m0 + wr * 64 + mi * 16 + fq * 4;
            int pxg = px_base + pxl;
            int b = pxg >> 12, hw = pxg & 4095;
            float4 o;
            o.x = acc[mi][ni][0] + bv;
            o.y = acc[mi][ni][1] + bv;
            o.z = acc[mi][ni][2] + bv;
            o.w = acc[mi][ni][3] + bv;
            *reinterpret_cast<float4*>(
                &out[((size_t)(b * On + oc)) * HW + hw]) = o;
        }
    }
}

// ---------------------------------------------------------------------------
extern "C" void kernel_launch(void* const* d_in, const int* in_sizes, int n_in,
                              void* d_out, int out_size, void* d_ws, size_t ws_size,
                              hipStream_t stream) {
    const float* x    = (const float*)d_in[0];
    const float* pgw  = (const float*)d_in[1];
    const float* pgb  = (const float*)d_in[2];
    const float* w    = (const float*)d_in[3];
    const float* bias = (const float*)d_in[4];
    float* out = (float*)d_out;

    char* wsb = (char*)d_ws;
    unsigned short* pgBF = (unsigned short*)wsb;                 // 24.77 MB
    size_t off = (size_t)PGC * Bn * HW * 2;
    unsigned short* B2   = (unsigned short*)(wsb + off);         // 0.88 MB
    off += (size_t)NP * KSH * 2;
    unsigned short* WB   = (unsigned short*)(wsb + off);         // 0.26 MB
    off += (size_t)128 * KP * 2;
    unsigned short* XTGa = (unsigned short*)(wsb + off);         // 8.93 MB
    unsigned short* XTG  = XTGa + (size_t)XGUARD * 8;            // guarded base
    off += (size_t)XTG_ROWS_TOTAL * 16;
    unsigned short* S    = (unsigned short*)(wsb + off);         // sampled (tiled)

    const size_t sfull = (size_t)MFULL * KP * 2;                 // 67.1 MB
    int nh;
    if (ws_size >= off + sfull)          nh = 1;   // ~102 MB total
    else if (ws_size >= off + sfull / 2) nh = 2;
    else                                 nh = 4;
    const int cnt = MFULL / nh;

    // prep: zero XTG + build B2 + WB
    {
        int tot = ZN + B2N + WBN;
        prep_kernel<<<(tot + 255) / 256, 256, 0, stream>>>(pgw, w, XTGa, B2, WB);
    }
    // transpose x -> XTG (group-planar NHWC bf16, 66x66 halo)
    xpose_kernel<<<dim3(Hn, Bn), 256, 0, stream>>>(x, XTG);

    // pg conv: 256x128/BK=64, 8 waves, T2 swizzle, phase-split pipeline
    pg_shift_kernel<<<dim3(PG_MT, NP / 128), 512, 0, stream>>>(
        XTG, B2, pgb, pgBF);

    // deformable sampling (XCD-batch-affine 1D grid) -> tiled S, then main GEMM
    for (int h = 0; h < nh; ++h) {
        int nblk = (cnt >> 12) * 2016;   // batches_in_chunk * (126 gk * 16 pxb)
        sample_kernel<<<dim3(nblk), 256, 0, stream>>>(
            XTG, pgBF, S, h * cnt);
        main_gemm_kernel<<<dim3(cnt / 128, 1), 256, 0, stream>>>(
            S, WB, bias, out, h * cnt);
    }
}

// Round 16
// 116.848 us; speedup vs baseline: 1.5975x; 1.1920x over previous
//
#include <hip/hip_runtime.h>
#include <math.h>

#define Bn 8
#define Cn 112
#define Hn 64
#define Wn 64
#define On 112
#define Gn 14
#define PGC 378          // 3*G*K2
#define HW 4096          // 64*64
#define CKW 1008         // C*K2
#define KP 1024          // padded K (main GEMM and dense pg GEMM)
#define NP 384           // padded N (oc) for pg GEMM
#define MFULL 32768
#define XROW 4356        // 66*66 rows per batch
#define PG_MT 137        // M-tiles of 256
#define MPAD (PG_MT * 256)                 // 35072
#define PLANE_ROWS 34848                   // 8 batches * 4356 rows per plane
#define XGUARD 67
#define XTG_ROWS_TOTAL 558080              // padded alloc rows (>= 15 planes + guards)

typedef __attribute__((ext_vector_type(8))) short bf16x8;
typedef __attribute__((ext_vector_type(4))) float f32x4;

__device__ __forceinline__ unsigned short f2bf(float f) {
    union { float f; unsigned int u; } v; v.f = f;
    unsigned int r = v.u + 0x7fffu + ((v.u >> 16) & 1u);
    return (unsigned short)(r >> 16);
}
__device__ __forceinline__ float bf2f(unsigned short u) {
    union { unsigned int u; float f; } v; v.u = ((unsigned int)u) << 16;
    return v.f;
}
__device__ __forceinline__ float bflo(unsigned int u) {
    union { unsigned int u; float f; } v; v.u = u << 16; return v.f;
}
__device__ __forceinline__ float bfhi(unsigned int u) {
    union { unsigned int u; float f; } v; v.u = u & 0xffff0000u; return v.f;
}
__device__ __forceinline__ void gload_lds16(const void* g, void* l) {
    __builtin_amdgcn_global_load_lds(
        (const __attribute__((address_space(1))) unsigned int*)g,
        (__attribute__((address_space(3))) unsigned int*)l, 16, 0, 0);
}

// ---------------------------------------------------------------------------
// prep (merged): zero XTG alloc | B2 dense [384][1024] | WB [128][1024]
// B2[oc][p_g*8+cc] = pgw[oc][(p_g%14)*8+cc][p_g/14],  p_g<126 (else 0)
// ---------------------------------------------------------------------------
#define ZN XTG_ROWS_TOTAL
#define B2N (NP * KP)
#define WBN (128 * KP)
__global__ __launch_bounds__(256) void prep_kernel(
    const float* __restrict__ pgw, const float* __restrict__ w,
    unsigned short* __restrict__ XTGa, unsigned short* __restrict__ B2,
    unsigned short* __restrict__ WB)
{
    int t = blockIdx.x * 256 + threadIdx.x;
    if (t < ZN) {
        const uint4 z = {0, 0, 0, 0};
        reinterpret_cast<uint4*>(XTGa)[t] = z;
        return;
    }
    t -= ZN;
    if (t < B2N) {
        int oc = t >> 10, ck = t & 1023;
        int pg_ = ck >> 3, cc = ck & 7;
        int tap = pg_ / 14, pl = pg_ % 14;
        float v = (pg_ < 126 && oc < PGC)
            ? pgw[(size_t)oc * CKW + (pl * 8 + cc) * 9 + tap] : 0.f;
        B2[t] = f2bf(v);
        return;
    }
    t -= B2N;
    if (t < WBN) {
        int oc = t >> 10, ck = t & 1023;
        float v = 0.f;
        if (oc < On && ck < CKW) {
            int g = ck / 72, r = ck % 72;
            int k = r >> 3, cc = r & 7;
            v = w[(size_t)oc * CKW + (g * 8 + cc) * 9 + k];
        }
        WB[t] = f2bf(v);
    }
}

// ---------------------------------------------------------------------------
// xpose: x NCHW f32 -> XTG bf16 planes [g][b][row66x66][8ch]
// ---------------------------------------------------------------------------
__global__ __launch_bounds__(256) void xpose_kernel(
    const float* __restrict__ x, unsigned short* __restrict__ XTG)
{
    __shared__ unsigned short lds[64][136];

    const int tid = threadIdx.x;
    const int y = blockIdx.x, b = blockIdx.y;
    const int xx = tid & 63, cw = tid >> 6;

    const float* xb = x + (size_t)b * Cn * HW + y * 64;
    #pragma unroll
    for (int p = 0; p < 28; ++p) {
        int c = p * 4 + cw;
        lds[xx][c] = f2bf(xb[(size_t)c * HW + xx]);
    }
    __syncthreads();

    #pragma unroll
    for (int q = 0; q < 4; ++q) {
        int task = q * 256 + tid;            // 0..895 used (64 xx * 14 g)
        if (task < 896) {
            int g = task >> 6;
            int x2 = task & 63;
            unsigned short* dst = XTG + ((size_t)g * PLANE_ROWS
                + (size_t)b * XROW + (y + 1) * 66 + x2 + 1) * 8;
            *reinterpret_cast<uint4*>(dst) =
                *reinterpret_cast<const uint4*>(&lds[x2][g * 8]);
        }
    }
}

// ---------------------------------------------------------------------------
// pg shift-GEMM v6: dense-K (1024, 16 K-tiles of 8 planes), 256x128 tile,
// 8 waves (4M x 2N), per-wave 64x64.  T2 XOR-swizzled LDS, 3 buffers,
// counted vmcnt(6), phase-split, setprio.  Per-lane plane index carries its
// own tap-shift (dense packing crosses tap boundaries).
// Epilogue: acc(+bias) -> LDS transpose T[oc][px] -> lane=pixel coalesced
// stores with one divmod chain per thread.
// ---------------------------------------------------------------------------
__global__ __launch_bounds__(512, 1) void pg_shift_kernel(
    const unsigned short* __restrict__ XTG, const unsigned short* __restrict__ B2,
    const float* __restrict__ pgb, unsigned short* __restrict__ pgBF)
{
    __shared__ __align__(16) unsigned short Asm[3][256 * 64];   // 96 KB
    __shared__ __align__(16) unsigned short Bsm[3][128 * 64];   // 48 KB

    const int tid  = threadIdx.x;
    const int lane = tid & 63;
    const int w    = tid >> 6;          // 0..7
    const int wr   = w >> 1;            // 0..3  (M)
    const int wc   = w & 1;             // 0..1  (N)
    const int m0   = blockIdx.x * 256;
    const int n0   = blockIdx.y * 128;
    const int fr   = lane & 15, fq = lane >> 4;
    const int lr8  = lane >> 3;
    const int lc8  = lane & 7;

    f32x4 acc[4][4] = {};

    auto asrc = [&](int kt, int r) -> const unsigned short* {
        int pg_ = kt * 8 + (lc8 ^ (r & 7));
        int tap = pg_ / 14, pl = pg_ % 14;
        int shift = (tap / 3 - 1) * 66 + (tap % 3) - 1;
        if (pg_ >= 126) { pl = 14; shift = 0; }
        return XTG + ((long)pl * PLANE_ROWS + (long)(m0 + r) + shift) * 8;
    };

    auto stageA = [&](int buf, int kt) {
        #pragma unroll
        for (int s = 0; s < 2; ++s) {
            int r = w * 32 + s * 8 + lr8;
            gload_lds16(asrc(kt, r), &Asm[buf][(w * 32 + s * 8) * 64]);
        }
        {
            int r = w * 16 + lr8;
            int cl = lc8 ^ (r & 7);
            gload_lds16(&B2[(size_t)(n0 + r) * KP + kt * 64 + cl * 8],
                        &Bsm[buf][(w * 16) * 64]);
        }
    };
    auto stageB = [&](int buf, int kt) {
        #pragma unroll
        for (int s = 2; s < 4; ++s) {
            int r = w * 32 + s * 8 + lr8;
            gload_lds16(asrc(kt, r), &Asm[buf][(w * 32 + s * 8) * 64]);
        }
        {
            int r = w * 16 + 8 + lr8;
            int cl = lc8 ^ (r & 7);
            gload_lds16(&B2[(size_t)(n0 + r) * KP + kt * 64 + cl * 8],
                        &Bsm[buf][(w * 16 + 8) * 64]);
        }
    };

    stageA(0, 0); stageB(0, 0);
    stageA(1, 1); stageB(1, 1);

    for (int kt = 0; kt < 16; ++kt) {
        if (kt < 15) asm volatile("s_waitcnt vmcnt(6)" ::: "memory");
        else         asm volatile("s_waitcnt vmcnt(0)" ::: "memory");
        __builtin_amdgcn_s_barrier();
        asm volatile("" ::: "memory");

        const int cur = kt % 3;
        const int nxt = (kt + 2) % 3;
        const char* Ab = (const char*)Asm[cur];
        const char* Bb = (const char*)Bsm[cur];

        // phase A (ks = 0)
        {
            bf16x8 a[4], b[4];
            const int csw = fq;
            #pragma unroll
            for (int mi = 0; mi < 4; ++mi) {
                int r = wr * 64 + mi * 16 + fr;
                a[mi] = *reinterpret_cast<const bf16x8*>(
                    Ab + r * 128 + ((csw ^ (fr & 7)) << 4));
            }
            #pragma unroll
            for (int ni = 0; ni < 4; ++ni) {
                int r = wc * 64 + ni * 16 + fr;
                b[ni] = *reinterpret_cast<const bf16x8*>(
                    Bb + r * 128 + ((csw ^ (fr & 7)) << 4));
            }
            if (kt + 2 < 16) stageA(nxt, kt + 2);
            __builtin_amdgcn_s_setprio(1);
            #pragma unroll
            for (int mi = 0; mi < 4; ++mi)
                #pragma unroll
                for (int ni = 0; ni < 4; ++ni)
                    acc[mi][ni] = __builtin_amdgcn_mfma_f32_16x16x32_bf16(
                        a[mi], b[ni], acc[mi][ni], 0, 0, 0);
            __builtin_amdgcn_s_setprio(0);
        }
        __builtin_amdgcn_s_barrier();
        asm volatile("" ::: "memory");

        // phase B (ks = 1)
        {
            bf16x8 a[4], b[4];
            const int csw = 4 + fq;
            #pragma unroll
            for (int mi = 0; mi < 4; ++mi) {
                int r = wr * 64 + mi * 16 + fr;
                a[mi] = *reinterpret_cast<const bf16x8*>(
                    Ab + r * 128 + ((csw ^ (fr & 7)) << 4));
            }
            #pragma unroll
            for (int ni = 0; ni < 4; ++ni) {
                int r = wc * 64 + ni * 16 + fr;
                b[ni] = *reinterpret_cast<const bf16x8*>(
                    Bb + r * 128 + ((csw ^ (fr & 7)) << 4));
            }
            if (kt + 2 < 16) stageB(nxt, kt + 2);
            __builtin_amdgcn_s_setprio(1);
            #pragma unroll
            for (int mi = 0; mi < 4; ++mi)
                #pragma unroll
                for (int ni = 0; ni < 4; ++ni)
                    acc[mi][ni] = __builtin_amdgcn_mfma_f32_16x16x32_bf16(
                        a[mi], b[ni], acc[mi][ni], 0, 0, 0);
            __builtin_amdgcn_s_setprio(0);
        }
    }

    // ---------------- epilogue: LDS transpose + coalesced store -----------
    __builtin_amdgcn_s_barrier();           // all LDS reads of Asm done
    unsigned short* T = (unsigned short*)Asm;   // [128 oc][264 px-stride]

    #pragma unroll
    for (int ni = 0; ni < 4; ++ni) {
        int ocl = wc * 64 + ni * 16 + fr;
        float bv = (n0 + ocl < PGC) ? pgb[n0 + ocl] : 0.f;
        #pragma unroll
        for (int mi = 0; mi < 4; ++mi) {
            int pxl = wr * 64 + mi * 16 + fq * 4;
            ushort4 pk;
            pk.x = f2bf(acc[mi][ni][0] + bv);
            pk.y = f2bf(acc[mi][ni][1] + bv);
            pk.z = f2bf(acc[mi][ni][2] + bv);
            pk.w = f2bf(acc[mi][ni][3] + bv);
            *reinterpret_cast<ushort4*>(&T[ocl * 264 + pxl]) = pk;
        }
    }
    __builtin_amdgcn_s_barrier();

    const int pxls = tid & 255;
    const int half = tid >> 8;
    const int pxd  = m0 + pxls;
    const int bb   = pxd / XROW;
    const int rem  = pxd - bb * XROW;
    const int yy   = rem / 66 - 1;
    const int xx   = rem - (yy + 1) * 66 - 1;
    const bool valid = (pxd < Bn * XROW) &&
                       ((unsigned)yy < 64u) && ((unsigned)xx < 64u);
    unsigned short* pbase = pgBF + (size_t)bb * PGC * HW + yy * 64 + xx;

    #pragma unroll 4
    for (int oc = 0; oc < 64; ++oc) {
        int ocg = n0 + half * 64 + oc;
        if (ocg >= PGC) break;               // wave-uniform
        unsigned short v = T[(half * 64 + oc) * 264 + pxls];
        if (valid) pbase[(size_t)ocg * HW] = v;
    }
}

// ---------------------------------------------------------------------------
// sample: 1D grid with bijective XCD swizzle; inner order (batch, gk, pxb)
// so each XCD works one batch.  Thread = (pixel, (g,k) tap), planar 16B
// corner loads; writes tiled S [px/128][ck/8][px%128][8ch].
// ---------------------------------------------------------------------------
__global__ __launch_bounds__(256) void sample_kernel(
    const unsigned short* __restrict__ XTG, const unsigned short* __restrict__ pg,
    unsigned short* __restrict__ S, int px_base)
{
    const int cpx = gridDim.x >> 3;
    const int swz = (blockIdx.x & 7) * cpx + (blockIdx.x >> 3);
    const int bloc = swz / 2016;             // local batch (126 gk * 16 pxb)
    const int rem  = swz - bloc * 2016;
    const int gk   = rem >> 4;               // 0..125
    const int pxb  = rem & 15;
    const int pxl  = (bloc << 12) + (pxb << 8) + threadIdx.x;

    const int g = gk / 9, k = gk - 9 * g;
    const int pxg = px_base + pxl;
    const int b = pxg >> 12, hw = pxg & 4095;
    const int y = hw >> 6, xc = hw & 63;
    const int pblk = pxl >> 7, prem = pxl & 127;

    if (gk == 0) {   // zero K-pad blocks cb = 126, 127
        const uint4 z = {0, 0, 0, 0};
        *reinterpret_cast<uint4*>(
            &S[(((size_t)pblk * 128 + 126) * 128 + prem) * 8]) = z;
        *reinterpret_cast<uint4*>(
            &S[(((size_t)pblk * 128 + 127) * 128 + prem) * 8]) = z;
    }

    const unsigned short* pgb = pg + (size_t)b * PGC * HW + hw;
    float dy = bf2f(pgb[(size_t)(18 * g + 2 * k) * HW]);
    float dx = bf2f(pgb[(size_t)(18 * g + 2 * k + 1) * HW]);
    float mv = bf2f(pgb[(size_t)(252 + 9 * g + k) * HW]);
    float m  = 1.f / (1.f + __expf(-mv));

    const int ky = k / 3, kx = k % 3;
    float yf = (float)(y + ky - 1) + dy;
    float xf = (float)(xc + kx - 1) + dx;
    float y0 = floorf(yf), x0 = floorf(xf);
    float wy1 = yf - y0, wx1 = xf - x0;
    float wy0 = 1.f - wy1, wx0 = 1.f - wx1;
    int iy0 = (int)y0, ix0 = (int)x0;
    bool vy0 = (iy0 >= 0) && (iy0 < Hn);
    bool vy1 = (iy0 >= -1) && (iy0 < Hn - 1);
    bool vx0 = (ix0 >= 0) && (ix0 < Wn);
    bool vx1 = (ix0 >= -1) && (ix0 < Wn - 1);
    int cy0 = min(max(iy0, 0), Hn - 1), cy1 = min(max(iy0 + 1, 0), Hn - 1);
    int cx0 = min(max(ix0, 0), Wn - 1), cx1 = min(max(ix0 + 1, 0), Wn - 1);
    float w00 = (vy0 && vx0) ? wy0 * wx0 * m : 0.f;
    float w01 = (vy0 && vx1) ? wy0 * wx1 * m : 0.f;
    float w10 = (vy1 && vx0) ? wy1 * wx0 * m : 0.f;
    float w11 = (vy1 && vx1) ? wy1 * wx1 * m : 0.f;

    const unsigned short* xg = XTG +
        ((size_t)g * PLANE_ROWS + (size_t)b * XROW) * 8;
    const int r00 = (cy0 + 1) * 66 + cx0 + 1, r01 = (cy0 + 1) * 66 + cx1 + 1;
    const int r10 = (cy1 + 1) * 66 + cx0 + 1, r11 = (cy1 + 1) * 66 + cx1 + 1;
    uint4 q00 = *reinterpret_cast<const uint4*>(xg + (size_t)r00 * 8);
    uint4 q01 = *reinterpret_cast<const uint4*>(xg + (size_t)r01 * 8);
    uint4 q10 = *reinterpret_cast<const uint4*>(xg + (size_t)r10 * 8);
    uint4 q11 = *reinterpret_cast<const uint4*>(xg + (size_t)r11 * 8);

    unsigned int c00[4] = {q00.x, q00.y, q00.z, q00.w};
    unsigned int c01[4] = {q01.x, q01.y, q01.z, q01.w};
    unsigned int c10[4] = {q10.x, q10.y, q10.z, q10.w};
    unsigned int c11[4] = {q11.x, q11.y, q11.z, q11.w};

    unsigned int pk[4];
    #pragma unroll
    for (int j = 0; j < 4; ++j) {
        float lo = bflo(c00[j]) * w00 + bflo(c01[j]) * w01 +
                   bflo(c10[j]) * w10 + bflo(c11[j]) * w11;
        float hi = bfhi(c00[j]) * w00 + bfhi(c01[j]) * w01 +
                   bfhi(c10[j]) * w10 + bfhi(c11[j]) * w11;
        pk[j] = (unsigned int)f2bf(lo) | ((unsigned int)f2bf(hi) << 16);
    }
    *reinterpret_cast<uint4*>(
        &S[(((size_t)pblk * 128 + gk) * 128 + prem) * 8]) =
        *reinterpret_cast<const uint4*>(pk);
}

// ---------------------------------------------------------------------------
// main GEMM: out[b][oc][hw] = S_tiled[px][ck] * WB[oc][ck] + bias[oc]
// Double-buffered prefetch, counted vmcnt (validated rounds 9-15).
// ---------------------------------------------------------------------------
__global__ __launch_bounds__(256) void main_gemm_kernel(
    const unsigned short* __restrict__ S, const unsigned short* __restrict__ WB,
    const float* __restrict__ bias, float* __restrict__ out, int px_base)
{
    __shared__ __align__(16) unsigned short Asm[2][128 * 32];
    __shared__ __align__(16) unsigned short Bsm[2][128 * 32];

    const int tid  = threadIdx.x;
    const int lane = tid & 63;
    const int w    = tid >> 6;
    const int wr   = w >> 1, wc = w & 1;
    const int m0   = blockIdx.x * 128;
    const int fr   = lane & 15, fq = lane >> 4;

    f32x4 acc[4][4] = {};

    const int ldr = lane >> 2;
    const int lq  = lane & 3;
    const int ldc = lq * 8;

    auto stage = [&](int buf, int kt) {
        #pragma unroll
        for (int i = 0; i < 2; ++i) {
            int row = w * 32 + i * 16 + ldr;
            int cb  = kt * 4 + lq;
            gload_lds16(&S[(((size_t)blockIdx.x * 128 + cb) * 128 + row) * 8],
                        &Asm[buf][(w * 32 + i * 16) * 32]);
            gload_lds16(&WB[(size_t)row * KP + kt * 32 + ldc],
                        &Bsm[buf][(w * 32 + i * 16) * 32]);
        }
    };

    stage(0, 0);
    int cur = 0;
    for (int kt = 0; kt < 32; ++kt) {
        if (kt + 1 < 32) {
            stage(cur ^ 1, kt + 1);
            asm volatile("s_waitcnt vmcnt(4)" ::: "memory");
        } else {
            asm volatile("s_waitcnt vmcnt(0)" ::: "memory");
        }
        __builtin_amdgcn_s_barrier();
        asm volatile("" ::: "memory");

        bf16x8 a[4], b[4];
        #pragma unroll
        for (int mi = 0; mi < 4; ++mi)
            a[mi] = *reinterpret_cast<const bf16x8*>(
                &Asm[cur][(wr * 64 + mi * 16 + fr) * 32 + fq * 8]);
        #pragma unroll
        for (int ni = 0; ni < 4; ++ni)
            b[ni] = *reinterpret_cast<const bf16x8*>(
                &Bsm[cur][(wc * 64 + ni * 16 + fr) * 32 + fq * 8]);
        #pragma unroll
        for (int mi = 0; mi < 4; ++mi)
            #pragma unroll
            for (int ni = 0; ni < 4; ++ni)
                acc[mi][ni] = __builtin_amdgcn_mfma_f32_16x16x32_bf16(
                    a[mi], b[ni], acc[mi][ni], 0, 0, 0);

        asm volatile("s_waitcnt lgkmcnt(0)" ::: "memory");
        __builtin_amdgcn_s_barrier();
        asm volatile("" ::: "memory");
        cur ^= 1;
    }

    #pragma unroll
    for (int ni = 0; ni < 4; ++ni) {
        int oc = wc * 64 + ni * 16 + fr;
        if (oc >= On) continue;
        float bv = bias[oc];
        #pragma unroll
        for (int mi = 0; mi < 4; ++mi) {
            int pxl = m0 + wr * 64 + mi * 16 + fq * 4;
            int pxg = px_base + pxl;
            int b = pxg >> 12, hw = pxg & 4095;
            float4 o;
            o.x = acc[mi][ni][0] + bv;
            o.y = acc[mi][ni][1] + bv;
            o.z = acc[mi][ni][2] + bv;
            o.w = acc[mi][ni][3] + bv;
            *reinterpret_cast<float4*>(
                &out[((size_t)(b * On + oc)) * HW + hw]) = o;
        }
    }
}

// ---------------------------------------------------------------------------
extern "C" void kernel_launch(void* const* d_in, const int* in_sizes, int n_in,
                              void* d_out, int out_size, void* d_ws, size_t ws_size,
                              hipStream_t stream) {
    const float* x    = (const float*)d_in[0];
    const float* pgw  = (const float*)d_in[1];
    const float* pgb  = (const float*)d_in[2];
    const float* w    = (const float*)d_in[3];
    const float* bias = (const float*)d_in[4];
    float* out = (float*)d_out;

    char* wsb = (char*)d_ws;
    unsigned short* pgBF = (unsigned short*)wsb;                 // 24.77 MB
    size_t off = (size_t)PGC * Bn * HW * 2;
    unsigned short* B2   = (unsigned short*)(wsb + off);         // 0.79 MB
    off += (size_t)NP * KP * 2;
    unsigned short* WB   = (unsigned short*)(wsb + off);         // 0.26 MB
    off += (size_t)128 * KP * 2;
    unsigned short* XTGa = (unsigned short*)(wsb + off);         // 8.93 MB
    unsigned short* XTG  = XTGa + (size_t)XGUARD * 8;            // guarded base
    off += (size_t)XTG_ROWS_TOTAL * 16;
    unsigned short* S    = (unsigned short*)(wsb + off);         // sampled (tiled)

    const size_t sfull = (size_t)MFULL * KP * 2;                 // 67.1 MB
    int nh;
    if (ws_size >= off + sfull)          nh = 1;   // ~102 MB total
    else if (ws_size >= off + sfull / 2) nh = 2;
    else                                 nh = 4;
    const int cnt = MFULL / nh;

    // prep: zero XTG + build B2 (dense) + WB
    {
        int tot = ZN + B2N + WBN;
        prep_kernel<<<(tot + 255) / 256, 256, 0, stream>>>(pgw, w, XTGa, B2, WB);
    }
    // transpose x -> XTG (group-planar NHWC bf16, 66x66 halo)
    xpose_kernel<<<dim3(Hn, Bn), 256, 0, stream>>>(x, XTG);

    // pg conv: dense-K 256x128/BK=64, 8 waves, T2 swizzle, phase-split
    pg_shift_kernel<<<dim3(PG_MT, NP / 128), 512, 0, stream>>>(
        XTG, B2, pgb, pgBF);

    // deformable sampling (XCD-batch-affine 1D grid) -> tiled S, then main GEMM
    for (int h = 0; h < nh; ++h) {
        int nblk = (cnt >> 12) * 2016;   // batches_in_chunk * (126 gk * 16 pxb)
        sample_kernel<<<dim3(nblk), 256, 0, stream>>>(
            XTG, pgBF, S, h * cnt);
        main_gemm_kernel<<<dim3(cnt / 128, 1), 256, 0, stream>>>(
            S, WB, bias, out, h * cnt);
    }
}

// Round 17
// 111.187 us; speedup vs baseline: 1.6789x; 1.0509x over previous
//
#include <hip/hip_runtime.h>
#include <math.h>

#define Bn 8
#define Cn 112
#define Hn 64
#define Wn 64
#define On 112
#define Gn 14
#define PGC 378          // 3*G*K2
#define HW 4096          // 64*64
#define CKW 1008         // C*K2
#define KP 1024          // padded K (main GEMM and dense pg GEMM)
#define NP 384           // padded N (oc) for pg GEMM
#define MFULL 32768
#define XROW 4356        // 66*66 rows per batch
#define PG_MT 137        // M-tiles of 256
#define MPAD (PG_MT * 256)                 // 35072
#define PLANE_ROWS 34848                   // 8 batches * 4356 rows per plane
#define XGUARD 67
#define XTG_ROWS_TOTAL 558080              // padded alloc rows (>= 15 planes + guards)

typedef __attribute__((ext_vector_type(8))) short bf16x8;
typedef __attribute__((ext_vector_type(4))) float f32x4;

__device__ __forceinline__ unsigned short f2bf(float f) {
    union { float f; unsigned int u; } v; v.f = f;
    unsigned int r = v.u + 0x7fffu + ((v.u >> 16) & 1u);
    return (unsigned short)(r >> 16);
}
__device__ __forceinline__ float bf2f(unsigned short u) {
    union { unsigned int u; float f; } v; v.u = ((unsigned int)u) << 16;
    return v.f;
}
__device__ __forceinline__ float bflo(unsigned int u) {
    union { unsigned int u; float f; } v; v.u = u << 16; return v.f;
}
__device__ __forceinline__ float bfhi(unsigned int u) {
    union { unsigned int u; float f; } v; v.u = u & 0xffff0000u; return v.f;
}
__device__ __forceinline__ void gload_lds16(const void* g, void* l) {
    __builtin_amdgcn_global_load_lds(
        (const __attribute__((address_space(1))) unsigned int*)g,
        (__attribute__((address_space(3))) unsigned int*)l, 16, 0, 0);
}

// ---------------------------------------------------------------------------
// prep (merged): zero XTG alloc | B2 dense [384][1024] | WB [128][1024]
// B2[oc][p_g*8+cc] = pgw[oc][(p_g%14)*8+cc][p_g/14],  p_g<126 (else 0)
// ---------------------------------------------------------------------------
#define ZN XTG_ROWS_TOTAL
#define B2N (NP * KP)
#define WBN (128 * KP)
__global__ __launch_bounds__(256) void prep_kernel(
    const float* __restrict__ pgw, const float* __restrict__ w,
    unsigned short* __restrict__ XTGa, unsigned short* __restrict__ B2,
    unsigned short* __restrict__ WB)
{
    int t = blockIdx.x * 256 + threadIdx.x;
    if (t < ZN) {
        const uint4 z = {0, 0, 0, 0};
        reinterpret_cast<uint4*>(XTGa)[t] = z;
        return;
    }
    t -= ZN;
    if (t < B2N) {
        int oc = t >> 10, ck = t & 1023;
        int pg_ = ck >> 3, cc = ck & 7;
        int tap = pg_ / 14, pl = pg_ % 14;
        float v = (pg_ < 126 && oc < PGC)
            ? pgw[(size_t)oc * CKW + (pl * 8 + cc) * 9 + tap] : 0.f;
        B2[t] = f2bf(v);
        return;
    }
    t -= B2N;
    if (t < WBN) {
        int oc = t >> 10, ck = t & 1023;
        float v = 0.f;
        if (oc < On && ck < CKW) {
            int g = ck / 72, r = ck % 72;
            int k = r >> 3, cc = r & 7;
            v = w[(size_t)oc * CKW + (g * 8 + cc) * 9 + k];
        }
        WB[t] = f2bf(v);
    }
}

// ---------------------------------------------------------------------------
// xpose: x NCHW f32 -> XTG bf16 planes [g][b][row66x66][8ch]
// ---------------------------------------------------------------------------
__global__ __launch_bounds__(256) void xpose_kernel(
    const float* __restrict__ x, unsigned short* __restrict__ XTG)
{
    __shared__ unsigned short lds[64][136];

    const int tid = threadIdx.x;
    const int y = blockIdx.x, b = blockIdx.y;
    const int xx = tid & 63, cw = tid >> 6;

    const float* xb = x + (size_t)b * Cn * HW + y * 64;
    #pragma unroll
    for (int p = 0; p < 28; ++p) {
        int c = p * 4 + cw;
        lds[xx][c] = f2bf(xb[(size_t)c * HW + xx]);
    }
    __syncthreads();

    #pragma unroll
    for (int q = 0; q < 4; ++q) {
        int task = q * 256 + tid;            // 0..895 used (64 xx * 14 g)
        if (task < 896) {
            int g = task >> 6;
            int x2 = task & 63;
            unsigned short* dst = XTG + ((size_t)g * PLANE_ROWS
                + (size_t)b * XROW + (y + 1) * 66 + x2 + 1) * 8;
            *reinterpret_cast<uint4*>(dst) =
                *reinterpret_cast<const uint4*>(&lds[x2][g * 8]);
        }
    }
}

// ---------------------------------------------------------------------------
// pg shift-GEMM v7: dense-K (1024), BK=32 (32 K-tiles of 4 planes),
// 256x128 tile, 8 waves (4M x 2N), per-wave 64x64.
// 72 KB LDS (3 buffers) -> 2 blocks/CU; 411 blocks all co-resident (no tail).
// Swizzle: chunk ^= row&3 (4 x 16B chunks per 64B row, 2-way bank = free);
// staging picks pre-swizzled source plane per lane.  Counted vmcnt(3),
// one barrier per K-tile, setprio around MFMA.
// Epilogue: acc(+bias) -> LDS transpose T[oc][px] -> coalesced stores.
// ---------------------------------------------------------------------------
#define A_BUF_B 16384        // 256 rows * 64 B
#define B_BUF_B 8192         // 128 rows * 64 B
__global__ __launch_bounds__(512, 4) void pg_shift_kernel(
    const unsigned short* __restrict__ XTG, const unsigned short* __restrict__ B2,
    const float* __restrict__ pgb, unsigned short* __restrict__ pgBF)
{
    __shared__ __align__(16) unsigned char smem[3 * (A_BUF_B + B_BUF_B)]; // 72 KB

    const int tid  = threadIdx.x;
    const int lane = tid & 63;
    const int w    = tid >> 6;          // 0..7
    const int wr   = w >> 1;            // 0..3  (M)
    const int wc   = w & 1;             // 0..1  (N)
    const int m0   = blockIdx.x * 256;
    const int n0   = blockIdx.y * 128;
    const int fr   = lane & 15, fq = lane >> 4;   // fq in 0..3 = 16B chunk

    f32x4 acc[4][4] = {};

    auto Abuf = [&](int b) -> unsigned char* { return smem + b * A_BUF_B; };
    auto Bbuf = [&](int b) -> unsigned char* {
        return smem + 3 * A_BUF_B + b * B_BUF_B; };

    // stage one K-tile: exactly 3 gload_lds per lane (2 A + 1 B)
    auto stage = [&](int buf, int kt) {
        #pragma unroll
        for (int s = 0; s < 2; ++s) {
            int r = w * 32 + s * 16 + (lane >> 2);
            int ch = (lane & 3) ^ (r & 3);
            int pg_ = kt * 4 + ch;
            int tap = pg_ / 14, pl = pg_ % 14;
            int shift = (tap / 3 - 1) * 66 + (tap % 3) - 1;
            if (pg_ >= 126) { pl = 14; shift = 0; }
            gload_lds16(XTG + ((long)pl * PLANE_ROWS + (long)(m0 + r) + shift) * 8,
                        Abuf(buf) + (w * 32 + s * 16) * 64);
        }
        {
            int r = w * 16 + (lane >> 2);
            int ch = (lane & 3) ^ (r & 3);
            gload_lds16(&B2[(size_t)(n0 + r) * KP + kt * 32 + ch * 8],
                        Bbuf(buf) + (w * 16) * 64);
        }
    };

    stage(0, 0);
    stage(1, 1);

    for (int kt = 0; kt < 32; ++kt) {
        if (kt < 31) asm volatile("s_waitcnt vmcnt(3)" ::: "memory");
        else         asm volatile("s_waitcnt vmcnt(0)" ::: "memory");
        __builtin_amdgcn_s_barrier();
        asm volatile("" ::: "memory");

        const int cur = kt % 3;
        const unsigned char* Ab = Abuf(cur);
        const unsigned char* Bb = Bbuf(cur);

        bf16x8 a[4], b[4];
        #pragma unroll
        for (int mi = 0; mi < 4; ++mi) {
            int r = wr * 64 + mi * 16 + fr;
            a[mi] = *reinterpret_cast<const bf16x8*>(
                Ab + r * 64 + ((fq ^ (r & 3)) << 4));
        }
        #pragma unroll
        for (int ni = 0; ni < 4; ++ni) {
            int r = wc * 64 + ni * 16 + fr;
            b[ni] = *reinterpret_cast<const bf16x8*>(
                Bb + r * 64 + ((fq ^ (r & 3)) << 4));
        }
        if (kt + 2 < 32) stage((kt + 2) % 3, kt + 2);

        __builtin_amdgcn_s_setprio(1);
        #pragma unroll
        for (int mi = 0; mi < 4; ++mi)
            #pragma unroll
            for (int ni = 0; ni < 4; ++ni)
                acc[mi][ni] = __builtin_amdgcn_mfma_f32_16x16x32_bf16(
                    a[mi], b[ni], acc[mi][ni], 0, 0, 0);
        __builtin_amdgcn_s_setprio(0);
    }

    // ---------------- epilogue: LDS transpose + coalesced store -----------
    __builtin_amdgcn_s_barrier();           // all LDS reads done
    unsigned short* T = (unsigned short*)smem;   // [128 oc][264 px] = 67.6 KB

    #pragma unroll
    for (int ni = 0; ni < 4; ++ni) {
        int ocl = wc * 64 + ni * 16 + fr;
        float bv = (n0 + ocl < PGC) ? pgb[n0 + ocl] : 0.f;
        #pragma unroll
        for (int mi = 0; mi < 4; ++mi) {
            int pxl = wr * 64 + mi * 16 + fq * 4;
            ushort4 pk;
            pk.x = f2bf(acc[mi][ni][0] + bv);
            pk.y = f2bf(acc[mi][ni][1] + bv);
            pk.z = f2bf(acc[mi][ni][2] + bv);
            pk.w = f2bf(acc[mi][ni][3] + bv);
            *reinterpret_cast<ushort4*>(&T[ocl * 264 + pxl]) = pk;
        }
    }
    __builtin_amdgcn_s_barrier();

    const int pxls = tid & 255;
    const int half = tid >> 8;
    const int pxd  = m0 + pxls;
    const int bb   = pxd / XROW;
    const int rem  = pxd - bb * XROW;
    const int yy   = rem / 66 - 1;
    const int xx   = rem - (yy + 1) * 66 - 1;
    const bool valid = (pxd < Bn * XROW) &&
                       ((unsigned)yy < 64u) && ((unsigned)xx < 64u);
    unsigned short* pbase = pgBF + (size_t)bb * PGC * HW + yy * 64 + xx;

    #pragma unroll 4
    for (int oc = 0; oc < 64; ++oc) {
        int ocg = n0 + half * 64 + oc;
        if (ocg >= PGC) break;               // wave-uniform
        unsigned short v = T[(half * 64 + oc) * 264 + pxls];
        if (valid) pbase[(size_t)ocg * HW] = v;
    }
}

// ---------------------------------------------------------------------------
// sample: 1D grid with bijective XCD swizzle; inner order (batch, gk, pxb)
// so each XCD works one batch.  Thread = (pixel, (g,k) tap), planar 16B
// corner loads; writes tiled S [px/128][ck/8][px%128][8ch].
// ---------------------------------------------------------------------------
__global__ __launch_bounds__(256) void sample_kernel(
    const unsigned short* __restrict__ XTG, const unsigned short* __restrict__ pg,
    unsigned short* __restrict__ S, int px_base)
{
    const int cpx = gridDim.x >> 3;
    const int swz = (blockIdx.x & 7) * cpx + (blockIdx.x >> 3);
    const int bloc = swz / 2016;             // local batch (126 gk * 16 pxb)
    const int rem  = swz - bloc * 2016;
    const int gk   = rem >> 4;               // 0..125
    const int pxb  = rem & 15;
    const int pxl  = (bloc << 12) + (pxb << 8) + threadIdx.x;

    const int g = gk / 9, k = gk - 9 * g;
    const int pxg = px_base + pxl;
    const int b = pxg >> 12, hw = pxg & 4095;
    const int y = hw >> 6, xc = hw & 63;
    const int pblk = pxl >> 7, prem = pxl & 127;

    if (gk == 0) {   // zero K-pad blocks cb = 126, 127
        const uint4 z = {0, 0, 0, 0};
        *reinterpret_cast<uint4*>(
            &S[(((size_t)pblk * 128 + 126) * 128 + prem) * 8]) = z;
        *reinterpret_cast<uint4*>(
            &S[(((size_t)pblk * 128 + 127) * 128 + prem) * 8]) = z;
    }

    const unsigned short* pgb = pg + (size_t)b * PGC * HW + hw;
    float dy = bf2f(pgb[(size_t)(18 * g + 2 * k) * HW]);
    float dx = bf2f(pgb[(size_t)(18 * g + 2 * k + 1) * HW]);
    float mv = bf2f(pgb[(size_t)(252 + 9 * g + k) * HW]);
    float m  = 1.f / (1.f + __expf(-mv));

    const int ky = k / 3, kx = k % 3;
    float yf = (float)(y + ky - 1) + dy;
    float xf = (float)(xc + kx - 1) + dx;
    float y0 = floorf(yf), x0 = floorf(xf);
    float wy1 = yf - y0, wx1 = xf - x0;
    float wy0 = 1.f - wy1, wx0 = 1.f - wx1;
    int iy0 = (int)y0, ix0 = (int)x0;
    bool vy0 = (iy0 >= 0) && (iy0 < Hn);
    bool vy1 = (iy0 >= -1) && (iy0 < Hn - 1);
    bool vx0 = (ix0 >= 0) && (ix0 < Wn);
    bool vx1 = (ix0 >= -1) && (ix0 < Wn - 1);
    int cy0 = min(max(iy0, 0), Hn - 1), cy1 = min(max(iy0 + 1, 0), Hn - 1);
    int cx0 = min(max(ix0, 0), Wn - 1), cx1 = min(max(ix0 + 1, 0), Wn - 1);
    float w00 = (vy0 && vx0) ? wy0 * wx0 * m : 0.f;
    float w01 = (vy0 && vx1) ? wy0 * wx1 * m : 0.f;
    float w10 = (vy1 && vx0) ? wy1 * wx0 * m : 0.f;
    float w11 = (vy1 && vx1) ? wy1 * wx1 * m : 0.f;

    const unsigned short* xg = XTG +
        ((size_t)g * PLANE_ROWS + (size_t)b * XROW) * 8;
    const int r00 = (cy0 + 1) * 66 + cx0 + 1, r01 = (cy0 + 1) * 66 + cx1 + 1;
    const int r10 = (cy1 + 1) * 66 + cx0 + 1, r11 = (cy1 + 1) * 66 + cx1 + 1;
    uint4 q00 = *reinterpret_cast<const uint4*>(xg + (size_t)r00 * 8);
    uint4 q01 = *reinterpret_cast<const uint4*>(xg + (size_t)r01 * 8);
    uint4 q10 = *reinterpret_cast<const uint4*>(xg + (size_t)r10 * 8);
    uint4 q11 = *reinterpret_cast<const uint4*>(xg + (size_t)r11 * 8);

    unsigned int c00[4] = {q00.x, q00.y, q00.z, q00.w};
    unsigned int c01[4] = {q01.x, q01.y, q01.z, q01.w};
    unsigned int c10[4] = {q10.x, q10.y, q10.z, q10.w};
    unsigned int c11[4] = {q11.x, q11.y, q11.z, q11.w};

    unsigned int pk[4];
    #pragma unroll
    for (int j = 0; j < 4; ++j) {
        float lo = bflo(c00[j]) * w00 + bflo(c01[j]) * w01 +
                   bflo(c10[j]) * w10 + bflo(c11[j]) * w11;
        float hi = bfhi(c00[j]) * w00 + bfhi(c01[j]) * w01 +
                   bfhi(c10[j]) * w10 + bfhi(c11[j]) * w11;
        pk[j] = (unsigned int)f2bf(lo) | ((unsigned int)f2bf(hi) << 16);
    }
    *reinterpret_cast<uint4*>(
        &S[(((size_t)pblk * 128 + gk) * 128 + prem) * 8]) =
        *reinterpret_cast<const uint4*>(pk);
}

// ---------------------------------------------------------------------------
// main GEMM: out[b][oc][hw] = S_tiled[px][ck] * WB[oc][ck] + bias[oc]
// Double-buffered prefetch, counted vmcnt (validated rounds 9-16).
// ---------------------------------------------------------------------------
__global__ __launch_bounds__(256) void main_gemm_kernel(
    const unsigned short* __restrict__ S, const unsigned short* __restrict__ WB,
    const float* __restrict__ bias, float* __restrict__ out, int px_base)
{
    __shared__ __align__(16) unsigned short Asm[2][128 * 32];
    __shared__ __align__(16) unsigned short Bsm[2][128 * 32];

    const int tid  = threadIdx.x;
    const int lane = tid & 63;
    const int w    = tid >> 6;
    const int wr   = w >> 1, wc = w & 1;
    const int m0   = blockIdx.x * 128;
    const int fr   = lane & 15, fq = lane >> 4;

    f32x4 acc[4][4] = {};

    const int ldr = lane >> 2;
    const int lq  = lane & 3;
    const int ldc = lq * 8;

    auto stage = [&](int buf, int kt) {
        #pragma unroll
        for (int i = 0; i < 2; ++i) {
            int row = w * 32 + i * 16 + ldr;
            int cb  = kt * 4 + lq;
            gload_lds16(&S[(((size_t)blockIdx.x * 128 + cb) * 128 + row) * 8],
                        &Asm[buf][(w * 32 + i * 16) * 32]);
            gload_lds16(&WB[(size_t)row * KP + kt * 32 + ldc],
                        &Bsm[buf][(w * 32 + i * 16) * 32]);
        }
    };

    stage(0, 0);
    int cur = 0;
    for (int kt = 0; kt < 32; ++kt) {
        if (kt + 1 < 32) {
            stage(cur ^ 1, kt + 1);
            asm volatile("s_waitcnt vmcnt(4)" ::: "memory");
        } else {
            asm volatile("s_waitcnt vmcnt(0)" ::: "memory");
        }
        __builtin_amdgcn_s_barrier();
        asm volatile("" ::: "memory");

        bf16x8 a[4], b[4];
        #pragma unroll
        for (int mi = 0; mi < 4; ++mi)
            a[mi] = *reinterpret_cast<const bf16x8*>(
                &Asm[cur][(wr * 64 + mi * 16 + fr) * 32 + fq * 8]);
        #pragma unroll
        for (int ni = 0; ni < 4; ++ni)
            b[ni] = *reinterpret_cast<const bf16x8*>(
                &Bsm[cur][(wc * 64 + ni * 16 + fr) * 32 + fq * 8]);
        #pragma unroll
        for (int mi = 0; mi < 4; ++mi)
            #pragma unroll
            for (int ni = 0; ni < 4; ++ni)
                acc[mi][ni] = __builtin_amdgcn_mfma_f32_16x16x32_bf16(
                    a[mi], b[ni], acc[mi][ni], 0, 0, 0);

        asm volatile("s_waitcnt lgkmcnt(0)" ::: "memory");
        __builtin_amdgcn_s_barrier();
        asm volatile("" ::: "memory");
        cur ^= 1;
    }

    #pragma unroll
    for (int ni = 0; ni < 4; ++ni) {
        int oc = wc * 64 + ni * 16 + fr;
        if (oc >= On) continue;
        float bv = bias[oc];
        #pragma unroll
        for (int mi = 0; mi < 4; ++mi) {
            int pxl = m0 + wr * 64 + mi * 16 + fq * 4;
            int pxg = px_base + pxl;
            int b = pxg >> 12, hw = pxg & 4095;
            float4 o;
            o.x = acc[mi][ni][0] + bv;
            o.y = acc[mi][ni][1] + bv;
            o.z = acc[mi][ni][2] + bv;
            o.w = acc[mi][ni][3] + bv;
            *reinterpret_cast<float4*>(
                &out[((size_t)(b * On + oc)) * HW + hw]) = o;
        }
    }
}

// ---------------------------------------------------------------------------
extern "C" void kernel_launch(void* const* d_in, const int* in_sizes, int n_in,
                              void* d_out, int out_size, void* d_ws, size_t ws_size,
                              hipStream_t stream) {
    const float* x    = (const float*)d_in[0];
    const float* pgw  = (const float*)d_in[1];
    const float* pgb  = (const float*)d_in[2];
    const float* w    = (const float*)d_in[3];
    const float* bias = (const float*)d_in[4];
    float* out = (float*)d_out;

    char* wsb = (char*)d_ws;
    unsigned short* pgBF = (unsigned short*)wsb;                 // 24.77 MB
    size_t off = (size_t)PGC * Bn * HW * 2;
    unsigned short* B2   = (unsigned short*)(wsb + off);         // 0.79 MB
    off += (size_t)NP * KP * 2;
    unsigned short* WB   = (unsigned short*)(wsb + off);         // 0.26 MB
    off += (size_t)128 * KP * 2;
    unsigned short* XTGa = (unsigned short*)(wsb + off);         // 8.93 MB
    unsigned short* XTG  = XTGa + (size_t)XGUARD * 8;            // guarded base
    off += (size_t)XTG_ROWS_TOTAL * 16;
    unsigned short* S    = (unsigned short*)(wsb + off);         // sampled (tiled)

    const size_t sfull = (size_t)MFULL * KP * 2;                 // 67.1 MB
    int nh;
    if (ws_size >= off + sfull)          nh = 1;   // ~102 MB total
    else if (ws_size >= off + sfull / 2) nh = 2;
    else                                 nh = 4;
    const int cnt = MFULL / nh;

    // prep: zero XTG + build B2 (dense) + WB
    {
        int tot = ZN + B2N + WBN;
        prep_kernel<<<(tot + 255) / 256, 256, 0, stream>>>(pgw, w, XTGa, B2, WB);
    }
    // transpose x -> XTG (group-planar NHWC bf16, 66x66 halo)
    xpose_kernel<<<dim3(Hn, Bn), 256, 0, stream>>>(x, XTG);

    // pg conv: dense-K 256x128/BK=32, 2 blocks/CU, all-resident grid
    pg_shift_kernel<<<dim3(PG_MT, NP / 128), 512, 0, stream>>>(
        XTG, B2, pgb, pgBF);

    // deformable sampling (XCD-batch-affine 1D grid) -> tiled S, then main GEMM
    for (int h = 0; h < nh; ++h) {
        int nblk = (cnt >> 12) * 2016;   // batches_in_chunk * (126 gk * 16 pxb)
        sample_kernel<<<dim3(nblk), 256, 0, stream>>>(
            XTG, pgBF, S, h * cnt);
        main_gemm_kernel<<<dim3(cnt / 128, 1), 256, 0, stream>>>(
            S, WB, bias, out, h * cnt);
    }
}